// Round 1
// baseline (1031.723 us; speedup 1.0000x reference)
//
#include <hip/hip_runtime.h>
#include <math.h>

#define NG 64   // graphs

static inline int cdiv(int a, int b) { return (a + b - 1) / b; }

// ---------------- feature build ----------------
__global__ __launch_bounds__(256) void k_build_x(
    const float* __restrict__ xc, const int* __restrict__ xcl,
    const int* __restrict__ xpi, const float* __restrict__ ctab,
    const float* __restrict__ ptab, float* __restrict__ x, int n) {
  int t = blockIdx.x * blockDim.x + threadIdx.x;
  int total = n * 134;
  if (t >= total) return;
  int node = t / 134, c = t % 134;
  float v;
  if (c < 6)       v = xc[node * 6 + c];
  else if (c < 70) v = ctab[xcl[node] * 64 + (c - 6)];
  else             v = ptab[xpi[node] * 64 + (c - 70)];
  x[t] = v;
}

// ---------------- CSR build ----------------
__global__ __launch_bounds__(256) void k_hist(const int* __restrict__ dst,
                                              int* __restrict__ deg, int E, int N) {
  int t = blockIdx.x * blockDim.x + threadIdx.x;
  if (t < E) atomicAdd(&deg[dst[t]], 1);
  else if (t < E + N) atomicAdd(&deg[t - E], 1);  // self loops
}

__global__ __launch_bounds__(1024) void k_scan(const int* __restrict__ deg,
                                               int* __restrict__ rowptr, int n) {
  __shared__ int tmp[1024];
  __shared__ int carry_s;
  if (threadIdx.x == 0) carry_s = 0;
  __syncthreads();
  for (int base = 0; base < n; base += 1024) {
    int i = base + (int)threadIdx.x;
    int v = (i < n) ? deg[i] : 0;
    tmp[threadIdx.x] = v;
    __syncthreads();
    for (int off = 1; off < 1024; off <<= 1) {
      int t = (threadIdx.x >= off) ? tmp[threadIdx.x - off] : 0;
      __syncthreads();
      tmp[threadIdx.x] += t;
      __syncthreads();
    }
    if (i < n) rowptr[i + 1] = carry_s + tmp[threadIdx.x];
    __syncthreads();
    if (threadIdx.x == 1023) carry_s += tmp[1023];
    __syncthreads();
  }
  if (threadIdx.x == 0) rowptr[0] = 0;
}

__global__ __launch_bounds__(256) void k_scatter(
    const int* __restrict__ src, const int* __restrict__ dst,
    const int* __restrict__ rowptr, int* __restrict__ fill,
    int* __restrict__ csr, int E, int N) {
  int t = blockIdx.x * blockDim.x + threadIdx.x;
  int s, d;
  if (t < E) { s = src[t]; d = dst[t]; }
  else if (t < E + N) { s = t - E; d = t - E; }
  else return;
  int pos = rowptr[d] + atomicAdd(&fill[d], 1);
  csr[pos] = s;
}

// ---------------- fp32 GEMM: C[M,NC] = A[M,K] @ W[K,NC] + bias ----------------
#define BM 128
#define BN 128
#define BK 8
__global__ __launch_bounds__(256) void k_gemm(
    const float* __restrict__ A, const float* __restrict__ W,
    const float* __restrict__ bias, float* __restrict__ C,
    int M, int K, int NC) {
  __shared__ float As[BK][BM];
  __shared__ float Bs[BK][BN];
  int tid = threadIdx.x;
  int tx = tid & 15, ty = tid >> 4;
  int row0 = blockIdx.x * BM, col0 = blockIdx.y * BN;
  float acc[8][8] = {};
  for (int k0 = 0; k0 < K; k0 += BK) {
#pragma unroll
    for (int i = 0; i < 4; ++i) {
      int idx = tid + i * 256;
      int kk = idx & 7, r = idx >> 3;
      int gr = row0 + r, gk = k0 + kk;
      As[kk][r] = (gr < M && gk < K) ? A[(size_t)gr * K + gk] : 0.f;
    }
#pragma unroll
    for (int i = 0; i < 4; ++i) {
      int idx = tid + i * 256;
      int col = idx & 127, kk = idx >> 7;
      int gk = k0 + kk;
      Bs[kk][col] = (gk < K) ? W[(size_t)gk * NC + col0 + col] : 0.f;
    }
    __syncthreads();
#pragma unroll
    for (int kk = 0; kk < BK; ++kk) {
      float4 a0 = *(const float4*)&As[kk][ty * 8];
      float4 a1 = *(const float4*)&As[kk][ty * 8 + 4];
      float4 b0 = *(const float4*)&Bs[kk][tx * 8];
      float4 b1 = *(const float4*)&Bs[kk][tx * 8 + 4];
      float a[8] = {a0.x, a0.y, a0.z, a0.w, a1.x, a1.y, a1.z, a1.w};
      float b[8] = {b0.x, b0.y, b0.z, b0.w, b1.x, b1.y, b1.z, b1.w};
#pragma unroll
      for (int i = 0; i < 8; ++i)
#pragma unroll
        for (int j = 0; j < 8; ++j) acc[i][j] += a[i] * b[j];
    }
    __syncthreads();
  }
#pragma unroll
  for (int i = 0; i < 8; ++i) {
    int gr = row0 + ty * 8 + i;
    if (gr < M) {
#pragma unroll
      for (int j = 0; j < 8; j += 4) {
        int gc = col0 + tx * 8 + j;
        float4 v;
        v.x = acc[i][j + 0] + bias[gc + 0];
        v.y = acc[i][j + 1] + bias[gc + 1];
        v.z = acc[i][j + 2] + bias[gc + 2];
        v.w = acc[i][j + 3] + bias[gc + 3];
        *(float4*)&C[(size_t)gr * NC + gc] = v;
      }
    }
  }
}

// ---------------- GAT layer 1 aggregate (H=4, C=128) + bias + LN + ELU ----------------
// one wave (64 lanes) per node; lane owns 8 consecutive channels of the 512
__global__ __launch_bounds__(256) void k_gat1(
    const float* __restrict__ xl, const float* __restrict__ xr,
    const int* __restrict__ rowptr, const int* __restrict__ csr,
    const float* __restrict__ att, const float* __restrict__ bias,
    const float* __restrict__ lng, const float* __restrict__ lnb,
    float* __restrict__ out, int n) {
  int wid = (blockIdx.x * blockDim.x + threadIdx.x) >> 6;
  int lane = threadIdx.x & 63;
  if (wid >= n) return;
  int base = lane * 8;
  float xrv[8], attv[8];
  {
    const float* p = &xr[(size_t)wid * 512 + base];
    float4 t0 = *(const float4*)p;
    float4 t1 = *(const float4*)(p + 4);
    xrv[0] = t0.x; xrv[1] = t0.y; xrv[2] = t0.z; xrv[3] = t0.w;
    xrv[4] = t1.x; xrv[5] = t1.y; xrv[6] = t1.z; xrv[7] = t1.w;
    const float* ap = &att[(lane >> 4) * 128 + (lane & 15) * 8];
    float4 u0 = *(const float4*)ap;
    float4 u1 = *(const float4*)(ap + 4);
    attv[0] = u0.x; attv[1] = u0.y; attv[2] = u0.z; attv[3] = u0.w;
    attv[4] = u1.x; attv[5] = u1.y; attv[6] = u1.z; attv[7] = u1.w;
  }
  float m = -INFINITY, s = 0.f;
  float acc[8] = {};
  int e0 = rowptr[wid], e1 = rowptr[wid + 1];
  for (int p = e0; p < e1; ++p) {
    int src = csr[p];
    const float* vp = &xl[(size_t)src * 512 + base];
    float4 v0 = *(const float4*)vp;
    float4 v1 = *(const float4*)(vp + 4);
    float v[8] = {v0.x, v0.y, v0.z, v0.w, v1.x, v1.y, v1.z, v1.w};
    float pe = 0.f;
#pragma unroll
    for (int j = 0; j < 8; ++j) {
      float t = v[j] + xrv[j];
      t = t > 0.f ? t : 0.2f * t;
      pe += t * attv[j];
    }
    pe += __shfl_xor(pe, 1);
    pe += __shfl_xor(pe, 2);
    pe += __shfl_xor(pe, 4);
    pe += __shfl_xor(pe, 8);
    if (pe <= m) {
      float w = __expf(pe - m);
      s += w;
#pragma unroll
      for (int j = 0; j < 8; ++j) acc[j] += w * v[j];
    } else {
      float sc = __expf(m - pe);
      s = s * sc + 1.f;
#pragma unroll
      for (int j = 0; j < 8; ++j) acc[j] = acc[j] * sc + v[j];
      m = pe;
    }
  }
  float inv = 1.f / (s + 1e-16f);
  float o[8];
#pragma unroll
  for (int j = 0; j < 8; ++j) o[j] = acc[j] * inv + bias[base + j];
  // LayerNorm over 512 (whole wave)
  float sum = 0.f, sq = 0.f;
#pragma unroll
  for (int j = 0; j < 8; ++j) { sum += o[j]; sq += o[j] * o[j]; }
#pragma unroll
  for (int off = 1; off < 64; off <<= 1) {
    sum += __shfl_xor(sum, off);
    sq += __shfl_xor(sq, off);
  }
  float mean = sum * (1.f / 512.f);
  float var = fmaxf(sq * (1.f / 512.f) - mean * mean, 0.f);
  float rstd = rsqrtf(var + 1e-5f);
#pragma unroll
  for (int j = 0; j < 8; ++j) {
    float y = (o[j] - mean) * rstd * lng[base + j] + lnb[base + j];
    y = y > 0.f ? y : __expf(y) - 1.f;   // ELU
    out[(size_t)wid * 512 + base + j] = y;
  }
}

// ---------------- GAT layer 2 aggregate (H=1, C=256) + bias + LN + ELU ----------------
__global__ __launch_bounds__(256) void k_gat2(
    const float* __restrict__ xl, const float* __restrict__ xr,
    const int* __restrict__ rowptr, const int* __restrict__ csr,
    const float* __restrict__ att, const float* __restrict__ bias,
    const float* __restrict__ lng, const float* __restrict__ lnb,
    float* __restrict__ out, int n) {
  int wid = (blockIdx.x * blockDim.x + threadIdx.x) >> 6;
  int lane = threadIdx.x & 63;
  if (wid >= n) return;
  int base = lane * 4;
  float4 xr4 = *(const float4*)&xr[(size_t)wid * 256 + base];
  float xrv[4] = {xr4.x, xr4.y, xr4.z, xr4.w};
  float4 at4 = *(const float4*)&att[base];
  float attv[4] = {at4.x, at4.y, at4.z, at4.w};
  float m = -INFINITY, s = 0.f;
  float acc[4] = {};
  int e0 = rowptr[wid], e1 = rowptr[wid + 1];
  for (int p = e0; p < e1; ++p) {
    int src = csr[p];
    float4 v4 = *(const float4*)&xl[(size_t)src * 256 + base];
    float v[4] = {v4.x, v4.y, v4.z, v4.w};
    float pe = 0.f;
#pragma unroll
    for (int j = 0; j < 4; ++j) {
      float t = v[j] + xrv[j];
      t = t > 0.f ? t : 0.2f * t;
      pe += t * attv[j];
    }
#pragma unroll
    for (int off = 1; off < 64; off <<= 1) pe += __shfl_xor(pe, off);
    if (pe <= m) {
      float w = __expf(pe - m);
      s += w;
#pragma unroll
      for (int j = 0; j < 4; ++j) acc[j] += w * v[j];
    } else {
      float sc = __expf(m - pe);
      s = s * sc + 1.f;
#pragma unroll
      for (int j = 0; j < 4; ++j) acc[j] = acc[j] * sc + v[j];
      m = pe;
    }
  }
  float inv = 1.f / (s + 1e-16f);
  float o[4];
#pragma unroll
  for (int j = 0; j < 4; ++j) o[j] = acc[j] * inv + bias[base + j];
  float sum = 0.f, sq = 0.f;
#pragma unroll
  for (int j = 0; j < 4; ++j) { sum += o[j]; sq += o[j] * o[j]; }
#pragma unroll
  for (int off = 1; off < 64; off <<= 1) {
    sum += __shfl_xor(sum, off);
    sq += __shfl_xor(sq, off);
  }
  float mean = sum * (1.f / 256.f);
  float var = fmaxf(sq * (1.f / 256.f) - mean * mean, 0.f);
  float rstd = rsqrtf(var + 1e-5f);
#pragma unroll
  for (int j = 0; j < 4; ++j) {
    float y = (o[j] - mean) * rstd * lng[base + j] + lnb[base + j];
    y = y > 0.f ? y : __expf(y) - 1.f;
    out[(size_t)wid * 256 + base + j] = y;
  }
}

// ---------------- pooling (batch is sorted) ----------------
__global__ __launch_bounds__(256) void k_pool(
    const float* __restrict__ h2, const int* __restrict__ batch,
    float* __restrict__ pooled, int* __restrict__ cnt, int n) {
  int c = threadIdx.x;  // 256 channels
  int n0 = blockIdx.x * 256;
  int n1 = min(n0 + 256, n);
  if (n0 >= n) return;
  float acc = 0.f;
  int cur = batch[n0];
  int cl = 0;
  for (int i = n0; i < n1; ++i) {
    int bb = batch[i];
    if (bb != cur) {
      atomicAdd(&pooled[cur * 256 + c], acc);
      if (c == 0) atomicAdd(&cnt[cur], cl);
      acc = 0.f; cl = 0; cur = bb;
    }
    acc += h2[(size_t)i * 256 + c];
    cl++;
  }
  atomicAdd(&pooled[cur * 256 + c], acc);
  if (c == 0) atomicAdd(&cnt[cur], cl);
}

// ---------------- projection head ----------------
__global__ __launch_bounds__(512) void k_proj1(
    const float* __restrict__ pooled, const int* __restrict__ cnt,
    const float* __restrict__ W, const float* __restrict__ b,
    const float* __restrict__ lng, const float* __restrict__ lnb,
    float* __restrict__ hout) {
  __shared__ float row[256];
  __shared__ float red[16];
  int g = blockIdx.x, c = threadIdx.x;
  if (c < 256) {
    float cc = fmaxf((float)cnt[g], 1.f);
    row[c] = pooled[g * 256 + c] / cc;
  }
  __syncthreads();
  float acc = b[c];
#pragma unroll 4
  for (int k = 0; k < 256; ++k) acc += row[k] * W[k * 512 + c];
  float sum = acc, sq = acc * acc;
#pragma unroll
  for (int off = 1; off < 64; off <<= 1) {
    sum += __shfl_xor(sum, off);
    sq += __shfl_xor(sq, off);
  }
  int wv = threadIdx.x >> 6;
  if ((threadIdx.x & 63) == 0) { red[wv] = sum; red[8 + wv] = sq; }
  __syncthreads();
  float S = 0.f, Q = 0.f;
#pragma unroll
  for (int t = 0; t < 8; ++t) { S += red[t]; Q += red[8 + t]; }
  float mean = S * (1.f / 512.f);
  float var = fmaxf(Q * (1.f / 512.f) - mean * mean, 0.f);
  float rstd = rsqrtf(var + 1e-5f);
  float y = (acc - mean) * rstd * lng[c] + lnb[c];
  float ge = 0.5f * y * (1.f + erff(y * 0.70710678118654752f));  // exact gelu
  hout[g * 512 + c] = ge;
}

__global__ __launch_bounds__(512) void k_proj2(
    const float* __restrict__ h, const float* __restrict__ W,
    const float* __restrict__ b, float* __restrict__ out) {
  __shared__ float row[512];
  __shared__ float red[8];
  int g = blockIdx.x, c = threadIdx.x;
  row[c] = h[g * 512 + c];
  __syncthreads();
  float acc = b[c];
#pragma unroll 4
  for (int k = 0; k < 512; ++k) acc += row[k] * W[k * 512 + c];
  float sq = acc * acc;
#pragma unroll
  for (int off = 1; off < 64; off <<= 1) sq += __shfl_xor(sq, off);
  int wv = threadIdx.x >> 6;
  if ((threadIdx.x & 63) == 0) red[wv] = sq;
  __syncthreads();
  float S = 0.f;
#pragma unroll
  for (int t = 0; t < 8; ++t) S += red[t];
  float norm = fmaxf(sqrtf(S), 1e-12f);
  out[g * 512 + c] = acc / norm;
}

// ---------------- launch ----------------
extern "C" void kernel_launch(void* const* d_in, const int* in_sizes, int n_in,
                              void* d_out, int out_size, void* d_ws, size_t ws_size,
                              hipStream_t stream) {
  const float* x_cont = (const float*)d_in[0];
  const int* x_class  = (const int*)d_in[1];
  const int* x_pitch  = (const int*)d_in[2];
  const int* ei       = (const int*)d_in[3];
  const int* batch    = (const int*)d_in[4];
  const float* ctab = (const float*)d_in[5];
  const float* ptab = (const float*)d_in[6];
  const float* Wl1 = (const float*)d_in[7];
  const float* bl1 = (const float*)d_in[8];
  const float* Wr1 = (const float*)d_in[9];
  const float* br1 = (const float*)d_in[10];
  const float* att1 = (const float*)d_in[11];
  const float* bias1 = (const float*)d_in[12];
  const float* ln1g = (const float*)d_in[13];
  const float* ln1b = (const float*)d_in[14];
  const float* Wl2 = (const float*)d_in[15];
  const float* bl2 = (const float*)d_in[16];
  const float* Wr2 = (const float*)d_in[17];
  const float* br2 = (const float*)d_in[18];
  const float* att2 = (const float*)d_in[19];
  const float* bias2 = (const float*)d_in[20];
  const float* ln2g = (const float*)d_in[21];
  const float* ln2b = (const float*)d_in[22];
  const float* Wp1 = (const float*)d_in[23];
  const float* bp1 = (const float*)d_in[24];
  const float* lnpg = (const float*)d_in[25];
  const float* lnpb = (const float*)d_in[26];
  const float* Wp2 = (const float*)d_in[27];
  const float* bp2 = (const float*)d_in[28];
  float* out = (float*)d_out;
  (void)n_in; (void)out_size; (void)ws_size;

  int N = in_sizes[1];
  int E = in_sizes[3] / 2;
  int ET = E + N;

  float* ws = (float*)d_ws;
  float* xbuf = ws;                                  // N*134
  float* xl1  = xbuf + (size_t)N * 134;              // N*512
  float* xr1  = xl1 + (size_t)N * 512;               // N*512
  float* h1   = xr1 + (size_t)N * 512;               // N*512
  float* pooled = h1 + (size_t)N * 512;              // NG*256
  int* cnt    = (int*)(pooled + NG * 256);           // NG
  float* hproj = (float*)(cnt + NG);                 // NG*512
  int* deg    = (int*)(hproj + NG * 512);            // N
  int* fill   = deg + N;                             // N
  int* rowptr = fill + N;                            // N+1
  int* csr    = rowptr + N + 1;                      // ET
  // aliases (xl1/xr1 dead after k_gat1)
  float* xl2 = xl1;
  float* xr2 = xl1 + (size_t)N * 256;
  float* h2  = xr1;

  const int* esrc = ei;
  const int* edst = ei + E;

  hipMemsetAsync(deg, 0, (size_t)2 * N * sizeof(int), stream);
  hipMemsetAsync(pooled, 0, (size_t)NG * 256 * sizeof(float) + NG * sizeof(int), stream);

  k_build_x<<<cdiv(N * 134, 256), 256, 0, stream>>>(x_cont, x_class, x_pitch, ctab, ptab, xbuf, N);
  k_hist<<<cdiv(ET, 256), 256, 0, stream>>>(edst, deg, E, N);
  k_scan<<<1, 1024, 0, stream>>>(deg, rowptr, N);
  k_scatter<<<cdiv(ET, 256), 256, 0, stream>>>(esrc, edst, rowptr, fill, csr, E, N);

  dim3 g1(cdiv(N, BM), 512 / BN);
  k_gemm<<<g1, 256, 0, stream>>>(xbuf, Wl1, bl1, xl1, N, 134, 512);
  k_gemm<<<g1, 256, 0, stream>>>(xbuf, Wr1, br1, xr1, N, 134, 512);
  k_gat1<<<cdiv(N * 64, 256), 256, 0, stream>>>(xl1, xr1, rowptr, csr, att1, bias1, ln1g, ln1b, h1, N);

  dim3 g2(cdiv(N, BM), 256 / BN);
  k_gemm<<<g2, 256, 0, stream>>>(h1, Wl2, bl2, xl2, N, 512, 256);
  k_gemm<<<g2, 256, 0, stream>>>(h1, Wr2, br2, xr2, N, 512, 256);
  k_gat2<<<cdiv(N * 64, 256), 256, 0, stream>>>(xl2, xr2, rowptr, csr, att2, bias2, ln2g, ln2b, h2, N);

  k_pool<<<cdiv(N, 256), 256, 0, stream>>>(h2, batch, pooled, cnt, N);
  k_proj1<<<NG, 512, 0, stream>>>(pooled, cnt, Wp1, bp1, lnpg, lnpb, hproj);
  k_proj2<<<NG, 512, 0, stream>>>(hproj, Wp2, bp2, out);
}

// Round 2
// 581.593 us; speedup vs baseline: 1.7740x; 1.7740x over previous
//
#include <hip/hip_runtime.h>
#include <math.h>

#define NG 64   // graphs

typedef short bf16x8 __attribute__((ext_vector_type(8)));
typedef float f32x4 __attribute__((ext_vector_type(4)));

static inline int cdiv(int a, int b) { return (a + b - 1) / b; }

__device__ inline ushort f2b(float f) {
  union { float f; uint u; } v; v.f = f;
  uint u = v.u;
  return (ushort)((u + 0x7fffu + ((u >> 16) & 1u)) >> 16);
}
__device__ inline float b2f(ushort h) {
  union { uint u; float f; } v; v.u = ((uint)h) << 16;
  return v.f;
}

// ---------------- feature build (bf16, K padded to 160) ----------------
__global__ __launch_bounds__(256) void k_build_xb(
    const float* __restrict__ xc, const int* __restrict__ xcl,
    const int* __restrict__ xpi, const float* __restrict__ ctab,
    const float* __restrict__ ptab, ushort* __restrict__ x, int n) {
  int t = blockIdx.x * blockDim.x + threadIdx.x;
  int total = n * 160;
  if (t >= total) return;
  int node = t / 160, c = t % 160;
  float v;
  if (c < 6)        v = xc[node * 6 + c];
  else if (c < 70)  v = ctab[xcl[node] * 64 + (c - 6)];
  else if (c < 134) v = ptab[xpi[node] * 64 + (c - 70)];
  else              v = 0.f;
  x[t] = f2b(v);
}

// ---------------- weight prep: transpose + concat + pad, fp32 -> bf16 ----------------
// W1t[1024][160]: rows 0..511 = Wl1 columns, 512..1023 = Wr1 columns
__global__ __launch_bounds__(256) void k_prep_w1(
    const float* __restrict__ Wl, const float* __restrict__ Wr,
    ushort* __restrict__ Wt) {
  int t = blockIdx.x * blockDim.x + threadIdx.x;
  if (t >= 1024 * 160) return;
  int c = t / 160, k = t % 160;
  float v = 0.f;
  if (k < 134) v = (c < 512) ? Wl[k * 512 + c] : Wr[k * 512 + (c - 512)];
  Wt[t] = f2b(v);
}
// W2t[512][512]: rows 0..255 = Wl2 cols, 256..511 = Wr2 cols
__global__ __launch_bounds__(256) void k_prep_w2(
    const float* __restrict__ Wl, const float* __restrict__ Wr,
    ushort* __restrict__ Wt) {
  int t = blockIdx.x * blockDim.x + threadIdx.x;
  if (t >= 512 * 512) return;
  int c = t / 512, k = t % 512;
  float v = (c < 256) ? Wl[k * 256 + c] : Wr[k * 256 + (c - 256)];
  Wt[t] = f2b(v);
}

// ---------------- CSR build ----------------
__global__ __launch_bounds__(256) void k_hist(const int* __restrict__ dst,
                                              int* __restrict__ deg, int E, int N) {
  int t = blockIdx.x * blockDim.x + threadIdx.x;
  if (t < E) atomicAdd(&deg[dst[t]], 1);
  else if (t < E + N) atomicAdd(&deg[t - E], 1);  // self loops
}

__global__ __launch_bounds__(1024) void k_scan(const int* __restrict__ deg,
                                               int* __restrict__ rowptr, int n) {
  __shared__ int tmp[1024];
  __shared__ int carry_s;
  if (threadIdx.x == 0) carry_s = 0;
  __syncthreads();
  for (int base = 0; base < n; base += 1024) {
    int i = base + (int)threadIdx.x;
    int v = (i < n) ? deg[i] : 0;
    tmp[threadIdx.x] = v;
    __syncthreads();
    for (int off = 1; off < 1024; off <<= 1) {
      int t = (threadIdx.x >= off) ? tmp[threadIdx.x - off] : 0;
      __syncthreads();
      tmp[threadIdx.x] += t;
      __syncthreads();
    }
    if (i < n) rowptr[i + 1] = carry_s + tmp[threadIdx.x];
    __syncthreads();
    if (threadIdx.x == 1023) carry_s += tmp[1023];
    __syncthreads();
  }
  if (threadIdx.x == 0) rowptr[0] = 0;
}

__global__ __launch_bounds__(256) void k_scatter(
    const int* __restrict__ src, const int* __restrict__ dst,
    const int* __restrict__ rowptr, int* __restrict__ fill,
    int* __restrict__ csr, int E, int N) {
  int t = blockIdx.x * blockDim.x + threadIdx.x;
  int s, d;
  if (t < E) { s = src[t]; d = dst[t]; }
  else if (t < E + N) { s = t - E; d = t - E; }
  else return;
  int pos = rowptr[d] + atomicAdd(&fill[d], 1);
  csr[pos] = s;
}

// ---------------- bf16 MFMA GEMM: C[M,NC] = A[M,Kp] @ Bt[NC,Kp]^T + bias ----------------
// A bf16 row-major [M][Kp]; Bt bf16 row-major [NC][Kp] (i.e. W transposed);
// bias: col<nhalf -> blo[col] else bhi[col-nhalf]. C fp32.
#define GBM 128
#define GBN 128
#define GBK 32
__device__ __forceinline__ int swzf(int r, int s) {
  return r * 64 + ((s * 16) ^ (((r >> 1) & 3) << 4));
}
__global__ __launch_bounds__(256) void k_gemm_mfma(
    const ushort* __restrict__ A, const ushort* __restrict__ Bt,
    const float* __restrict__ blo, const float* __restrict__ bhi, int nhalf,
    float* __restrict__ C, int M, int Kp, int NC) {
  __shared__ ushort sA[GBM * GBK];
  __shared__ ushort sB[GBN * GBK];
  int tid = threadIdx.x;
  int lane = tid & 63, w = tid >> 6;
  int wr = w >> 1, wc = w & 1;
  int row0 = blockIdx.x * GBM, col0 = blockIdx.y * GBN;
  int nK = Kp / GBK;

  // staging mapping: idx = tid + i*256 -> r = idx>>2, s = idx&3 (16B each)
  int rs = tid >> 2, ss = tid & 3;
  int wO0 = swzf(rs, ss);
  int wO1 = swzf(rs + 64, ss);
  bool okA0 = (row0 + rs) < M;
  bool okA1 = (row0 + rs + 64) < M;
  size_t baseA0 = (size_t)(row0 + rs) * Kp + ss * 8;
  size_t baseA1 = (size_t)(row0 + rs + 64) * Kp + ss * 8;
  size_t baseB0 = (size_t)(col0 + rs) * Kp + ss * 8;
  size_t baseB1 = (size_t)(col0 + rs + 64) * Kp + ss * 8;

  // fragment read offsets
  int fr = lane & 15, kq = lane >> 4;
  int aoff[4], boff[4];
#pragma unroll
  for (int m = 0; m < 4; ++m) {
    int ra = wr * 64 + m * 16 + fr;
    aoff[m] = ra * 64 + ((kq * 16) ^ (((ra >> 1) & 3) << 4));
    int rb = wc * 64 + m * 16 + fr;
    boff[m] = rb * 64 + ((kq * 16) ^ (((rb >> 1) & 3) << 4));
  }

  f32x4 acc[4][4] = {};
  bf16x8 zz = {};
  bf16x8 pa0, pa1, pb0, pb1, qa0, qa1, qb0, qb1;

#define LOADG(KS, RA0, RA1, RB0, RB1)                                   \
  do {                                                                  \
    const ushort* ap = A + (size_t)(KS) * GBK;                          \
    const ushort* bp = Bt + (size_t)(KS) * GBK;                         \
    RA0 = okA0 ? *(const bf16x8*)(ap + baseA0) : zz;                    \
    RA1 = okA1 ? *(const bf16x8*)(ap + baseA1) : zz;                    \
    RB0 = *(const bf16x8*)(bp + baseB0);                                \
    RB1 = *(const bf16x8*)(bp + baseB1);                                \
  } while (0)

#define STAGE(RA0, RA1, RB0, RB1)                                       \
  do {                                                                  \
    *(bf16x8*)((char*)sA + wO0) = RA0;                                  \
    *(bf16x8*)((char*)sA + wO1) = RA1;                                  \
    *(bf16x8*)((char*)sB + wO0) = RB0;                                  \
    *(bf16x8*)((char*)sB + wO1) = RB1;                                  \
  } while (0)

#define COMPUTE()                                                       \
  do {                                                                  \
    bf16x8 av[4], bv[4];                                                \
    _Pragma("unroll") for (int m = 0; m < 4; ++m)                       \
        av[m] = *(const bf16x8*)((const char*)sA + aoff[m]);            \
    _Pragma("unroll") for (int n = 0; n < 4; ++n)                       \
        bv[n] = *(const bf16x8*)((const char*)sB + boff[n]);            \
    _Pragma("unroll") for (int m = 0; m < 4; ++m)                       \
        _Pragma("unroll") for (int n = 0; n < 4; ++n)                   \
            acc[m][n] = __builtin_amdgcn_mfma_f32_16x16x32_bf16(        \
                av[m], bv[n], acc[m][n], 0, 0, 0);                      \
  } while (0)

  LOADG(0, pa0, pa1, pb0, pb1);
  for (int ks = 0; ks < nK; ++ks) {
    __syncthreads();
    if (ks & 1) {
      STAGE(qa0, qa1, qb0, qb1);
      if (ks + 1 < nK) LOADG(ks + 1, pa0, pa1, pb0, pb1);
    } else {
      STAGE(pa0, pa1, pb0, pb1);
      if (ks + 1 < nK) LOADG(ks + 1, qa0, qa1, qb0, qb1);
    }
    __syncthreads();
    COMPUTE();
  }

  // epilogue: C/D layout col=lane&15, row=(lane>>4)*4+j (m89-verified)
#pragma unroll
  for (int m = 0; m < 4; ++m) {
#pragma unroll
    for (int n = 0; n < 4; ++n) {
      int grow = row0 + wr * 64 + m * 16 + kq * 4;
      int gcol = col0 + wc * 64 + n * 16 + fr;
      float bv = (gcol < nhalf) ? blo[gcol] : bhi[gcol - nhalf];
#pragma unroll
      for (int j = 0; j < 4; ++j) {
        if (grow + j < M) C[(size_t)(grow + j) * NC + gcol] = acc[m][n][j] + bv;
      }
    }
  }
#undef LOADG
#undef STAGE
#undef COMPUTE
}

// ---------------- GAT layer 1 aggregate (H=4, C=128) + bias + LN + ELU -> bf16 ----------------
// xlr: [N][1024] fp32, cols 0..511 = xl, 512..1023 = xr. out: [N][512] bf16.
__global__ __launch_bounds__(256) void k_gat1(
    const float* __restrict__ xlr,
    const int* __restrict__ rowptr, const int* __restrict__ csr,
    const float* __restrict__ att, const float* __restrict__ bias,
    const float* __restrict__ lng, const float* __restrict__ lnb,
    ushort* __restrict__ out, int n) {
  int wid = (blockIdx.x * blockDim.x + threadIdx.x) >> 6;
  int lane = threadIdx.x & 63;
  if (wid >= n) return;
  int base = lane * 8;
  float xrv[8], attv[8];
  {
    const float* p = &xlr[(size_t)wid * 1024 + 512 + base];
    float4 t0 = *(const float4*)p;
    float4 t1 = *(const float4*)(p + 4);
    xrv[0] = t0.x; xrv[1] = t0.y; xrv[2] = t0.z; xrv[3] = t0.w;
    xrv[4] = t1.x; xrv[5] = t1.y; xrv[6] = t1.z; xrv[7] = t1.w;
    const float* ap = &att[(lane >> 4) * 128 + (lane & 15) * 8];
    float4 u0 = *(const float4*)ap;
    float4 u1 = *(const float4*)(ap + 4);
    attv[0] = u0.x; attv[1] = u0.y; attv[2] = u0.z; attv[3] = u0.w;
    attv[4] = u1.x; attv[5] = u1.y; attv[6] = u1.z; attv[7] = u1.w;
  }
  float m = -INFINITY, s = 0.f;
  float acc[8] = {};
  int e0 = rowptr[wid], e1 = rowptr[wid + 1];
  for (int p = e0; p < e1; ++p) {
    int src = csr[p];
    const float* vp = &xlr[(size_t)src * 1024 + base];
    float4 v0 = *(const float4*)vp;
    float4 v1 = *(const float4*)(vp + 4);
    float v[8] = {v0.x, v0.y, v0.z, v0.w, v1.x, v1.y, v1.z, v1.w};
    float pe = 0.f;
#pragma unroll
    for (int j = 0; j < 8; ++j) {
      float t = v[j] + xrv[j];
      t = t > 0.f ? t : 0.2f * t;
      pe += t * attv[j];
    }
    pe += __shfl_xor(pe, 1);
    pe += __shfl_xor(pe, 2);
    pe += __shfl_xor(pe, 4);
    pe += __shfl_xor(pe, 8);
    if (pe <= m) {
      float w = __expf(pe - m);
      s += w;
#pragma unroll
      for (int j = 0; j < 8; ++j) acc[j] += w * v[j];
    } else {
      float sc = __expf(m - pe);
      s = s * sc + 1.f;
#pragma unroll
      for (int j = 0; j < 8; ++j) acc[j] = acc[j] * sc + v[j];
      m = pe;
    }
  }
  float inv = 1.f / (s + 1e-16f);
  float o[8];
#pragma unroll
  for (int j = 0; j < 8; ++j) o[j] = acc[j] * inv + bias[base + j];
  float sum = 0.f, sq = 0.f;
#pragma unroll
  for (int j = 0; j < 8; ++j) { sum += o[j]; sq += o[j] * o[j]; }
#pragma unroll
  for (int off = 1; off < 64; off <<= 1) {
    sum += __shfl_xor(sum, off);
    sq += __shfl_xor(sq, off);
  }
  float mean = sum * (1.f / 512.f);
  float var = fmaxf(sq * (1.f / 512.f) - mean * mean, 0.f);
  float rstd = rsqrtf(var + 1e-5f);
  bf16x8 ov;
#pragma unroll
  for (int j = 0; j < 8; ++j) {
    float y = (o[j] - mean) * rstd * lng[base + j] + lnb[base + j];
    y = y > 0.f ? y : __expf(y) - 1.f;   // ELU
    ov[j] = (short)f2b(y);
  }
  *(bf16x8*)&out[(size_t)wid * 512 + base] = ov;
}

// ---------------- GAT layer 2 aggregate (H=1, C=256) + bias + LN + ELU ----------------
// xlr: [N][512] fp32, cols 0..255 = xl, 256..511 = xr. out fp32 [N][256].
__global__ __launch_bounds__(256) void k_gat2(
    const float* __restrict__ xlr,
    const int* __restrict__ rowptr, const int* __restrict__ csr,
    const float* __restrict__ att, const float* __restrict__ bias,
    const float* __restrict__ lng, const float* __restrict__ lnb,
    float* __restrict__ out, int n) {
  int wid = (blockIdx.x * blockDim.x + threadIdx.x) >> 6;
  int lane = threadIdx.x & 63;
  if (wid >= n) return;
  int base = lane * 4;
  float4 xr4 = *(const float4*)&xlr[(size_t)wid * 512 + 256 + base];
  float xrv[4] = {xr4.x, xr4.y, xr4.z, xr4.w};
  float4 at4 = *(const float4*)&att[base];
  float attv[4] = {at4.x, at4.y, at4.z, at4.w};
  float m = -INFINITY, s = 0.f;
  float acc[4] = {};
  int e0 = rowptr[wid], e1 = rowptr[wid + 1];
  for (int p = e0; p < e1; ++p) {
    int src = csr[p];
    float4 v4 = *(const float4*)&xlr[(size_t)src * 512 + base];
    float v[4] = {v4.x, v4.y, v4.z, v4.w};
    float pe = 0.f;
#pragma unroll
    for (int j = 0; j < 4; ++j) {
      float t = v[j] + xrv[j];
      t = t > 0.f ? t : 0.2f * t;
      pe += t * attv[j];
    }
#pragma unroll
    for (int off = 1; off < 64; off <<= 1) pe += __shfl_xor(pe, off);
    if (pe <= m) {
      float w = __expf(pe - m);
      s += w;
#pragma unroll
      for (int j = 0; j < 4; ++j) acc[j] += w * v[j];
    } else {
      float sc = __expf(m - pe);
      s = s * sc + 1.f;
#pragma unroll
      for (int j = 0; j < 4; ++j) acc[j] = acc[j] * sc + v[j];
      m = pe;
    }
  }
  float inv = 1.f / (s + 1e-16f);
  float o[4];
#pragma unroll
  for (int j = 0; j < 4; ++j) o[j] = acc[j] * inv + bias[base + j];
  float sum = 0.f, sq = 0.f;
#pragma unroll
  for (int j = 0; j < 4; ++j) { sum += o[j]; sq += o[j] * o[j]; }
#pragma unroll
  for (int off = 1; off < 64; off <<= 1) {
    sum += __shfl_xor(sum, off);
    sq += __shfl_xor(sq, off);
  }
  float mean = sum * (1.f / 256.f);
  float var = fmaxf(sq * (1.f / 256.f) - mean * mean, 0.f);
  float rstd = rsqrtf(var + 1e-5f);
#pragma unroll
  for (int j = 0; j < 4; ++j) {
    float y = (o[j] - mean) * rstd * lng[base + j] + lnb[base + j];
    y = y > 0.f ? y : __expf(y) - 1.f;
    out[(size_t)wid * 256 + base + j] = y;
  }
}

// ---------------- pooling (batch is sorted) ----------------
__global__ __launch_bounds__(256) void k_pool(
    const float* __restrict__ h2, const int* __restrict__ batch,
    float* __restrict__ pooled, int* __restrict__ cnt, int n) {
  int c = threadIdx.x;  // 256 channels
  int n0 = blockIdx.x * 256;
  int n1 = min(n0 + 256, n);
  if (n0 >= n) return;
  float acc = 0.f;
  int cur = batch[n0];
  int cl = 0;
  for (int i = n0; i < n1; ++i) {
    int bb = batch[i];
    if (bb != cur) {
      atomicAdd(&pooled[cur * 256 + c], acc);
      if (c == 0) atomicAdd(&cnt[cur], cl);
      acc = 0.f; cl = 0; cur = bb;
    }
    acc += h2[(size_t)i * 256 + c];
    cl++;
  }
  atomicAdd(&pooled[cur * 256 + c], acc);
  if (c == 0) atomicAdd(&cnt[cur], cl);
}

// ---------------- projection head ----------------
__global__ __launch_bounds__(512) void k_proj1(
    const float* __restrict__ pooled, const int* __restrict__ cnt,
    const float* __restrict__ W, const float* __restrict__ b,
    const float* __restrict__ lng, const float* __restrict__ lnb,
    float* __restrict__ hout) {
  __shared__ float row[256];
  __shared__ float red[16];
  int g = blockIdx.x, c = threadIdx.x;
  if (c < 256) {
    float cc = fmaxf((float)cnt[g], 1.f);
    row[c] = pooled[g * 256 + c] / cc;
  }
  __syncthreads();
  float acc = b[c];
#pragma unroll 4
  for (int k = 0; k < 256; ++k) acc += row[k] * W[k * 512 + c];
  float sum = acc, sq = acc * acc;
#pragma unroll
  for (int off = 1; off < 64; off <<= 1) {
    sum += __shfl_xor(sum, off);
    sq += __shfl_xor(sq, off);
  }
  int wv = threadIdx.x >> 6;
  if ((threadIdx.x & 63) == 0) { red[wv] = sum; red[8 + wv] = sq; }
  __syncthreads();
  float S = 0.f, Q = 0.f;
#pragma unroll
  for (int t = 0; t < 8; ++t) { S += red[t]; Q += red[8 + t]; }
  float mean = S * (1.f / 512.f);
  float var = fmaxf(Q * (1.f / 512.f) - mean * mean, 0.f);
  float rstd = rsqrtf(var + 1e-5f);
  float y = (acc - mean) * rstd * lng[c] + lnb[c];
  float ge = 0.5f * y * (1.f + erff(y * 0.70710678118654752f));  // exact gelu
  hout[g * 512 + c] = ge;
}

__global__ __launch_bounds__(512) void k_proj2(
    const float* __restrict__ h, const float* __restrict__ W,
    const float* __restrict__ b, float* __restrict__ out) {
  __shared__ float row[512];
  __shared__ float red[8];
  int g = blockIdx.x, c = threadIdx.x;
  row[c] = h[g * 512 + c];
  __syncthreads();
  float acc = b[c];
#pragma unroll 4
  for (int k = 0; k < 512; ++k) acc += row[k] * W[k * 512 + c];
  float sq = acc * acc;
#pragma unroll
  for (int off = 1; off < 64; off <<= 1) sq += __shfl_xor(sq, off);
  int wv = threadIdx.x >> 6;
  if ((threadIdx.x & 63) == 0) red[wv] = sq;
  __syncthreads();
  float S = 0.f;
#pragma unroll
  for (int t = 0; t < 8; ++t) S += red[t];
  float norm = fmaxf(sqrtf(S), 1e-12f);
  out[g * 512 + c] = acc / norm;
}

// ---------------- launch ----------------
extern "C" void kernel_launch(void* const* d_in, const int* in_sizes, int n_in,
                              void* d_out, int out_size, void* d_ws, size_t ws_size,
                              hipStream_t stream) {
  const float* x_cont = (const float*)d_in[0];
  const int* x_class  = (const int*)d_in[1];
  const int* x_pitch  = (const int*)d_in[2];
  const int* ei       = (const int*)d_in[3];
  const int* batch    = (const int*)d_in[4];
  const float* ctab = (const float*)d_in[5];
  const float* ptab = (const float*)d_in[6];
  const float* Wl1 = (const float*)d_in[7];
  const float* bl1 = (const float*)d_in[8];
  const float* Wr1 = (const float*)d_in[9];
  const float* br1 = (const float*)d_in[10];
  const float* att1 = (const float*)d_in[11];
  const float* bias1 = (const float*)d_in[12];
  const float* ln1g = (const float*)d_in[13];
  const float* ln1b = (const float*)d_in[14];
  const float* Wl2 = (const float*)d_in[15];
  const float* bl2 = (const float*)d_in[16];
  const float* Wr2 = (const float*)d_in[17];
  const float* br2 = (const float*)d_in[18];
  const float* att2 = (const float*)d_in[19];
  const float* bias2 = (const float*)d_in[20];
  const float* ln2g = (const float*)d_in[21];
  const float* ln2b = (const float*)d_in[22];
  const float* Wp1 = (const float*)d_in[23];
  const float* bp1 = (const float*)d_in[24];
  const float* lnpg = (const float*)d_in[25];
  const float* lnpb = (const float*)d_in[26];
  const float* Wp2 = (const float*)d_in[27];
  const float* bp2 = (const float*)d_in[28];
  float* out = (float*)d_out;
  (void)n_in; (void)out_size; (void)ws_size;

  int N = in_sizes[1];
  int E = in_sizes[3] / 2;
  int ET = E + N;

  // ---- workspace layout (with aliasing) ----
  char* p = (char*)d_ws;
  ushort* xb   = (ushort*)p; p += (size_t)N * 160 * 2;   // bf16 features, dead after GEMM1
  ushort* W1t  = (ushort*)p; p += (size_t)1024 * 160 * 2;
  ushort* W2t  = (ushort*)p; p += (size_t)512 * 512 * 2;
  float*  xlr1 = (float*)p;  p += (size_t)N * 1024 * 4;  // also xlr2 (GEMM2 out)
  ushort* h1b  = (ushort*)p; p += (size_t)N * 512 * 2;   // also h2 (fp32 N*256, same bytes)
  float* pooled = (float*)p; p += (size_t)NG * 256 * 4;
  int* cnt     = (int*)p;    p += NG * 4;
  float* hproj = (float*)p;  p += (size_t)NG * 512 * 4;
  int* deg     = (int*)p;    p += (size_t)N * 4;
  int* fill    = (int*)p;    p += (size_t)N * 4;
  int* rowptr  = (int*)p;    p += (size_t)(N + 1) * 4;
  int* csr     = (int*)p;    p += (size_t)ET * 4;
  float* xlr2 = xlr1;
  float* h2   = (float*)h1b;

  const int* esrc = ei;
  const int* edst = ei + E;

  hipMemsetAsync(deg, 0, (size_t)2 * N * sizeof(int), stream);
  hipMemsetAsync(pooled, 0, (size_t)NG * 256 * sizeof(float) + NG * sizeof(int), stream);

  k_build_xb<<<cdiv(N * 160, 256), 256, 0, stream>>>(x_cont, x_class, x_pitch, ctab, ptab, xb, N);
  k_prep_w1<<<cdiv(1024 * 160, 256), 256, 0, stream>>>(Wl1, Wr1, W1t);
  k_prep_w2<<<cdiv(512 * 512, 256), 256, 0, stream>>>(Wl2, Wr2, W2t);
  k_hist<<<cdiv(ET, 256), 256, 0, stream>>>(edst, deg, E, N);
  k_scan<<<1, 1024, 0, stream>>>(deg, rowptr, N);
  k_scatter<<<cdiv(ET, 256), 256, 0, stream>>>(esrc, edst, rowptr, fill, csr, E, N);

  dim3 g1(cdiv(N, GBM), 1024 / GBN);
  k_gemm_mfma<<<g1, 256, 0, stream>>>(xb, W1t, bl1, br1, 512, xlr1, N, 160, 1024);
  k_gat1<<<cdiv(N * 64, 256), 256, 0, stream>>>(xlr1, rowptr, csr, att1, bias1, ln1g, ln1b, h1b, N);

  dim3 g2(cdiv(N, GBM), 512 / GBN);
  k_gemm_mfma<<<g2, 256, 0, stream>>>(h1b, W2t, bl2, br2, 256, xlr2, N, 512, 512);
  k_gat2<<<cdiv(N * 64, 256), 256, 0, stream>>>(xlr2, rowptr, csr, att2, bias2, ln2g, ln2b, h2, N);

  k_pool<<<cdiv(N, 256), 256, 0, stream>>>(h2, batch, pooled, cnt, N);
  k_proj1<<<NG, 512, 0, stream>>>(pooled, cnt, Wp1, bp1, lnpg, lnpb, hproj);
  k_proj2<<<NG, 512, 0, stream>>>(hproj, Wp2, bp2, out);
}

// Round 3
// 520.930 us; speedup vs baseline: 1.9805x; 1.1165x over previous
//
#include <hip/hip_runtime.h>
#include <math.h>

#define NG 64   // graphs

typedef short bf16x8 __attribute__((ext_vector_type(8)));
typedef short bf16x4 __attribute__((ext_vector_type(4)));
typedef float f32x4 __attribute__((ext_vector_type(4)));

static inline int cdiv(int a, int b) { return (a + b - 1) / b; }

__device__ inline ushort f2b(float f) {
  union { float f; uint u; } v; v.f = f;
  uint u = v.u;
  return (ushort)((u + 0x7fffu + ((u >> 16) & 1u)) >> 16);
}
__device__ inline float b2f(ushort h) {
  union { uint u; float f; } v; v.u = ((uint)h) << 16;
  return v.f;
}

// ---------------- feature build (bf16, K padded to 160) ----------------
__global__ __launch_bounds__(256) void k_build_xb(
    const float* __restrict__ xc, const int* __restrict__ xcl,
    const int* __restrict__ xpi, const float* __restrict__ ctab,
    const float* __restrict__ ptab, ushort* __restrict__ x, int n) {
  int t = blockIdx.x * blockDim.x + threadIdx.x;
  int total = n * 160;
  if (t >= total) return;
  int node = t / 160, c = t % 160;
  float v;
  if (c < 6)        v = xc[node * 6 + c];
  else if (c < 70)  v = ctab[xcl[node] * 64 + (c - 6)];
  else if (c < 134) v = ptab[xpi[node] * 64 + (c - 70)];
  else              v = 0.f;
  x[t] = f2b(v);
}

// ---------------- weight prep: transpose + concat + pad, fp32 -> bf16 ----------------
__global__ __launch_bounds__(256) void k_prep_w1(
    const float* __restrict__ Wl, const float* __restrict__ Wr,
    ushort* __restrict__ Wt) {
  int t = blockIdx.x * blockDim.x + threadIdx.x;
  if (t >= 1024 * 160) return;
  int c = t / 160, k = t % 160;
  float v = 0.f;
  if (k < 134) v = (c < 512) ? Wl[k * 512 + c] : Wr[k * 512 + (c - 512)];
  Wt[t] = f2b(v);
}
__global__ __launch_bounds__(256) void k_prep_w2(
    const float* __restrict__ Wl, const float* __restrict__ Wr,
    ushort* __restrict__ Wt) {
  int t = blockIdx.x * blockDim.x + threadIdx.x;
  if (t >= 512 * 512) return;
  int c = t / 512, k = t % 512;
  float v = (c < 256) ? Wl[k * 256 + c] : Wr[k * 256 + (c - 256)];
  Wt[t] = f2b(v);
}

// ---------------- CSR build ----------------
__global__ __launch_bounds__(256) void k_hist(const int* __restrict__ dst,
                                              int* __restrict__ deg, int E, int N) {
  int t = blockIdx.x * blockDim.x + threadIdx.x;
  if (t < E) atomicAdd(&deg[dst[t]], 1);
  else if (t < E + N) atomicAdd(&deg[t - E], 1);  // self loops
}

__global__ __launch_bounds__(1024) void k_scan(const int* __restrict__ deg,
                                               int* __restrict__ rowptr, int n) {
  __shared__ int tmp[1024];
  __shared__ int carry_s;
  if (threadIdx.x == 0) carry_s = 0;
  __syncthreads();
  for (int base = 0; base < n; base += 1024) {
    int i = base + (int)threadIdx.x;
    int v = (i < n) ? deg[i] : 0;
    tmp[threadIdx.x] = v;
    __syncthreads();
    for (int off = 1; off < 1024; off <<= 1) {
      int t = (threadIdx.x >= off) ? tmp[threadIdx.x - off] : 0;
      __syncthreads();
      tmp[threadIdx.x] += t;
      __syncthreads();
    }
    if (i < n) rowptr[i + 1] = carry_s + tmp[threadIdx.x];
    __syncthreads();
    if (threadIdx.x == 1023) carry_s += tmp[1023];
    __syncthreads();
  }
  if (threadIdx.x == 0) rowptr[0] = 0;
}

__global__ __launch_bounds__(256) void k_scatter(
    const int* __restrict__ src, const int* __restrict__ dst,
    const int* __restrict__ rowptr, int* __restrict__ fill,
    int* __restrict__ csr, int E, int N) {
  int t = blockIdx.x * blockDim.x + threadIdx.x;
  int s, d;
  if (t < E) { s = src[t]; d = dst[t]; }
  else if (t < E + N) { s = t - E; d = t - E; }
  else return;
  int pos = rowptr[d] + atomicAdd(&fill[d], 1);
  csr[pos] = s;
}

// ---------------- bf16 MFMA GEMM: C[M,NC] = A[M,Kp] @ Bt[NC,Kp]^T + bias -> bf16 ----------------
#define GBM 128
#define GBN 128
#define GBK 32
__device__ __forceinline__ int swzf(int r, int s) {
  return r * 64 + ((s * 16) ^ (((r >> 1) & 3) << 4));
}
__global__ __launch_bounds__(256) void k_gemm_mfma(
    const ushort* __restrict__ A, const ushort* __restrict__ Bt,
    const float* __restrict__ blo, const float* __restrict__ bhi, int nhalf,
    ushort* __restrict__ C, int M, int Kp, int NC) {
  __shared__ ushort sA[GBM * GBK];
  __shared__ ushort sB[GBN * GBK];
  int tid = threadIdx.x;
  int lane = tid & 63, w = tid >> 6;
  int wr = w >> 1, wc = w & 1;
  int row0 = blockIdx.x * GBM, col0 = blockIdx.y * GBN;
  int nK = Kp / GBK;

  int rs = tid >> 2, ss = tid & 3;
  int wO0 = swzf(rs, ss);
  int wO1 = swzf(rs + 64, ss);
  bool okA0 = (row0 + rs) < M;
  bool okA1 = (row0 + rs + 64) < M;
  size_t baseA0 = (size_t)(row0 + rs) * Kp + ss * 8;
  size_t baseA1 = (size_t)(row0 + rs + 64) * Kp + ss * 8;
  size_t baseB0 = (size_t)(col0 + rs) * Kp + ss * 8;
  size_t baseB1 = (size_t)(col0 + rs + 64) * Kp + ss * 8;

  int fr = lane & 15, kq = lane >> 4;
  int aoff[4], boff[4];
#pragma unroll
  for (int m = 0; m < 4; ++m) {
    int ra = wr * 64 + m * 16 + fr;
    aoff[m] = ra * 64 + ((kq * 16) ^ (((ra >> 1) & 3) << 4));
    int rb = wc * 64 + m * 16 + fr;
    boff[m] = rb * 64 + ((kq * 16) ^ (((rb >> 1) & 3) << 4));
  }

  f32x4 acc[4][4] = {};
  bf16x8 zz = {};
  bf16x8 pa0, pa1, pb0, pb1, qa0, qa1, qb0, qb1;

#define LOADG(KS, RA0, RA1, RB0, RB1)                                   \
  do {                                                                  \
    const ushort* ap = A + (size_t)(KS) * GBK;                          \
    const ushort* bp = Bt + (size_t)(KS) * GBK;                         \
    RA0 = okA0 ? *(const bf16x8*)(ap + baseA0) : zz;                    \
    RA1 = okA1 ? *(const bf16x8*)(ap + baseA1) : zz;                    \
    RB0 = *(const bf16x8*)(bp + baseB0);                                \
    RB1 = *(const bf16x8*)(bp + baseB1);                                \
  } while (0)

#define STAGE(RA0, RA1, RB0, RB1)                                       \
  do {                                                                  \
    *(bf16x8*)((char*)sA + wO0) = RA0;                                  \
    *(bf16x8*)((char*)sA + wO1) = RA1;                                  \
    *(bf16x8*)((char*)sB + wO0) = RB0;                                  \
    *(bf16x8*)((char*)sB + wO1) = RB1;                                  \
  } while (0)

#define COMPUTE()                                                       \
  do {                                                                  \
    bf16x8 av[4], bv[4];                                                \
    _Pragma("unroll") for (int m = 0; m < 4; ++m)                       \
        av[m] = *(const bf16x8*)((const char*)sA + aoff[m]);            \
    _Pragma("unroll") for (int n = 0; n < 4; ++n)                       \
        bv[n] = *(const bf16x8*)((const char*)sB + boff[n]);            \
    _Pragma("unroll") for (int m = 0; m < 4; ++m)                       \
        _Pragma("unroll") for (int n = 0; n < 4; ++n)                   \
            acc[m][n] = __builtin_amdgcn_mfma_f32_16x16x32_bf16(        \
                av[m], bv[n], acc[m][n], 0, 0, 0);                      \
  } while (0)

  LOADG(0, pa0, pa1, pb0, pb1);
  for (int ks = 0; ks < nK; ++ks) {
    __syncthreads();
    if (ks & 1) {
      STAGE(qa0, qa1, qb0, qb1);
      if (ks + 1 < nK) LOADG(ks + 1, pa0, pa1, pb0, pb1);
    } else {
      STAGE(pa0, pa1, pb0, pb1);
      if (ks + 1 < nK) LOADG(ks + 1, qa0, qa1, qb0, qb1);
    }
    __syncthreads();
    COMPUTE();
  }

  // epilogue -> bf16 (C/D layout: col=lane&15, row=(lane>>4)*4+j)
#pragma unroll
  for (int m = 0; m < 4; ++m) {
#pragma unroll
    for (int n = 0; n < 4; ++n) {
      int grow = row0 + wr * 64 + m * 16 + kq * 4;
      int gcol = col0 + wc * 64 + n * 16 + fr;
      float bv = (gcol < nhalf) ? blo[gcol] : bhi[gcol - nhalf];
#pragma unroll
      for (int j = 0; j < 4; ++j) {
        if (grow + j < M) C[(size_t)(grow + j) * NC + gcol] = f2b(acc[m][n][j] + bv);
      }
    }
  }
#undef LOADG
#undef STAGE
#undef COMPUTE
}

// ---------------- GAT layer 1 aggregate (H=4, C=128) + bias + LN + ELU -> bf16 ----------------
// xlr: [N][1024] bf16, cols 0..511 = xl, 512..1023 = xr. out: [N][512] bf16.
__global__ __launch_bounds__(256) void k_gat1(
    const ushort* __restrict__ xlr,
    const int* __restrict__ rowptr, const int* __restrict__ csr,
    const float* __restrict__ att, const float* __restrict__ bias,
    const float* __restrict__ lng, const float* __restrict__ lnb,
    ushort* __restrict__ out, int n) {
  int wid = (blockIdx.x * blockDim.x + threadIdx.x) >> 6;
  int lane = threadIdx.x & 63;
  if (wid >= n) return;
  int base = lane * 8;
  float xrv[8], attv[8];
  {
    bf16x8 t = *(const bf16x8*)&xlr[(size_t)wid * 1024 + 512 + base];
#pragma unroll
    for (int j = 0; j < 8; ++j) xrv[j] = b2f((ushort)t[j]);
    const float* ap = &att[(lane >> 4) * 128 + (lane & 15) * 8];
    float4 u0 = *(const float4*)ap;
    float4 u1 = *(const float4*)(ap + 4);
    attv[0] = u0.x; attv[1] = u0.y; attv[2] = u0.z; attv[3] = u0.w;
    attv[4] = u1.x; attv[5] = u1.y; attv[6] = u1.z; attv[7] = u1.w;
  }
  float m = -INFINITY, s = 0.f;
  float acc[8] = {};
  int e0 = rowptr[wid], e1 = rowptr[wid + 1];
  for (int p = e0; p < e1; ++p) {
    int src = csr[p];
    bf16x8 vb = *(const bf16x8*)&xlr[(size_t)src * 1024 + base];
    float v[8];
#pragma unroll
    for (int j = 0; j < 8; ++j) v[j] = b2f((ushort)vb[j]);
    float pe = 0.f;
#pragma unroll
    for (int j = 0; j < 8; ++j) {
      float t = v[j] + xrv[j];
      t = t > 0.f ? t : 0.2f * t;
      pe += t * attv[j];
    }
    pe += __shfl_xor(pe, 1);
    pe += __shfl_xor(pe, 2);
    pe += __shfl_xor(pe, 4);
    pe += __shfl_xor(pe, 8);
    if (pe <= m) {
      float w = __expf(pe - m);
      s += w;
#pragma unroll
      for (int j = 0; j < 8; ++j) acc[j] += w * v[j];
    } else {
      float sc = __expf(m - pe);
      s = s * sc + 1.f;
#pragma unroll
      for (int j = 0; j < 8; ++j) acc[j] = acc[j] * sc + v[j];
      m = pe;
    }
  }
  float inv = 1.f / (s + 1e-16f);
  float o[8];
#pragma unroll
  for (int j = 0; j < 8; ++j) o[j] = acc[j] * inv + bias[base + j];
  float sum = 0.f, sq = 0.f;
#pragma unroll
  for (int j = 0; j < 8; ++j) { sum += o[j]; sq += o[j] * o[j]; }
#pragma unroll
  for (int off = 1; off < 64; off <<= 1) {
    sum += __shfl_xor(sum, off);
    sq += __shfl_xor(sq, off);
  }
  float mean = sum * (1.f / 512.f);
  float var = fmaxf(sq * (1.f / 512.f) - mean * mean, 0.f);
  float rstd = rsqrtf(var + 1e-5f);
  bf16x8 ov;
#pragma unroll
  for (int j = 0; j < 8; ++j) {
    float y = (o[j] - mean) * rstd * lng[base + j] + lnb[base + j];
    y = y > 0.f ? y : __expf(y) - 1.f;   // ELU
    ov[j] = (short)f2b(y);
  }
  *(bf16x8*)&out[(size_t)wid * 512 + base] = ov;
}

// ---------------- GAT layer 2 aggregate (H=1, C=256) + bias + LN + ELU ----------------
// xlr: [N][512] bf16, cols 0..255 = xl, 256..511 = xr. out fp32 [N][256].
__global__ __launch_bounds__(256) void k_gat2(
    const ushort* __restrict__ xlr,
    const int* __restrict__ rowptr, const int* __restrict__ csr,
    const float* __restrict__ att, const float* __restrict__ bias,
    const float* __restrict__ lng, const float* __restrict__ lnb,
    float* __restrict__ out, int n) {
  int wid = (blockIdx.x * blockDim.x + threadIdx.x) >> 6;
  int lane = threadIdx.x & 63;
  if (wid >= n) return;
  int base = lane * 4;
  float xrv[4], attv[4];
  {
    bf16x4 t = *(const bf16x4*)&xlr[(size_t)wid * 512 + 256 + base];
#pragma unroll
    for (int j = 0; j < 4; ++j) xrv[j] = b2f((ushort)t[j]);
    float4 at4 = *(const float4*)&att[base];
    attv[0] = at4.x; attv[1] = at4.y; attv[2] = at4.z; attv[3] = at4.w;
  }
  float m = -INFINITY, s = 0.f;
  float acc[4] = {};
  int e0 = rowptr[wid], e1 = rowptr[wid + 1];
  for (int p = e0; p < e1; ++p) {
    int src = csr[p];
    bf16x4 vb = *(const bf16x4*)&xlr[(size_t)src * 512 + base];
    float v[4];
#pragma unroll
    for (int j = 0; j < 4; ++j) v[j] = b2f((ushort)vb[j]);
    float pe = 0.f;
#pragma unroll
    for (int j = 0; j < 4; ++j) {
      float t = v[j] + xrv[j];
      t = t > 0.f ? t : 0.2f * t;
      pe += t * attv[j];
    }
#pragma unroll
    for (int off = 1; off < 64; off <<= 1) pe += __shfl_xor(pe, off);
    if (pe <= m) {
      float w = __expf(pe - m);
      s += w;
#pragma unroll
      for (int j = 0; j < 4; ++j) acc[j] += w * v[j];
    } else {
      float sc = __expf(m - pe);
      s = s * sc + 1.f;
#pragma unroll
      for (int j = 0; j < 4; ++j) acc[j] = acc[j] * sc + v[j];
      m = pe;
    }
  }
  float inv = 1.f / (s + 1e-16f);
  float o[4];
#pragma unroll
  for (int j = 0; j < 4; ++j) o[j] = acc[j] * inv + bias[base + j];
  float sum = 0.f, sq = 0.f;
#pragma unroll
  for (int j = 0; j < 4; ++j) { sum += o[j]; sq += o[j] * o[j]; }
#pragma unroll
  for (int off = 1; off < 64; off <<= 1) {
    sum += __shfl_xor(sum, off);
    sq += __shfl_xor(sq, off);
  }
  float mean = sum * (1.f / 256.f);
  float var = fmaxf(sq * (1.f / 256.f) - mean * mean, 0.f);
  float rstd = rsqrtf(var + 1e-5f);
#pragma unroll
  for (int j = 0; j < 4; ++j) {
    float y = (o[j] - mean) * rstd * lng[base + j] + lnb[base + j];
    y = y > 0.f ? y : __expf(y) - 1.f;
    out[(size_t)wid * 256 + base + j] = y;
  }
}

// ---------------- pooling (batch is sorted) ----------------
__global__ __launch_bounds__(256) void k_pool(
    const float* __restrict__ h2, const int* __restrict__ batch,
    float* __restrict__ pooled, int* __restrict__ cnt, int n) {
  int c = threadIdx.x;  // 256 channels
  int n0 = blockIdx.x * 256;
  int n1 = min(n0 + 256, n);
  if (n0 >= n) return;
  float acc = 0.f;
  int cur = batch[n0];
  int cl = 0;
  for (int i = n0; i < n1; ++i) {
    int bb = batch[i];
    if (bb != cur) {
      atomicAdd(&pooled[cur * 256 + c], acc);
      if (c == 0) atomicAdd(&cnt[cur], cl);
      acc = 0.f; cl = 0; cur = bb;
    }
    acc += h2[(size_t)i * 256 + c];
    cl++;
  }
  atomicAdd(&pooled[cur * 256 + c], acc);
  if (c == 0) atomicAdd(&cnt[cur], cl);
}

// ---------------- projection head ----------------
__global__ __launch_bounds__(512) void k_proj1(
    const float* __restrict__ pooled, const int* __restrict__ cnt,
    const float* __restrict__ W, const float* __restrict__ b,
    const float* __restrict__ lng, const float* __restrict__ lnb,
    float* __restrict__ hout) {
  __shared__ float row[256];
  __shared__ float red[16];
  int g = blockIdx.x, c = threadIdx.x;
  if (c < 256) {
    float cc = fmaxf((float)cnt[g], 1.f);
    row[c] = pooled[g * 256 + c] / cc;
  }
  __syncthreads();
  float acc = b[c];
#pragma unroll 4
  for (int k = 0; k < 256; ++k) acc += row[k] * W[k * 512 + c];
  float sum = acc, sq = acc * acc;
#pragma unroll
  for (int off = 1; off < 64; off <<= 1) {
    sum += __shfl_xor(sum, off);
    sq += __shfl_xor(sq, off);
  }
  int wv = threadIdx.x >> 6;
  if ((threadIdx.x & 63) == 0) { red[wv] = sum; red[8 + wv] = sq; }
  __syncthreads();
  float S = 0.f, Q = 0.f;
#pragma unroll
  for (int t = 0; t < 8; ++t) { S += red[t]; Q += red[8 + t]; }
  float mean = S * (1.f / 512.f);
  float var = fmaxf(Q * (1.f / 512.f) - mean * mean, 0.f);
  float rstd = rsqrtf(var + 1e-5f);
  float y = (acc - mean) * rstd * lng[c] + lnb[c];
  float ge = 0.5f * y * (1.f + erff(y * 0.70710678118654752f));  // exact gelu
  hout[g * 512 + c] = ge;
}

__global__ __launch_bounds__(512) void k_proj2(
    const float* __restrict__ h, const float* __restrict__ W,
    const float* __restrict__ b, float* __restrict__ out) {
  __shared__ float row[512];
  __shared__ float red[8];
  int g = blockIdx.x, c = threadIdx.x;
  row[c] = h[g * 512 + c];
  __syncthreads();
  float acc = b[c];
#pragma unroll 4
  for (int k = 0; k < 512; ++k) acc += row[k] * W[k * 512 + c];
  float sq = acc * acc;
#pragma unroll
  for (int off = 1; off < 64; off <<= 1) sq += __shfl_xor(sq, off);
  int wv = threadIdx.x >> 6;
  if ((threadIdx.x & 63) == 0) red[wv] = sq;
  __syncthreads();
  float S = 0.f;
#pragma unroll
  for (int t = 0; t < 8; ++t) S += red[t];
  float norm = fmaxf(sqrtf(S), 1e-12f);
  out[g * 512 + c] = acc / norm;
}

// ---------------- launch ----------------
extern "C" void kernel_launch(void* const* d_in, const int* in_sizes, int n_in,
                              void* d_out, int out_size, void* d_ws, size_t ws_size,
                              hipStream_t stream) {
  const float* x_cont = (const float*)d_in[0];
  const int* x_class  = (const int*)d_in[1];
  const int* x_pitch  = (const int*)d_in[2];
  const int* ei       = (const int*)d_in[3];
  const int* batch    = (const int*)d_in[4];
  const float* ctab = (const float*)d_in[5];
  const float* ptab = (const float*)d_in[6];
  const float* Wl1 = (const float*)d_in[7];
  const float* bl1 = (const float*)d_in[8];
  const float* Wr1 = (const float*)d_in[9];
  const float* br1 = (const float*)d_in[10];
  const float* att1 = (const float*)d_in[11];
  const float* bias1 = (const float*)d_in[12];
  const float* ln1g = (const float*)d_in[13];
  const float* ln1b = (const float*)d_in[14];
  const float* Wl2 = (const float*)d_in[15];
  const float* bl2 = (const float*)d_in[16];
  const float* Wr2 = (const float*)d_in[17];
  const float* br2 = (const float*)d_in[18];
  const float* att2 = (const float*)d_in[19];
  const float* bias2 = (const float*)d_in[20];
  const float* ln2g = (const float*)d_in[21];
  const float* ln2b = (const float*)d_in[22];
  const float* Wp1 = (const float*)d_in[23];
  const float* bp1 = (const float*)d_in[24];
  const float* lnpg = (const float*)d_in[25];
  const float* lnpb = (const float*)d_in[26];
  const float* Wp2 = (const float*)d_in[27];
  const float* bp2 = (const float*)d_in[28];
  float* out = (float*)d_out;
  (void)n_in; (void)out_size; (void)ws_size;

  int N = in_sizes[1];
  int E = in_sizes[3] / 2;
  int ET = E + N;

  // ---- workspace layout (with aliasing) ----
  char* p = (char*)d_ws;
  ushort* xb   = (ushort*)p; p += (size_t)N * 160 * 2;
  ushort* W1t  = (ushort*)p; p += (size_t)1024 * 160 * 2;
  ushort* W2t  = (ushort*)p; p += (size_t)512 * 512 * 2;
  ushort* xlr1 = (ushort*)p; p += (size_t)N * 1024 * 2;  // also xlr2 (bf16 N*512)
  ushort* h1b  = (ushort*)p; p += (size_t)N * 512 * 2;   // also h2 (fp32 N*256, same bytes)
  float* pooled = (float*)p; p += (size_t)NG * 256 * 4;
  int* cnt     = (int*)p;    p += NG * 4;
  float* hproj = (float*)p;  p += (size_t)NG * 512 * 4;
  int* deg     = (int*)p;    p += (size_t)N * 4;
  int* fill    = (int*)p;    p += (size_t)N * 4;
  int* rowptr  = (int*)p;    p += (size_t)(N + 1) * 4;
  int* csr     = (int*)p;    p += (size_t)ET * 4;
  ushort* xlr2 = xlr1;
  float* h2   = (float*)h1b;

  const int* esrc = ei;
  const int* edst = ei + E;

  hipMemsetAsync(deg, 0, (size_t)2 * N * sizeof(int), stream);
  hipMemsetAsync(pooled, 0, (size_t)NG * 256 * sizeof(float) + NG * sizeof(int), stream);

  k_build_xb<<<cdiv(N * 160, 256), 256, 0, stream>>>(x_cont, x_class, x_pitch, ctab, ptab, xb, N);
  k_prep_w1<<<cdiv(1024 * 160, 256), 256, 0, stream>>>(Wl1, Wr1, W1t);
  k_prep_w2<<<cdiv(512 * 512, 256), 256, 0, stream>>>(Wl2, Wr2, W2t);
  k_hist<<<cdiv(ET, 256), 256, 0, stream>>>(edst, deg, E, N);
  k_scan<<<1, 1024, 0, stream>>>(deg, rowptr, N);
  k_scatter<<<cdiv(ET, 256), 256, 0, stream>>>(esrc, edst, rowptr, fill, csr, E, N);

  dim3 g1(cdiv(N, GBM), 1024 / GBN);
  k_gemm_mfma<<<g1, 256, 0, stream>>>(xb, W1t, bl1, br1, 512, xlr1, N, 160, 1024);
  k_gat1<<<cdiv(N * 64, 256), 256, 0, stream>>>(xlr1, rowptr, csr, att1, bias1, ln1g, ln1b, h1b, N);

  dim3 g2(cdiv(N, GBM), 512 / GBN);
  k_gemm_mfma<<<g2, 256, 0, stream>>>(h1b, W2t, bl2, br2, 256, xlr2, N, 512, 512);
  k_gat2<<<cdiv(N * 64, 256), 256, 0, stream>>>(xlr2, rowptr, csr, att2, bias2, ln2g, ln2b, h2, N);

  k_pool<<<cdiv(N, 256), 256, 0, stream>>>(h2, batch, pooled, cnt, N);
  k_proj1<<<NG, 512, 0, stream>>>(pooled, cnt, Wp1, bp1, lnpg, lnpb, hproj);
  k_proj2<<<NG, 512, 0, stream>>>(hproj, Wp2, bp2, out);
}

// Round 4
// 396.219 us; speedup vs baseline: 2.6039x; 1.3148x over previous
//
#include <hip/hip_runtime.h>
#include <math.h>

#define NG 64   // graphs

typedef short bf16x8 __attribute__((ext_vector_type(8)));
typedef short bf16x4 __attribute__((ext_vector_type(4)));
typedef float f32x4 __attribute__((ext_vector_type(4)));

static inline int cdiv(int a, int b) { return (a + b - 1) / b; }

__device__ inline ushort f2b(float f) {
  union { float f; uint u; } v; v.f = f;
  uint u = v.u;
  return (ushort)((u + 0x7fffu + ((u >> 16) & 1u)) >> 16);
}
__device__ inline float b2f(ushort h) {
  union { uint u; float f; } v; v.u = ((uint)h) << 16;
  return v.f;
}

// ---------------- feature build (bf16, K padded to 160) ----------------
__global__ __launch_bounds__(256) void k_build_xb(
    const float* __restrict__ xc, const int* __restrict__ xcl,
    const int* __restrict__ xpi, const float* __restrict__ ctab,
    const float* __restrict__ ptab, ushort* __restrict__ x, int n) {
  int t = blockIdx.x * blockDim.x + threadIdx.x;
  int total = n * 160;
  if (t >= total) return;
  int node = t / 160, c = t % 160;
  float v;
  if (c < 6)        v = xc[node * 6 + c];
  else if (c < 70)  v = ctab[xcl[node] * 64 + (c - 6)];
  else if (c < 134) v = ptab[xpi[node] * 64 + (c - 70)];
  else              v = 0.f;
  x[t] = f2b(v);
}

// ---------------- weight prep: transpose + concat + pad, fp32 -> bf16 ----------------
__global__ __launch_bounds__(256) void k_prep_w1(
    const float* __restrict__ Wl, const float* __restrict__ Wr,
    ushort* __restrict__ Wt) {
  int t = blockIdx.x * blockDim.x + threadIdx.x;
  if (t >= 1024 * 160) return;
  int c = t / 160, k = t % 160;
  float v = 0.f;
  if (k < 134) v = (c < 512) ? Wl[k * 512 + c] : Wr[k * 512 + (c - 512)];
  Wt[t] = f2b(v);
}
__global__ __launch_bounds__(256) void k_prep_w2(
    const float* __restrict__ Wl, const float* __restrict__ Wr,
    ushort* __restrict__ Wt) {
  int t = blockIdx.x * blockDim.x + threadIdx.x;
  if (t >= 512 * 512) return;
  int c = t / 512, k = t % 512;
  float v = (c < 256) ? Wl[k * 256 + c] : Wr[k * 256 + (c - 256)];
  Wt[t] = f2b(v);
}

// ---------------- CSR build ----------------
__global__ __launch_bounds__(256) void k_hist(const int* __restrict__ dst,
                                              int* __restrict__ deg, int E, int N) {
  int t = blockIdx.x * blockDim.x + threadIdx.x;
  if (t < E) atomicAdd(&deg[dst[t]], 1);
  else if (t < E + N) atomicAdd(&deg[t - E], 1);  // self loops
}

// 3-phase scan: block sums -> scan sums -> per-block scan + offset
__global__ __launch_bounds__(256) void k_bsum(const int* __restrict__ deg,
                                              int* __restrict__ bsum, int n) {
  int i = blockIdx.x * 256 + threadIdx.x;
  int v = (i < n) ? deg[i] : 0;
#pragma unroll
  for (int off = 1; off < 64; off <<= 1) v += __shfl_xor(v, off);
  __shared__ int ws[4];
  if ((threadIdx.x & 63) == 0) ws[threadIdx.x >> 6] = v;
  __syncthreads();
  if (threadIdx.x == 0) bsum[blockIdx.x] = ws[0] + ws[1] + ws[2] + ws[3];
}

__global__ __launch_bounds__(256) void k_scanb(const int* __restrict__ bsum,
                                               int* __restrict__ boff, int nb) {
  int t = threadIdx.x, lane = t & 63;
  int v = (t < nb) ? bsum[t] : 0;
  int incl = v;
#pragma unroll
  for (int off = 1; off < 64; off <<= 1) {
    int u = __shfl_up(incl, off);
    if (lane >= off) incl += u;
  }
  __shared__ int wsum[4];
  if (lane == 63) wsum[t >> 6] = incl;
  __syncthreads();
  int add = 0;
  for (int w = 0; w < (t >> 6); ++w) add += wsum[w];
  if (t < nb) boff[t] = incl + add - v;  // exclusive
}

__global__ __launch_bounds__(256) void k_scanc(const int* __restrict__ deg,
                                               const int* __restrict__ boff,
                                               int* __restrict__ rowptr, int n) {
  int b = blockIdx.x, t = threadIdx.x, lane = t & 63;
  int i = b * 256 + t;
  int v = (i < n) ? deg[i] : 0;
  int incl = v;
#pragma unroll
  for (int off = 1; off < 64; off <<= 1) {
    int u = __shfl_up(incl, off);
    if (lane >= off) incl += u;
  }
  __shared__ int wsum[4];
  if (lane == 63) wsum[t >> 6] = incl;
  __syncthreads();
  int add = boff[b];
  for (int w = 0; w < (t >> 6); ++w) add += wsum[w];
  if (i < n) rowptr[i + 1] = incl + add;
  if (i == 0) rowptr[0] = 0;
}

__global__ __launch_bounds__(256) void k_scatter(
    const int* __restrict__ src, const int* __restrict__ dst,
    const int* __restrict__ rowptr, int* __restrict__ fill,
    int* __restrict__ csr, int E, int N) {
  int t = blockIdx.x * blockDim.x + threadIdx.x;
  int s, d;
  if (t < E) { s = src[t]; d = dst[t]; }
  else if (t < E + N) { s = t - E; d = t - E; }
  else return;
  int pos = rowptr[d] + atomicAdd(&fill[d], 1);
  csr[pos] = s;
}

// ---------------- bf16 MFMA GEMM: C[M,NC] = A[M,Kp] @ Bt[NC,Kp]^T + bias -> bf16 ----------------
#define GBM 128
#define GBN 128
#define GBK 32
#define ESTRIDE 136   // epilogue LDS row stride in u16 (272B, 16B-aligned)
__device__ __forceinline__ int swzf(int r, int s) {
  return r * 64 + ((s * 16) ^ (((r >> 1) & 3) << 4));
}
__global__ __launch_bounds__(256) void k_gemm_mfma(
    const ushort* __restrict__ A, const ushort* __restrict__ Bt,
    const float* __restrict__ blo, const float* __restrict__ bhi, int nhalf,
    ushort* __restrict__ C, int M, int Kp, int NC) {
  __shared__ ushort smem[GBM * ESTRIDE];  // 34816 B; aliases sA/sB in main loop
  ushort* sA = smem;
  ushort* sB = smem + GBM * GBK;
  int tid = threadIdx.x;
  int lane = tid & 63, w = tid >> 6;
  int wr = w >> 1, wc = w & 1;
  int row0 = blockIdx.x * GBM, col0 = blockIdx.y * GBN;
  int nK = Kp / GBK;

  int rs = tid >> 2, ss = tid & 3;
  int wO0 = swzf(rs, ss);
  int wO1 = swzf(rs + 64, ss);
  bool okA0 = (row0 + rs) < M;
  bool okA1 = (row0 + rs + 64) < M;
  size_t baseA0 = (size_t)(row0 + rs) * Kp + ss * 8;
  size_t baseA1 = (size_t)(row0 + rs + 64) * Kp + ss * 8;
  size_t baseB0 = (size_t)(col0 + rs) * Kp + ss * 8;
  size_t baseB1 = (size_t)(col0 + rs + 64) * Kp + ss * 8;

  int fr = lane & 15, kq = lane >> 4;
  int aoff[4], boff[4];
#pragma unroll
  for (int m = 0; m < 4; ++m) {
    int ra = wr * 64 + m * 16 + fr;
    aoff[m] = ra * 64 + ((kq * 16) ^ (((ra >> 1) & 3) << 4));
    int rb = wc * 64 + m * 16 + fr;
    boff[m] = rb * 64 + ((kq * 16) ^ (((rb >> 1) & 3) << 4));
  }

  f32x4 acc[4][4] = {};
  bf16x8 zz = {};
  bf16x8 pa0, pa1, pb0, pb1, qa0, qa1, qb0, qb1;

#define LOADG(KS, RA0, RA1, RB0, RB1)                                   \
  do {                                                                  \
    const ushort* ap = A + (size_t)(KS) * GBK;                          \
    const ushort* bp = Bt + (size_t)(KS) * GBK;                         \
    RA0 = okA0 ? *(const bf16x8*)(ap + baseA0) : zz;                    \
    RA1 = okA1 ? *(const bf16x8*)(ap + baseA1) : zz;                    \
    RB0 = *(const bf16x8*)(bp + baseB0);                                \
    RB1 = *(const bf16x8*)(bp + baseB1);                                \
  } while (0)

#define STAGE(RA0, RA1, RB0, RB1)                                       \
  do {                                                                  \
    *(bf16x8*)((char*)sA + wO0) = RA0;                                  \
    *(bf16x8*)((char*)sA + wO1) = RA1;                                  \
    *(bf16x8*)((char*)sB + wO0) = RB0;                                  \
    *(bf16x8*)((char*)sB + wO1) = RB1;                                  \
  } while (0)

#define COMPUTE()                                                       \
  do {                                                                  \
    bf16x8 av[4], bv[4];                                                \
    _Pragma("unroll") for (int m = 0; m < 4; ++m)                       \
        av[m] = *(const bf16x8*)((const char*)sA + aoff[m]);            \
    _Pragma("unroll") for (int n = 0; n < 4; ++n)                       \
        bv[n] = *(const bf16x8*)((const char*)sB + boff[n]);            \
    _Pragma("unroll") for (int m = 0; m < 4; ++m)                       \
        _Pragma("unroll") for (int n = 0; n < 4; ++n)                   \
            acc[m][n] = __builtin_amdgcn_mfma_f32_16x16x32_bf16(        \
                av[m], bv[n], acc[m][n], 0, 0, 0);                      \
  } while (0)

  LOADG(0, pa0, pa1, pb0, pb1);
  for (int ks = 0; ks < nK; ++ks) {
    __syncthreads();
    if (ks & 1) {
      STAGE(qa0, qa1, qb0, qb1);
      if (ks + 1 < nK) LOADG(ks + 1, pa0, pa1, pb0, pb1);
    } else {
      STAGE(pa0, pa1, pb0, pb1);
      if (ks + 1 < nK) LOADG(ks + 1, qa0, qa1, qb0, qb1);
    }
    __syncthreads();
    COMPUTE();
  }

  // ---- epilogue: stage tile in LDS, then coalesced bf16x8 stores ----
  __syncthreads();  // sA/sB dead; reuse smem as tile
#pragma unroll
  for (int m = 0; m < 4; ++m) {
#pragma unroll
    for (int n = 0; n < 4; ++n) {
      int tc = wc * 64 + n * 16 + fr;
      float bv = ((col0 + tc) < nhalf) ? blo[col0 + tc] : bhi[col0 + tc - nhalf];
#pragma unroll
      for (int j = 0; j < 4; ++j) {
        int tr = wr * 64 + m * 16 + kq * 4 + j;
        smem[tr * ESTRIDE + tc] = f2b(acc[m][n][j] + bv);
      }
    }
  }
  __syncthreads();
  int r0 = tid >> 4, cb = (tid & 15) * 8;
#pragma unroll
  for (int pass = 0; pass < 8; ++pass) {
    int r = pass * 16 + r0;
    int grow = row0 + r;
    if (grow < M) {
      bf16x8 vv = *(const bf16x8*)&smem[r * ESTRIDE + cb];
      *(bf16x8*)&C[(size_t)grow * NC + col0 + cb] = vv;
    }
  }
#undef LOADG
#undef STAGE
#undef COMPUTE
}

// ---------------- GAT layer 1 aggregate (H=4, C=128) + bias + LN + ELU -> bf16 ----------------
// xlr: [N][1024] bf16, cols 0..511 = xl, 512..1023 = xr. out: [N][512] bf16.
// max-free softmax: scores bounded (|e| <~ 8), w = exp(e - 8) preserves ratios exactly.
__global__ __launch_bounds__(256) void k_gat1(
    const ushort* __restrict__ xlr,
    const int* __restrict__ rowptr, const int* __restrict__ csr,
    const float* __restrict__ att, const float* __restrict__ bias,
    const float* __restrict__ lng, const float* __restrict__ lnb,
    ushort* __restrict__ out, int n) {
  int wid = (blockIdx.x * blockDim.x + threadIdx.x) >> 6;
  int lane = threadIdx.x & 63;
  if (wid >= n) return;
  int base = lane * 8;
  float xrv[8], attv[8];
  {
    bf16x8 t = *(const bf16x8*)&xlr[(size_t)wid * 1024 + 512 + base];
#pragma unroll
    for (int j = 0; j < 8; ++j) xrv[j] = b2f((ushort)t[j]);
    const float* ap = &att[base];
    float4 u0 = *(const float4*)ap;
    float4 u1 = *(const float4*)(ap + 4);
    attv[0] = u0.x; attv[1] = u0.y; attv[2] = u0.z; attv[3] = u0.w;
    attv[4] = u1.x; attv[5] = u1.y; attv[6] = u1.z; attv[7] = u1.w;
  }
  float s = 0.f;
  float acc[8] = {};
  int e0 = rowptr[wid], e1 = rowptr[wid + 1];
  bf16x8 vbn = *(const bf16x8*)&xlr[(size_t)csr[e0] * 1024 + base];
  for (int p = e0; p < e1; ++p) {
    bf16x8 vb = vbn;
    if (p + 1 < e1)
      vbn = *(const bf16x8*)&xlr[(size_t)csr[p + 1] * 1024 + base];
    float v[8];
#pragma unroll
    for (int j = 0; j < 8; ++j) v[j] = b2f((ushort)vb[j]);
    float pe = 0.f;
#pragma unroll
    for (int j = 0; j < 8; ++j) {
      float t = v[j] + xrv[j];
      t = t > 0.f ? t : 0.2f * t;
      pe += t * attv[j];
    }
    pe += __shfl_xor(pe, 1);
    pe += __shfl_xor(pe, 2);
    pe += __shfl_xor(pe, 4);
    pe += __shfl_xor(pe, 8);
    float w = __expf(pe - 8.f);
    s += w;
#pragma unroll
    for (int j = 0; j < 8; ++j) acc[j] += w * v[j];
  }
  float inv = 1.f / s;
  float o[8];
#pragma unroll
  for (int j = 0; j < 8; ++j) o[j] = acc[j] * inv + bias[base + j];
  float sum = 0.f, sq = 0.f;
#pragma unroll
  for (int j = 0; j < 8; ++j) { sum += o[j]; sq += o[j] * o[j]; }
#pragma unroll
  for (int off = 1; off < 64; off <<= 1) {
    sum += __shfl_xor(sum, off);
    sq += __shfl_xor(sq, off);
  }
  float mean = sum * (1.f / 512.f);
  float var = fmaxf(sq * (1.f / 512.f) - mean * mean, 0.f);
  float rstd = rsqrtf(var + 1e-5f);
  bf16x8 ov;
#pragma unroll
  for (int j = 0; j < 8; ++j) {
    float y = (o[j] - mean) * rstd * lng[base + j] + lnb[base + j];
    y = y > 0.f ? y : __expf(y) - 1.f;   // ELU
    ov[j] = (short)f2b(y);
  }
  *(bf16x8*)&out[(size_t)wid * 512 + base] = ov;
}

// ---------------- GAT layer 2 aggregate (H=1, C=256) + bias + LN + ELU ----------------
__global__ __launch_bounds__(256) void k_gat2(
    const ushort* __restrict__ xlr,
    const int* __restrict__ rowptr, const int* __restrict__ csr,
    const float* __restrict__ att, const float* __restrict__ bias,
    const float* __restrict__ lng, const float* __restrict__ lnb,
    float* __restrict__ out, int n) {
  int wid = (blockIdx.x * blockDim.x + threadIdx.x) >> 6;
  int lane = threadIdx.x & 63;
  if (wid >= n) return;
  int base = lane * 4;
  float xrv[4], attv[4];
  {
    bf16x4 t = *(const bf16x4*)&xlr[(size_t)wid * 512 + 256 + base];
#pragma unroll
    for (int j = 0; j < 4; ++j) xrv[j] = b2f((ushort)t[j]);
    float4 at4 = *(const float4*)&att[base];
    attv[0] = at4.x; attv[1] = at4.y; attv[2] = at4.z; attv[3] = at4.w;
  }
  float s = 0.f;
  float acc[4] = {};
  int e0 = rowptr[wid], e1 = rowptr[wid + 1];
  bf16x4 vbn = *(const bf16x4*)&xlr[(size_t)csr[e0] * 512 + base];
  for (int p = e0; p < e1; ++p) {
    bf16x4 vb = vbn;
    if (p + 1 < e1)
      vbn = *(const bf16x4*)&xlr[(size_t)csr[p + 1] * 512 + base];
    float v[4];
#pragma unroll
    for (int j = 0; j < 4; ++j) v[j] = b2f((ushort)vb[j]);
    float pe = 0.f;
#pragma unroll
    for (int j = 0; j < 4; ++j) {
      float t = v[j] + xrv[j];
      t = t > 0.f ? t : 0.2f * t;
      pe += t * attv[j];
    }
#pragma unroll
    for (int off = 1; off < 64; off <<= 1) pe += __shfl_xor(pe, off);
    float w = __expf(pe - 8.f);
    s += w;
#pragma unroll
    for (int j = 0; j < 4; ++j) acc[j] += w * v[j];
  }
  float inv = 1.f / s;
  float o[4];
#pragma unroll
  for (int j = 0; j < 4; ++j) o[j] = acc[j] * inv + bias[base + j];
  float sum = 0.f, sq = 0.f;
#pragma unroll
  for (int j = 0; j < 4; ++j) { sum += o[j]; sq += o[j] * o[j]; }
#pragma unroll
  for (int off = 1; off < 64; off <<= 1) {
    sum += __shfl_xor(sum, off);
    sq += __shfl_xor(sq, off);
  }
  float mean = sum * (1.f / 256.f);
  float var = fmaxf(sq * (1.f / 256.f) - mean * mean, 0.f);
  float rstd = rsqrtf(var + 1e-5f);
#pragma unroll
  for (int j = 0; j < 4; ++j) {
    float y = (o[j] - mean) * rstd * lng[base + j] + lnb[base + j];
    y = y > 0.f ? y : __expf(y) - 1.f;
    out[(size_t)wid * 256 + base + j] = y;
  }
}

// ---------------- pooling (batch is sorted), 64-row chunks ----------------
__global__ __launch_bounds__(256) void k_pool(
    const float* __restrict__ h2, const int* __restrict__ batch,
    float* __restrict__ pooled, int* __restrict__ cnt, int n) {
  int c = threadIdx.x;  // 256 channels
  int n0 = blockIdx.x * 64;
  int n1 = min(n0 + 64, n);
  if (n0 >= n) return;
  float acc = 0.f;
  int cur = batch[n0];
  int cl = 0;
  for (int i = n0; i < n1; ++i) {
    int bb = batch[i];
    if (bb != cur) {
      atomicAdd(&pooled[cur * 256 + c], acc);
      if (c == 0) atomicAdd(&cnt[cur], cl);
      acc = 0.f; cl = 0; cur = bb;
    }
    acc += h2[(size_t)i * 256 + c];
    cl++;
  }
  atomicAdd(&pooled[cur * 256 + c], acc);
  if (c == 0) atomicAdd(&cnt[cur], cl);
}

// ---------------- projection head ----------------
__global__ __launch_bounds__(512) void k_proj1(
    const float* __restrict__ pooled, const int* __restrict__ cnt,
    const float* __restrict__ W, const float* __restrict__ b,
    const float* __restrict__ lng, const float* __restrict__ lnb,
    float* __restrict__ hout) {
  __shared__ float row[256];
  __shared__ float red[16];
  int g = blockIdx.x, c = threadIdx.x;
  if (c < 256) {
    float cc = fmaxf((float)cnt[g], 1.f);
    row[c] = pooled[g * 256 + c] / cc;
  }
  __syncthreads();
  float acc = b[c];
#pragma unroll 4
  for (int k = 0; k < 256; ++k) acc += row[k] * W[k * 512 + c];
  float sum = acc, sq = acc * acc;
#pragma unroll
  for (int off = 1; off < 64; off <<= 1) {
    sum += __shfl_xor(sum, off);
    sq += __shfl_xor(sq, off);
  }
  int wv = threadIdx.x >> 6;
  if ((threadIdx.x & 63) == 0) { red[wv] = sum; red[8 + wv] = sq; }
  __syncthreads();
  float S = 0.f, Q = 0.f;
#pragma unroll
  for (int t = 0; t < 8; ++t) { S += red[t]; Q += red[8 + t]; }
  float mean = S * (1.f / 512.f);
  float var = fmaxf(Q * (1.f / 512.f) - mean * mean, 0.f);
  float rstd = rsqrtf(var + 1e-5f);
  float y = (acc - mean) * rstd * lng[c] + lnb[c];
  float ge = 0.5f * y * (1.f + erff(y * 0.70710678118654752f));  // exact gelu
  hout[g * 512 + c] = ge;
}

__global__ __launch_bounds__(512) void k_proj2(
    const float* __restrict__ h, const float* __restrict__ W,
    const float* __restrict__ b, float* __restrict__ out) {
  __shared__ float row[512];
  __shared__ float red[8];
  int g = blockIdx.x, c = threadIdx.x;
  row[c] = h[g * 512 + c];
  __syncthreads();
  float acc = b[c];
#pragma unroll 4
  for (int k = 0; k < 512; ++k) acc += row[k] * W[k * 512 + c];
  float sq = acc * acc;
#pragma unroll
  for (int off = 1; off < 64; off <<= 1) sq += __shfl_xor(sq, off);
  int wv = threadIdx.x >> 6;
  if ((threadIdx.x & 63) == 0) red[wv] = sq;
  __syncthreads();
  float S = 0.f;
#pragma unroll
  for (int t = 0; t < 8; ++t) S += red[t];
  float norm = fmaxf(sqrtf(S), 1e-12f);
  out[g * 512 + c] = acc / norm;
}

// ---------------- launch ----------------
extern "C" void kernel_launch(void* const* d_in, const int* in_sizes, int n_in,
                              void* d_out, int out_size, void* d_ws, size_t ws_size,
                              hipStream_t stream) {
  const float* x_cont = (const float*)d_in[0];
  const int* x_class  = (const int*)d_in[1];
  const int* x_pitch  = (const int*)d_in[2];
  const int* ei       = (const int*)d_in[3];
  const int* batch    = (const int*)d_in[4];
  const float* ctab = (const float*)d_in[5];
  const float* ptab = (const float*)d_in[6];
  const float* Wl1 = (const float*)d_in[7];
  const float* bl1 = (const float*)d_in[8];
  const float* Wr1 = (const float*)d_in[9];
  const float* br1 = (const float*)d_in[10];
  const float* att1 = (const float*)d_in[11];
  const float* bias1 = (const float*)d_in[12];
  const float* ln1g = (const float*)d_in[13];
  const float* ln1b = (const float*)d_in[14];
  const float* Wl2 = (const float*)d_in[15];
  const float* bl2 = (const float*)d_in[16];
  const float* Wr2 = (const float*)d_in[17];
  const float* br2 = (const float*)d_in[18];
  const float* att2 = (const float*)d_in[19];
  const float* bias2 = (const float*)d_in[20];
  const float* ln2g = (const float*)d_in[21];
  const float* ln2b = (const float*)d_in[22];
  const float* Wp1 = (const float*)d_in[23];
  const float* bp1 = (const float*)d_in[24];
  const float* lnpg = (const float*)d_in[25];
  const float* lnpb = (const float*)d_in[26];
  const float* Wp2 = (const float*)d_in[27];
  const float* bp2 = (const float*)d_in[28];
  float* out = (float*)d_out;
  (void)n_in; (void)out_size; (void)ws_size;

  int N = in_sizes[1];
  int E = in_sizes[3] / 2;
  int ET = E + N;
  int NB = cdiv(N, 256);  // scan blocks (<= 256)

  // ---- workspace layout (with aliasing) ----
  char* p = (char*)d_ws;
  ushort* xb   = (ushort*)p; p += (size_t)N * 160 * 2;
  ushort* W1t  = (ushort*)p; p += (size_t)1024 * 160 * 2;
  ushort* W2t  = (ushort*)p; p += (size_t)512 * 512 * 2;
  ushort* xlr1 = (ushort*)p; p += (size_t)N * 1024 * 2;  // also xlr2 (bf16 N*512)
  ushort* h1b  = (ushort*)p; p += (size_t)N * 512 * 2;   // also h2 (fp32 N*256, same bytes)
  float* pooled = (float*)p; p += (size_t)NG * 256 * 4;
  int* cnt     = (int*)p;    p += NG * 4;
  float* hproj = (float*)p;  p += (size_t)NG * 512 * 4;
  int* deg     = (int*)p;    p += (size_t)N * 4;
  int* fill    = (int*)p;    p += (size_t)N * 4;
  int* rowptr  = (int*)p;    p += (size_t)(N + 1) * 4;
  int* csr     = (int*)p;    p += (size_t)ET * 4;
  int* bsum    = (int*)p;    p += 256 * 4;
  int* boff    = (int*)p;    p += 256 * 4;
  ushort* xlr2 = xlr1;
  float* h2   = (float*)h1b;

  const int* esrc = ei;
  const int* edst = ei + E;

  hipMemsetAsync(deg, 0, (size_t)2 * N * sizeof(int), stream);
  hipMemsetAsync(pooled, 0, (size_t)NG * 256 * sizeof(float) + NG * sizeof(int), stream);

  k_build_xb<<<cdiv(N * 160, 256), 256, 0, stream>>>(x_cont, x_class, x_pitch, ctab, ptab, xb, N);
  k_prep_w1<<<cdiv(1024 * 160, 256), 256, 0, stream>>>(Wl1, Wr1, W1t);
  k_prep_w2<<<cdiv(512 * 512, 256), 256, 0, stream>>>(Wl2, Wr2, W2t);
  k_hist<<<cdiv(ET, 256), 256, 0, stream>>>(edst, deg, E, N);
  k_bsum<<<NB, 256, 0, stream>>>(deg, bsum, N);
  k_scanb<<<1, 256, 0, stream>>>(bsum, boff, NB);
  k_scanc<<<NB, 256, 0, stream>>>(deg, boff, rowptr, N);
  k_scatter<<<cdiv(ET, 256), 256, 0, stream>>>(esrc, edst, rowptr, fill, csr, E, N);

  dim3 g1(cdiv(N, GBM), 1024 / GBN);
  k_gemm_mfma<<<g1, 256, 0, stream>>>(xb, W1t, bl1, br1, 512, xlr1, N, 160, 1024);
  k_gat1<<<cdiv(N * 64, 256), 256, 0, stream>>>(xlr1, rowptr, csr, att1, bias1, ln1g, ln1b, h1b, N);

  dim3 g2(cdiv(N, GBM), 512 / GBN);
  k_gemm_mfma<<<g2, 256, 0, stream>>>(h1b, W2t, bl2, br2, 256, xlr2, N, 512, 512);
  k_gat2<<<cdiv(N * 64, 256), 256, 0, stream>>>(xlr2, rowptr, csr, att2, bias2, ln2g, ln2b, h2, N);

  k_pool<<<cdiv(N, 64), 256, 0, stream>>>(h2, batch, pooled, cnt, N);
  k_proj1<<<NG, 512, 0, stream>>>(pooled, cnt, Wp1, bp1, lnpg, lnpb, hproj);
  k_proj2<<<NG, 512, 0, stream>>>(hproj, Wp2, bp2, out);
}

// Round 5
// 384.066 us; speedup vs baseline: 2.6863x; 1.0316x over previous
//
#include <hip/hip_runtime.h>
#include <math.h>

#define NG 64   // graphs

typedef short bf16x8 __attribute__((ext_vector_type(8)));
typedef short bf16x4 __attribute__((ext_vector_type(4)));
typedef float f32x4 __attribute__((ext_vector_type(4)));

static inline int cdiv(int a, int b) { return (a + b - 1) / b; }

__device__ inline ushort f2b(float f) {
  union { float f; uint u; } v; v.f = f;
  uint u = v.u;
  return (ushort)((u + 0x7fffu + ((u >> 16) & 1u)) >> 16);
}
__device__ inline float b2f(ushort h) {
  union { uint u; float f; } v; v.u = ((uint)h) << 16;
  return v.f;
}

__device__ __forceinline__ void unpack8(bf16x8 vb, float* v) {
  union { bf16x8 b; uint u[4]; } cv; cv.b = vb;
#pragma unroll
  for (int q = 0; q < 4; ++q) {
    union { uint u; float f; } lo, hi;
    lo.u = cv.u[q] << 16;
    hi.u = cv.u[q] & 0xffff0000u;
    v[2 * q] = lo.f; v[2 * q + 1] = hi.f;
  }
}
__device__ __forceinline__ void unpack4(bf16x4 vb, float* v) {
  union { bf16x4 b; uint u[2]; } cv; cv.b = vb;
#pragma unroll
  for (int q = 0; q < 2; ++q) {
    union { uint u; float f; } lo, hi;
    lo.u = cv.u[q] << 16;
    hi.u = cv.u[q] & 0xffff0000u;
    v[2 * q] = lo.f; v[2 * q + 1] = hi.f;
  }
}

// ---------------- feature build (bf16, K padded to 160) ----------------
__global__ __launch_bounds__(256) void k_build_xb(
    const float* __restrict__ xc, const int* __restrict__ xcl,
    const int* __restrict__ xpi, const float* __restrict__ ctab,
    const float* __restrict__ ptab, ushort* __restrict__ x, int n) {
  int t = blockIdx.x * blockDim.x + threadIdx.x;
  int total = n * 160;
  if (t >= total) return;
  int node = t / 160, c = t % 160;
  float v;
  if (c < 6)        v = xc[node * 6 + c];
  else if (c < 70)  v = ctab[xcl[node] * 64 + (c - 6)];
  else if (c < 134) v = ptab[xpi[node] * 64 + (c - 70)];
  else              v = 0.f;
  x[t] = f2b(v);
}

// ---------------- weight prep: transpose + concat + pad, fp32 -> bf16 ----------------
__global__ __launch_bounds__(256) void k_prep_w1(
    const float* __restrict__ Wl, const float* __restrict__ Wr,
    ushort* __restrict__ Wt) {
  int t = blockIdx.x * blockDim.x + threadIdx.x;
  if (t >= 1024 * 160) return;
  int c = t / 160, k = t % 160;
  float v = 0.f;
  if (k < 134) v = (c < 512) ? Wl[k * 512 + c] : Wr[k * 512 + (c - 512)];
  Wt[t] = f2b(v);
}
__global__ __launch_bounds__(256) void k_prep_w2(
    const float* __restrict__ Wl, const float* __restrict__ Wr,
    ushort* __restrict__ Wt) {
  int t = blockIdx.x * blockDim.x + threadIdx.x;
  if (t >= 512 * 512) return;
  int c = t / 512, k = t % 512;
  float v = (c < 256) ? Wl[k * 256 + c] : Wr[k * 256 + (c - 256)];
  Wt[t] = f2b(v);
}

// ---------------- CSR build ----------------
__global__ __launch_bounds__(256) void k_hist(const int* __restrict__ dst,
                                              int* __restrict__ deg, int E, int N) {
  int t = blockIdx.x * blockDim.x + threadIdx.x;
  if (t < E) atomicAdd(&deg[dst[t]], 1);
  else if (t < E + N) atomicAdd(&deg[t - E], 1);  // self loops
}

// 3-phase scan: block sums -> scan sums -> per-block scan + offset
__global__ __launch_bounds__(256) void k_bsum(const int* __restrict__ deg,
                                              int* __restrict__ bsum, int n) {
  int i = blockIdx.x * 256 + threadIdx.x;
  int v = (i < n) ? deg[i] : 0;
#pragma unroll
  for (int off = 1; off < 64; off <<= 1) v += __shfl_xor(v, off);
  __shared__ int ws[4];
  if ((threadIdx.x & 63) == 0) ws[threadIdx.x >> 6] = v;
  __syncthreads();
  if (threadIdx.x == 0) bsum[blockIdx.x] = ws[0] + ws[1] + ws[2] + ws[3];
}

__global__ __launch_bounds__(256) void k_scanb(const int* __restrict__ bsum,
                                               int* __restrict__ boff, int nb) {
  int t = threadIdx.x, lane = t & 63;
  int v = (t < nb) ? bsum[t] : 0;
  int incl = v;
#pragma unroll
  for (int off = 1; off < 64; off <<= 1) {
    int u = __shfl_up(incl, off);
    if (lane >= off) incl += u;
  }
  __shared__ int wsum[4];
  if (lane == 63) wsum[t >> 6] = incl;
  __syncthreads();
  int add = 0;
  for (int w = 0; w < (t >> 6); ++w) add += wsum[w];
  if (t < nb) boff[t] = incl + add - v;  // exclusive
}

__global__ __launch_bounds__(256) void k_scanc(const int* __restrict__ deg,
                                               const int* __restrict__ boff,
                                               int* __restrict__ rowptr, int n) {
  int b = blockIdx.x, t = threadIdx.x, lane = t & 63;
  int i = b * 256 + t;
  int v = (i < n) ? deg[i] : 0;
  int incl = v;
#pragma unroll
  for (int off = 1; off < 64; off <<= 1) {
    int u = __shfl_up(incl, off);
    if (lane >= off) incl += u;
  }
  __shared__ int wsum[4];
  if (lane == 63) wsum[t >> 6] = incl;
  __syncthreads();
  int add = boff[b];
  for (int w = 0; w < (t >> 6); ++w) add += wsum[w];
  if (i < n) rowptr[i + 1] = incl + add;
  if (i == 0) rowptr[0] = 0;
}

__global__ __launch_bounds__(256) void k_scatter(
    const int* __restrict__ src, const int* __restrict__ dst,
    const int* __restrict__ rowptr, int* __restrict__ fill,
    int* __restrict__ csr, int E, int N) {
  int t = blockIdx.x * blockDim.x + threadIdx.x;
  int s, d;
  if (t < E) { s = src[t]; d = dst[t]; }
  else if (t < E + N) { s = t - E; d = t - E; }
  else return;
  int pos = rowptr[d] + atomicAdd(&fill[d], 1);
  csr[pos] = s;
}

// ---------------- bf16 MFMA GEMM: C[M,NC] = A[M,Kp] @ Bt[NC,Kp]^T + bias -> bf16 ----------------
#define GBM 128
#define GBN 128
#define GBK 32
#define ESTRIDE 136   // epilogue LDS row stride in u16 (272B, 16B-aligned)
__device__ __forceinline__ int swzf(int r, int s) {
  return r * 64 + ((s * 16) ^ (((r >> 1) & 3) << 4));
}
__global__ __launch_bounds__(256) void k_gemm_mfma(
    const ushort* __restrict__ A, const ushort* __restrict__ Bt,
    const float* __restrict__ blo, const float* __restrict__ bhi, int nhalf,
    ushort* __restrict__ C, int M, int Kp, int NC) {
  __shared__ ushort smem[GBM * ESTRIDE];  // 34816 B; aliases sA/sB in main loop
  ushort* sA = smem;
  ushort* sB = smem + GBM * GBK;
  int tid = threadIdx.x;
  int lane = tid & 63, w = tid >> 6;
  int wr = w >> 1, wc = w & 1;
  int row0 = blockIdx.x * GBM, col0 = blockIdx.y * GBN;
  int nK = Kp / GBK;

  int rs = tid >> 2, ss = tid & 3;
  int wO0 = swzf(rs, ss);
  int wO1 = swzf(rs + 64, ss);
  bool okA0 = (row0 + rs) < M;
  bool okA1 = (row0 + rs + 64) < M;
  size_t baseA0 = (size_t)(row0 + rs) * Kp + ss * 8;
  size_t baseA1 = (size_t)(row0 + rs + 64) * Kp + ss * 8;
  size_t baseB0 = (size_t)(col0 + rs) * Kp + ss * 8;
  size_t baseB1 = (size_t)(col0 + rs + 64) * Kp + ss * 8;

  int fr = lane & 15, kq = lane >> 4;
  int aoff[4], boff[4];
#pragma unroll
  for (int m = 0; m < 4; ++m) {
    int ra = wr * 64 + m * 16 + fr;
    aoff[m] = ra * 64 + ((kq * 16) ^ (((ra >> 1) & 3) << 4));
    int rb = wc * 64 + m * 16 + fr;
    boff[m] = rb * 64 + ((kq * 16) ^ (((rb >> 1) & 3) << 4));
  }

  f32x4 acc[4][4] = {};
  bf16x8 zz = {};
  bf16x8 pa0, pa1, pb0, pb1, qa0, qa1, qb0, qb1;

#define LOADG(KS, RA0, RA1, RB0, RB1)                                   \
  do {                                                                  \
    const ushort* ap = A + (size_t)(KS) * GBK;                          \
    const ushort* bp = Bt + (size_t)(KS) * GBK;                         \
    RA0 = okA0 ? *(const bf16x8*)(ap + baseA0) : zz;                    \
    RA1 = okA1 ? *(const bf16x8*)(ap + baseA1) : zz;                    \
    RB0 = *(const bf16x8*)(bp + baseB0);                                \
    RB1 = *(const bf16x8*)(bp + baseB1);                                \
  } while (0)

#define STAGE(RA0, RA1, RB0, RB1)                                       \
  do {                                                                  \
    *(bf16x8*)((char*)sA + wO0) = RA0;                                  \
    *(bf16x8*)((char*)sA + wO1) = RA1;                                  \
    *(bf16x8*)((char*)sB + wO0) = RB0;                                  \
    *(bf16x8*)((char*)sB + wO1) = RB1;                                  \
  } while (0)

#define COMPUTE()                                                       \
  do {                                                                  \
    bf16x8 av[4], bv[4];                                                \
    _Pragma("unroll") for (int m = 0; m < 4; ++m)                       \
        av[m] = *(const bf16x8*)((const char*)sA + aoff[m]);            \
    _Pragma("unroll") for (int n = 0; n < 4; ++n)                       \
        bv[n] = *(const bf16x8*)((const char*)sB + boff[n]);            \
    _Pragma("unroll") for (int m = 0; m < 4; ++m)                       \
        _Pragma("unroll") for (int n = 0; n < 4; ++n)                   \
            acc[m][n] = __builtin_amdgcn_mfma_f32_16x16x32_bf16(        \
                av[m], bv[n], acc[m][n], 0, 0, 0);                      \
  } while (0)

  LOADG(0, pa0, pa1, pb0, pb1);
  for (int ks = 0; ks < nK; ++ks) {
    __syncthreads();
    if (ks & 1) {
      STAGE(qa0, qa1, qb0, qb1);
      if (ks + 1 < nK) LOADG(ks + 1, pa0, pa1, pb0, pb1);
    } else {
      STAGE(pa0, pa1, pb0, pb1);
      if (ks + 1 < nK) LOADG(ks + 1, qa0, qa1, qb0, qb1);
    }
    __syncthreads();
    COMPUTE();
  }

  // ---- epilogue: stage tile in LDS, then coalesced bf16x8 stores ----
  __syncthreads();  // sA/sB dead; reuse smem as tile
#pragma unroll
  for (int m = 0; m < 4; ++m) {
#pragma unroll
    for (int n = 0; n < 4; ++n) {
      int tc = wc * 64 + n * 16 + fr;
      float bv = ((col0 + tc) < nhalf) ? blo[col0 + tc] : bhi[col0 + tc - nhalf];
#pragma unroll
      for (int j = 0; j < 4; ++j) {
        int tr = wr * 64 + m * 16 + kq * 4 + j;
        smem[tr * ESTRIDE + tc] = f2b(acc[m][n][j] + bv);
      }
    }
  }
  __syncthreads();
  int r0 = tid >> 4, cb = (tid & 15) * 8;
#pragma unroll
  for (int pass = 0; pass < 8; ++pass) {
    int r = pass * 16 + r0;
    int grow = row0 + r;
    if (grow < M) {
      bf16x8 vv = *(const bf16x8*)&smem[r * ESTRIDE + cb];
      *(bf16x8*)&C[(size_t)grow * NC + col0 + cb] = vv;
    }
  }
#undef LOADG
#undef STAGE
#undef COMPUTE
}

// ---------------- GAT layer 1 aggregate (H=4, C=128) + bias + LN + ELU -> bf16 ----------------
// xlr: [N][1024] bf16, cols 0..511 = xl, 512..1023 = xr. out: [N][512] bf16.
// att . leaky_relu(t) == 0.6*att.t + 0.4*att.|t|  (slope 0.2); |t| is a free VOP3 modifier.
// max-free softmax: scores bounded, w = exp(pe - 8) preserves ratios exactly.
__global__ __launch_bounds__(256) void k_gat1(
    const ushort* __restrict__ xlr,
    const int* __restrict__ rowptr, const int* __restrict__ csr,
    const float* __restrict__ att, const float* __restrict__ bias,
    const float* __restrict__ lng, const float* __restrict__ lnb,
    ushort* __restrict__ out, int n) {
  int wid = (blockIdx.x * blockDim.x + threadIdx.x) >> 6;
  int lane = threadIdx.x & 63;
  if (wid >= n) return;
  int base = lane * 8;
  float xrv[8], attv[8];
  {
    bf16x8 t = *(const bf16x8*)&xlr[(size_t)wid * 1024 + 512 + base];
    unpack8(t, xrv);
    const float* ap = &att[base];
    float4 u0 = *(const float4*)ap;
    float4 u1 = *(const float4*)(ap + 4);
    attv[0] = u0.x; attv[1] = u0.y; attv[2] = u0.z; attv[3] = u0.w;
    attv[4] = u1.x; attv[5] = u1.y; attv[6] = u1.z; attv[7] = u1.w;
  }
  float s = 0.f;
  float acc[8] = {};
  int e0 = rowptr[wid], e1 = rowptr[wid + 1];
  const ushort* xp = xlr + base;
  bf16x8 r0 = *(const bf16x8*)(xp + ((size_t)csr[e0] << 10));
  bf16x8 r1 = r0;
  if (e0 + 1 < e1) r1 = *(const bf16x8*)(xp + ((size_t)csr[e0 + 1] << 10));
  int p = e0;
  for (; p + 1 < e1; p += 2) {
    bf16x8 cA = r0, cB = r1;
    if (p + 2 < e1) r0 = *(const bf16x8*)(xp + ((size_t)csr[p + 2] << 10));
    if (p + 3 < e1) r1 = *(const bf16x8*)(xp + ((size_t)csr[p + 3] << 10));
    float vA[8], vB[8];
    unpack8(cA, vA);
    unpack8(cB, vB);
    float p1A = 0.f, p2A = 0.f, p1B = 0.f, p2B = 0.f;
#pragma unroll
    for (int j = 0; j < 8; ++j) {
      float tA = vA[j] + xrv[j];
      float tB = vB[j] + xrv[j];
      p1A = fmaf(attv[j], tA, p1A);
      p2A = fmaf(attv[j], fabsf(tA), p2A);
      p1B = fmaf(attv[j], tB, p1B);
      p2B = fmaf(attv[j], fabsf(tB), p2B);
    }
    float peA = 0.6f * p1A + 0.4f * p2A;
    float peB = 0.6f * p1B + 0.4f * p2B;
#pragma unroll
    for (int off = 1; off < 16; off <<= 1) {
      peA += __shfl_xor(peA, off);
      peB += __shfl_xor(peB, off);
    }
    float wA = __expf(peA - 8.f);
    float wB = __expf(peB - 8.f);
    s += wA + wB;
#pragma unroll
    for (int j = 0; j < 8; ++j) {
      acc[j] = fmaf(wA, vA[j], acc[j]);
      acc[j] = fmaf(wB, vB[j], acc[j]);
    }
  }
  if (p < e1) {  // tail edge (row already in r0)
    float vA[8];
    unpack8(r0, vA);
    float p1A = 0.f, p2A = 0.f;
#pragma unroll
    for (int j = 0; j < 8; ++j) {
      float tA = vA[j] + xrv[j];
      p1A = fmaf(attv[j], tA, p1A);
      p2A = fmaf(attv[j], fabsf(tA), p2A);
    }
    float peA = 0.6f * p1A + 0.4f * p2A;
#pragma unroll
    for (int off = 1; off < 16; off <<= 1) peA += __shfl_xor(peA, off);
    float wA = __expf(peA - 8.f);
    s += wA;
#pragma unroll
    for (int j = 0; j < 8; ++j) acc[j] = fmaf(wA, vA[j], acc[j]);
  }
  float inv = 1.f / s;
  float o[8];
#pragma unroll
  for (int j = 0; j < 8; ++j) o[j] = acc[j] * inv + bias[base + j];
  float sum = 0.f, sq = 0.f;
#pragma unroll
  for (int j = 0; j < 8; ++j) { sum += o[j]; sq += o[j] * o[j]; }
#pragma unroll
  for (int off = 1; off < 64; off <<= 1) {
    sum += __shfl_xor(sum, off);
    sq += __shfl_xor(sq, off);
  }
  float mean = sum * (1.f / 512.f);
  float var = fmaxf(sq * (1.f / 512.f) - mean * mean, 0.f);
  float rstd = rsqrtf(var + 1e-5f);
  bf16x8 ov;
#pragma unroll
  for (int j = 0; j < 8; ++j) {
    float y = (o[j] - mean) * rstd * lng[base + j] + lnb[base + j];
    y = y > 0.f ? y : __expf(y) - 1.f;   // ELU
    ov[j] = (short)f2b(y);
  }
  *(bf16x8*)&out[(size_t)wid * 512 + base] = ov;
}

// ---------------- GAT layer 2 aggregate (H=1, C=256) + bias + LN + ELU ----------------
__global__ __launch_bounds__(256) void k_gat2(
    const ushort* __restrict__ xlr,
    const int* __restrict__ rowptr, const int* __restrict__ csr,
    const float* __restrict__ att, const float* __restrict__ bias,
    const float* __restrict__ lng, const float* __restrict__ lnb,
    float* __restrict__ out, int n) {
  int wid = (blockIdx.x * blockDim.x + threadIdx.x) >> 6;
  int lane = threadIdx.x & 63;
  if (wid >= n) return;
  int base = lane * 4;
  float xrv[4], attv[4];
  {
    bf16x4 t = *(const bf16x4*)&xlr[(size_t)wid * 512 + 256 + base];
    unpack4(t, xrv);
    float4 at4 = *(const float4*)&att[base];
    attv[0] = at4.x; attv[1] = at4.y; attv[2] = at4.z; attv[3] = at4.w;
  }
  float s = 0.f;
  float acc[4] = {};
  int e0 = rowptr[wid], e1 = rowptr[wid + 1];
  const ushort* xp = xlr + base;
  bf16x4 r0 = *(const bf16x4*)(xp + ((size_t)csr[e0] << 9));
  bf16x4 r1 = r0;
  if (e0 + 1 < e1) r1 = *(const bf16x4*)(xp + ((size_t)csr[e0 + 1] << 9));
  int p = e0;
  for (; p + 1 < e1; p += 2) {
    bf16x4 cA = r0, cB = r1;
    if (p + 2 < e1) r0 = *(const bf16x4*)(xp + ((size_t)csr[p + 2] << 9));
    if (p + 3 < e1) r1 = *(const bf16x4*)(xp + ((size_t)csr[p + 3] << 9));
    float vA[4], vB[4];
    unpack4(cA, vA);
    unpack4(cB, vB);
    float p1A = 0.f, p2A = 0.f, p1B = 0.f, p2B = 0.f;
#pragma unroll
    for (int j = 0; j < 4; ++j) {
      float tA = vA[j] + xrv[j];
      float tB = vB[j] + xrv[j];
      p1A = fmaf(attv[j], tA, p1A);
      p2A = fmaf(attv[j], fabsf(tA), p2A);
      p1B = fmaf(attv[j], tB, p1B);
      p2B = fmaf(attv[j], fabsf(tB), p2B);
    }
    float peA = 0.6f * p1A + 0.4f * p2A;
    float peB = 0.6f * p1B + 0.4f * p2B;
#pragma unroll
    for (int off = 1; off < 64; off <<= 1) {
      peA += __shfl_xor(peA, off);
      peB += __shfl_xor(peB, off);
    }
    float wA = __expf(peA - 8.f);
    float wB = __expf(peB - 8.f);
    s += wA + wB;
#pragma unroll
    for (int j = 0; j < 4; ++j) {
      acc[j] = fmaf(wA, vA[j], acc[j]);
      acc[j] = fmaf(wB, vB[j], acc[j]);
    }
  }
  if (p < e1) {
    float vA[4];
    unpack4(r0, vA);
    float p1A = 0.f, p2A = 0.f;
#pragma unroll
    for (int j = 0; j < 4; ++j) {
      float tA = vA[j] + xrv[j];
      p1A = fmaf(attv[j], tA, p1A);
      p2A = fmaf(attv[j], fabsf(tA), p2A);
    }
    float peA = 0.6f * p1A + 0.4f * p2A;
#pragma unroll
    for (int off = 1; off < 64; off <<= 1) peA += __shfl_xor(peA, off);
    float wA = __expf(peA - 8.f);
    s += wA;
#pragma unroll
    for (int j = 0; j < 4; ++j) acc[j] = fmaf(wA, vA[j], acc[j]);
  }
  float inv = 1.f / s;
  float o[4];
#pragma unroll
  for (int j = 0; j < 4; ++j) o[j] = acc[j] * inv + bias[base + j];
  float sum = 0.f, sq = 0.f;
#pragma unroll
  for (int j = 0; j < 4; ++j) { sum += o[j]; sq += o[j] * o[j]; }
#pragma unroll
  for (int off = 1; off < 64; off <<= 1) {
    sum += __shfl_xor(sum, off);
    sq += __shfl_xor(sq, off);
  }
  float mean = sum * (1.f / 256.f);
  float var = fmaxf(sq * (1.f / 256.f) - mean * mean, 0.f);
  float rstd = rsqrtf(var + 1e-5f);
#pragma unroll
  for (int j = 0; j < 4; ++j) {
    float y = (o[j] - mean) * rstd * lng[base + j] + lnb[base + j];
    y = y > 0.f ? y : __expf(y) - 1.f;
    out[(size_t)wid * 256 + base + j] = y;
  }
}

// ---------------- pooling (batch is sorted), 64-row chunks ----------------
__global__ __launch_bounds__(256) void k_pool(
    const float* __restrict__ h2, const int* __restrict__ batch,
    float* __restrict__ pooled, int* __restrict__ cnt, int n) {
  int c = threadIdx.x;  // 256 channels
  int n0 = blockIdx.x * 64;
  int n1 = min(n0 + 64, n);
  if (n0 >= n) return;
  float acc = 0.f;
  int cur = batch[n0];
  int cl = 0;
  for (int i = n0; i < n1; ++i) {
    int bb = batch[i];
    if (bb != cur) {
      atomicAdd(&pooled[cur * 256 + c], acc);
      if (c == 0) atomicAdd(&cnt[cur], cl);
      acc = 0.f; cl = 0; cur = bb;
    }
    acc += h2[(size_t)i * 256 + c];
    cl++;
  }
  atomicAdd(&pooled[cur * 256 + c], acc);
  if (c == 0) atomicAdd(&cnt[cur], cl);
}

// ---------------- projection head ----------------
__global__ __launch_bounds__(512) void k_proj1(
    const float* __restrict__ pooled, const int* __restrict__ cnt,
    const float* __restrict__ W, const float* __restrict__ b,
    const float* __restrict__ lng, const float* __restrict__ lnb,
    float* __restrict__ hout) {
  __shared__ float row[256];
  __shared__ float red[16];
  int g = blockIdx.x, c = threadIdx.x;
  if (c < 256) {
    float cc = fmaxf((float)cnt[g], 1.f);
    row[c] = pooled[g * 256 + c] / cc;
  }
  __syncthreads();
  float acc = b[c];
#pragma unroll 4
  for (int k = 0; k < 256; ++k) acc += row[k] * W[k * 512 + c];
  float sum = acc, sq = acc * acc;
#pragma unroll
  for (int off = 1; off < 64; off <<= 1) {
    sum += __shfl_xor(sum, off);
    sq += __shfl_xor(sq, off);
  }
  int wv = threadIdx.x >> 6;
  if ((threadIdx.x & 63) == 0) { red[wv] = sum; red[8 + wv] = sq; }
  __syncthreads();
  float S = 0.f, Q = 0.f;
#pragma unroll
  for (int t = 0; t < 8; ++t) { S += red[t]; Q += red[8 + t]; }
  float mean = S * (1.f / 512.f);
  float var = fmaxf(Q * (1.f / 512.f) - mean * mean, 0.f);
  float rstd = rsqrtf(var + 1e-5f);
  float y = (acc - mean) * rstd * lng[c] + lnb[c];
  float ge = 0.5f * y * (1.f + erff(y * 0.70710678118654752f));  // exact gelu
  hout[g * 512 + c] = ge;
}

__global__ __launch_bounds__(512) void k_proj2(
    const float* __restrict__ h, const float* __restrict__ W,
    const float* __restrict__ b, float* __restrict__ out) {
  __shared__ float row[512];
  __shared__ float red[8];
  int g = blockIdx.x, c = threadIdx.x;
  row[c] = h[g * 512 + c];
  __syncthreads();
  float acc = b[c];
#pragma unroll 4
  for (int k = 0; k < 512; ++k) acc += row[k] * W[k * 512 + c];
  float sq = acc * acc;
#pragma unroll
  for (int off = 1; off < 64; off <<= 1) sq += __shfl_xor(sq, off);
  int wv = threadIdx.x >> 6;
  if ((threadIdx.x & 63) == 0) red[wv] = sq;
  __syncthreads();
  float S = 0.f;
#pragma unroll
  for (int t = 0; t < 8; ++t) S += red[t];
  float norm = fmaxf(sqrtf(S), 1e-12f);
  out[g * 512 + c] = acc / norm;
}

// ---------------- launch ----------------
extern "C" void kernel_launch(void* const* d_in, const int* in_sizes, int n_in,
                              void* d_out, int out_size, void* d_ws, size_t ws_size,
                              hipStream_t stream) {
  const float* x_cont = (const float*)d_in[0];
  const int* x_class  = (const int*)d_in[1];
  const int* x_pitch  = (const int*)d_in[2];
  const int* ei       = (const int*)d_in[3];
  const int* batch    = (const int*)d_in[4];
  const float* ctab = (const float*)d_in[5];
  const float* ptab = (const float*)d_in[6];
  const float* Wl1 = (const float*)d_in[7];
  const float* bl1 = (const float*)d_in[8];
  const float* Wr1 = (const float*)d_in[9];
  const float* br1 = (const float*)d_in[10];
  const float* att1 = (const float*)d_in[11];
  const float* bias1 = (const float*)d_in[12];
  const float* ln1g = (const float*)d_in[13];
  const float* ln1b = (const float*)d_in[14];
  const float* Wl2 = (const float*)d_in[15];
  const float* bl2 = (const float*)d_in[16];
  const float* Wr2 = (const float*)d_in[17];
  const float* br2 = (const float*)d_in[18];
  const float* att2 = (const float*)d_in[19];
  const float* bias2 = (const float*)d_in[20];
  const float* ln2g = (const float*)d_in[21];
  const float* ln2b = (const float*)d_in[22];
  const float* Wp1 = (const float*)d_in[23];
  const float* bp1 = (const float*)d_in[24];
  const float* lnpg = (const float*)d_in[25];
  const float* lnpb = (const float*)d_in[26];
  const float* Wp2 = (const float*)d_in[27];
  const float* bp2 = (const float*)d_in[28];
  float* out = (float*)d_out;
  (void)n_in; (void)out_size; (void)ws_size;

  int N = in_sizes[1];
  int E = in_sizes[3] / 2;
  int ET = E + N;
  int NB = cdiv(N, 256);  // scan blocks (<= 256)

  // ---- workspace layout (with aliasing) ----
  char* p = (char*)d_ws;
  ushort* xb   = (ushort*)p; p += (size_t)N * 160 * 2;
  ushort* W1t  = (ushort*)p; p += (size_t)1024 * 160 * 2;
  ushort* W2t  = (ushort*)p; p += (size_t)512 * 512 * 2;
  ushort* xlr1 = (ushort*)p; p += (size_t)N * 1024 * 2;  // also xlr2 (bf16 N*512)
  ushort* h1b  = (ushort*)p; p += (size_t)N * 512 * 2;   // also h2 (fp32 N*256, same bytes)
  float* pooled = (float*)p; p += (size_t)NG * 256 * 4;
  int* cnt     = (int*)p;    p += NG * 4;
  float* hproj = (float*)p;  p += (size_t)NG * 512 * 4;
  int* deg     = (int*)p;    p += (size_t)N * 4;
  int* fill    = (int*)p;    p += (size_t)N * 4;
  int* rowptr  = (int*)p;    p += (size_t)(N + 1) * 4;
  int* csr     = (int*)p;    p += (size_t)ET * 4;
  int* bsum    = (int*)p;    p += 256 * 4;
  int* boff    = (int*)p;    p += 256 * 4;
  ushort* xlr2 = xlr1;
  float* h2   = (float*)h1b;

  const int* esrc = ei;
  const int* edst = ei + E;

  hipMemsetAsync(deg, 0, (size_t)2 * N * sizeof(int), stream);
  hipMemsetAsync(pooled, 0, (size_t)NG * 256 * sizeof(float) + NG * sizeof(int), stream);

  k_build_xb<<<cdiv(N * 160, 256), 256, 0, stream>>>(x_cont, x_class, x_pitch, ctab, ptab, xb, N);
  k_prep_w1<<<cdiv(1024 * 160, 256), 256, 0, stream>>>(Wl1, Wr1, W1t);
  k_prep_w2<<<cdiv(512 * 512, 256), 256, 0, stream>>>(Wl2, Wr2, W2t);
  k_hist<<<cdiv(ET, 256), 256, 0, stream>>>(edst, deg, E, N);
  k_bsum<<<NB, 256, 0, stream>>>(deg, bsum, N);
  k_scanb<<<1, 256, 0, stream>>>(bsum, boff, NB);
  k_scanc<<<NB, 256, 0, stream>>>(deg, boff, rowptr, N);
  k_scatter<<<cdiv(ET, 256), 256, 0, stream>>>(esrc, edst, rowptr, fill, csr, E, N);

  dim3 g1(cdiv(N, GBM), 1024 / GBN);
  k_gemm_mfma<<<g1, 256, 0, stream>>>(xb, W1t, bl1, br1, 512, xlr1, N, 160, 1024);
  k_gat1<<<cdiv(N * 64, 256), 256, 0, stream>>>(xlr1, rowptr, csr, att1, bias1, ln1g, ln1b, h1b, N);

  dim3 g2(cdiv(N, GBM), 512 / GBN);
  k_gemm_mfma<<<g2, 256, 0, stream>>>(h1b, W2t, bl2, br2, 256, xlr2, N, 512, 512);
  k_gat2<<<cdiv(N * 64, 256), 256, 0, stream>>>(xlr2, rowptr, csr, att2, bias2, ln2g, ln2b, h2, N);

  k_pool<<<cdiv(N, 64), 256, 0, stream>>>(h2, batch, pooled, cnt, N);
  k_proj1<<<NG, 512, 0, stream>>>(pooled, cnt, Wp1, bp1, lnpg, lnpb, hproj);
  k_proj2<<<NG, 512, 0, stream>>>(hproj, Wp2, bp2, out);
}

// Round 6
// 348.556 us; speedup vs baseline: 2.9600x; 1.1019x over previous
//
#include <hip/hip_runtime.h>
#include <math.h>

#define NG 64   // graphs

typedef short bf16x8 __attribute__((ext_vector_type(8)));
typedef short bf16x4 __attribute__((ext_vector_type(4)));
typedef float f32x4 __attribute__((ext_vector_type(4)));

static inline int cdiv(int a, int b) { return (a + b - 1) / b; }

__device__ inline ushort f2b(float f) {
  union { float f; uint u; } v; v.f = f;
  uint u = v.u;
  return (ushort)((u + 0x7fffu + ((u >> 16) & 1u)) >> 16);
}
__device__ inline float b2f(ushort h) {
  union { uint u; float f; } v; v.u = ((uint)h) << 16;
  return v.f;
}

__device__ __forceinline__ void unpack8(bf16x8 vb, float* v) {
  union { bf16x8 b; uint u[4]; } cv; cv.b = vb;
#pragma unroll
  for (int q = 0; q < 4; ++q) {
    union { uint u; float f; } lo, hi;
    lo.u = cv.u[q] << 16;
    hi.u = cv.u[q] & 0xffff0000u;
    v[2 * q] = lo.f; v[2 * q + 1] = hi.f;
  }
}
__device__ __forceinline__ void unpack4(bf16x4 vb, float* v) {
  union { bf16x4 b; uint u[2]; } cv; cv.b = vb;
#pragma unroll
  for (int q = 0; q < 2; ++q) {
    union { uint u; float f; } lo, hi;
    lo.u = cv.u[q] << 16;
    hi.u = cv.u[q] & 0xffff0000u;
    v[2 * q] = lo.f; v[2 * q + 1] = hi.f;
  }
}

// ---------------- fused prep: features + both weight transposes + degree hist ----------------
__global__ __launch_bounds__(256) void k_prep(
    const float* __restrict__ xc, const int* __restrict__ xcl,
    const int* __restrict__ xpi, const float* __restrict__ ctab,
    const float* __restrict__ ptab,
    const float* __restrict__ Wl1, const float* __restrict__ Wr1,
    const float* __restrict__ Wl2, const float* __restrict__ Wr2,
    const int* __restrict__ edst,
    ushort* __restrict__ xb, ushort* __restrict__ W1t, ushort* __restrict__ W2t,
    int* __restrict__ deg, int n, int E) {
  int t = blockIdx.x * blockDim.x + threadIdx.x;
  int T1 = n * 160;
  int T2 = T1 + 1024 * 160;
  int T3 = T2 + 512 * 512;
  int T4 = T3 + E + n;
  if (t < T1) {
    int node = t / 160, c = t % 160;
    float v;
    if (c < 6)        v = xc[node * 6 + c];
    else if (c < 70)  v = ctab[xcl[node] * 64 + (c - 6)];
    else if (c < 134) v = ptab[xpi[node] * 64 + (c - 70)];
    else              v = 0.f;
    xb[t] = f2b(v);
  } else if (t < T2) {
    int u = t - T1;
    int c = u / 160, k = u % 160;
    float v = 0.f;
    if (k < 134) v = (c < 512) ? Wl1[k * 512 + c] : Wr1[k * 512 + (c - 512)];
    W1t[u] = f2b(v);
  } else if (t < T3) {
    int u = t - T2;
    int c = u / 512, k = u % 512;
    float v = (c < 256) ? Wl2[k * 256 + c] : Wr2[k * 256 + (c - 256)];
    W2t[u] = f2b(v);
  } else if (t < T4) {
    int u = t - T3;
    if (u < E) atomicAdd(&deg[edst[u]], 1);
    else atomicAdd(&deg[u - E], 1);   // self loops
  }
}

// 3-phase scan: block sums -> scan sums -> per-block scan + offset
__global__ __launch_bounds__(256) void k_bsum(const int* __restrict__ deg,
                                              int* __restrict__ bsum, int n) {
  int i = blockIdx.x * 256 + threadIdx.x;
  int v = (i < n) ? deg[i] : 0;
#pragma unroll
  for (int off = 1; off < 64; off <<= 1) v += __shfl_xor(v, off);
  __shared__ int ws[4];
  if ((threadIdx.x & 63) == 0) ws[threadIdx.x >> 6] = v;
  __syncthreads();
  if (threadIdx.x == 0) bsum[blockIdx.x] = ws[0] + ws[1] + ws[2] + ws[3];
}

__global__ __launch_bounds__(256) void k_scanb(const int* __restrict__ bsum,
                                               int* __restrict__ boff, int nb) {
  int t = threadIdx.x, lane = t & 63;
  int v = (t < nb) ? bsum[t] : 0;
  int incl = v;
#pragma unroll
  for (int off = 1; off < 64; off <<= 1) {
    int u = __shfl_up(incl, off);
    if (lane >= off) incl += u;
  }
  __shared__ int wsum[4];
  if (lane == 63) wsum[t >> 6] = incl;
  __syncthreads();
  int add = 0;
  for (int w = 0; w < (t >> 6); ++w) add += wsum[w];
  if (t < nb) boff[t] = incl + add - v;  // exclusive
}

__global__ __launch_bounds__(256) void k_scanc(const int* __restrict__ deg,
                                               const int* __restrict__ boff,
                                               int* __restrict__ rowptr, int n) {
  int b = blockIdx.x, t = threadIdx.x, lane = t & 63;
  int i = b * 256 + t;
  int v = (i < n) ? deg[i] : 0;
  int incl = v;
#pragma unroll
  for (int off = 1; off < 64; off <<= 1) {
    int u = __shfl_up(incl, off);
    if (lane >= off) incl += u;
  }
  __shared__ int wsum[4];
  if (lane == 63) wsum[t >> 6] = incl;
  __syncthreads();
  int add = boff[b];
  for (int w = 0; w < (t >> 6); ++w) add += wsum[w];
  if (i < n) rowptr[i + 1] = incl + add;
  if (i == 0) rowptr[0] = 0;
}

__global__ __launch_bounds__(256) void k_scatter(
    const int* __restrict__ src, const int* __restrict__ dst,
    const int* __restrict__ rowptr, int* __restrict__ fill,
    int* __restrict__ csr, int E, int N) {
  int t = blockIdx.x * blockDim.x + threadIdx.x;
  int s, d;
  if (t < E) { s = src[t]; d = dst[t]; }
  else if (t < E + N) { s = t - E; d = t - E; }
  else return;
  int pos = rowptr[d] + atomicAdd(&fill[d], 1);
  csr[pos] = s;
}

// ---------------- bf16 MFMA GEMM: C[M,NC] = A[M,Kp] @ Bt[NC,Kp]^T + bias -> bf16 ----------------
#define GBM 128
#define GBN 128
#define GBK 32
#define ESTRIDE 136   // epilogue LDS row stride in u16 (272B, 16B-aligned)
__device__ __forceinline__ int swzf(int r, int s) {
  return r * 64 + ((s * 16) ^ (((r >> 1) & 3) << 4));
}
__global__ __launch_bounds__(256) void k_gemm_mfma(
    const ushort* __restrict__ A, const ushort* __restrict__ Bt,
    const float* __restrict__ blo, const float* __restrict__ bhi, int nhalf,
    ushort* __restrict__ C, int M, int Kp, int NC) {
  __shared__ ushort smem[GBM * ESTRIDE];  // 34816 B; aliases sA/sB in main loop
  ushort* sA = smem;
  ushort* sB = smem + GBM * GBK;
  int tid = threadIdx.x;
  int lane = tid & 63, w = tid >> 6;
  int wr = w >> 1, wc = w & 1;
  int row0 = blockIdx.x * GBM, col0 = blockIdx.y * GBN;
  int nK = Kp / GBK;

  int rs = tid >> 2, ss = tid & 3;
  int wO0 = swzf(rs, ss);
  int wO1 = swzf(rs + 64, ss);
  bool okA0 = (row0 + rs) < M;
  bool okA1 = (row0 + rs + 64) < M;
  size_t baseA0 = (size_t)(row0 + rs) * Kp + ss * 8;
  size_t baseA1 = (size_t)(row0 + rs + 64) * Kp + ss * 8;
  size_t baseB0 = (size_t)(col0 + rs) * Kp + ss * 8;
  size_t baseB1 = (size_t)(col0 + rs + 64) * Kp + ss * 8;

  int fr = lane & 15, kq = lane >> 4;
  int aoff[4], boff[4];
#pragma unroll
  for (int m = 0; m < 4; ++m) {
    int ra = wr * 64 + m * 16 + fr;
    aoff[m] = ra * 64 + ((kq * 16) ^ (((ra >> 1) & 3) << 4));
    int rb = wc * 64 + m * 16 + fr;
    boff[m] = rb * 64 + ((kq * 16) ^ (((rb >> 1) & 3) << 4));
  }

  f32x4 acc[4][4] = {};
  bf16x8 zz = {};
  bf16x8 pa0, pa1, pb0, pb1, qa0, qa1, qb0, qb1;

#define LOADG(KS, RA0, RA1, RB0, RB1)                                   \
  do {                                                                  \
    const ushort* ap = A + (size_t)(KS) * GBK;                          \
    const ushort* bp = Bt + (size_t)(KS) * GBK;                         \
    RA0 = okA0 ? *(const bf16x8*)(ap + baseA0) : zz;                    \
    RA1 = okA1 ? *(const bf16x8*)(ap + baseA1) : zz;                    \
    RB0 = *(const bf16x8*)(bp + baseB0);                                \
    RB1 = *(const bf16x8*)(bp + baseB1);                                \
  } while (0)

#define STAGE(RA0, RA1, RB0, RB1)                                       \
  do {                                                                  \
    *(bf16x8*)((char*)sA + wO0) = RA0;                                  \
    *(bf16x8*)((char*)sA + wO1) = RA1;                                  \
    *(bf16x8*)((char*)sB + wO0) = RB0;                                  \
    *(bf16x8*)((char*)sB + wO1) = RB1;                                  \
  } while (0)

#define COMPUTE()                                                       \
  do {                                                                  \
    bf16x8 av[4], bv[4];                                                \
    _Pragma("unroll") for (int m = 0; m < 4; ++m)                       \
        av[m] = *(const bf16x8*)((const char*)sA + aoff[m]);            \
    _Pragma("unroll") for (int n = 0; n < 4; ++n)                       \
        bv[n] = *(const bf16x8*)((const char*)sB + boff[n]);            \
    _Pragma("unroll") for (int m = 0; m < 4; ++m)                       \
        _Pragma("unroll") for (int n = 0; n < 4; ++n)                   \
            acc[m][n] = __builtin_amdgcn_mfma_f32_16x16x32_bf16(        \
                av[m], bv[n], acc[m][n], 0, 0, 0);                      \
  } while (0)

  LOADG(0, pa0, pa1, pb0, pb1);
  for (int ks = 0; ks < nK; ++ks) {
    __syncthreads();
    if (ks & 1) {
      STAGE(qa0, qa1, qb0, qb1);
      if (ks + 1 < nK) LOADG(ks + 1, pa0, pa1, pb0, pb1);
    } else {
      STAGE(pa0, pa1, pb0, pb1);
      if (ks + 1 < nK) LOADG(ks + 1, qa0, qa1, qb0, qb1);
    }
    __syncthreads();
    COMPUTE();
  }

  // ---- epilogue: stage tile in LDS, then coalesced bf16x8 stores ----
  __syncthreads();  // sA/sB dead; reuse smem as tile
#pragma unroll
  for (int m = 0; m < 4; ++m) {
#pragma unroll
    for (int n = 0; n < 4; ++n) {
      int tc = wc * 64 + n * 16 + fr;
      float bv = ((col0 + tc) < nhalf) ? blo[col0 + tc] : bhi[col0 + tc - nhalf];
#pragma unroll
      for (int j = 0; j < 4; ++j) {
        int tr = wr * 64 + m * 16 + kq * 4 + j;
        smem[tr * ESTRIDE + tc] = f2b(acc[m][n][j] + bv);
      }
    }
  }
  __syncthreads();
  int r0 = tid >> 4, cb = (tid & 15) * 8;
#pragma unroll
  for (int pass = 0; pass < 8; ++pass) {
    int r = pass * 16 + r0;
    int grow = row0 + r;
    if (grow < M) {
      bf16x8 vv = *(const bf16x8*)&smem[r * ESTRIDE + cb];
      *(bf16x8*)&C[(size_t)grow * NC + col0 + cb] = vv;
    }
  }
#undef LOADG
#undef STAGE
#undef COMPUTE
}

// ---------------- GAT layer 1 aggregate (H=4, C=128) + bias + LN + ELU -> bf16 ----------------
// xlr: [N][1024] bf16 (2048 B/row), cols 0..511 = xl, 512..1023 = xr. out: [N][512] bf16.
// att.leaky_relu(t) == 0.6*att.t + 0.4*att.|t|; max-free softmax w = exp(pe - 8).
// 4-deep prefetch ring, clamped indices, 32-bit byte offsets (table < 4 GB).
__global__ __launch_bounds__(256) void k_gat1(
    const ushort* __restrict__ xlr,
    const int* __restrict__ rowptr, const int* __restrict__ csr,
    const float* __restrict__ att, const float* __restrict__ bias,
    const float* __restrict__ lng, const float* __restrict__ lnb,
    ushort* __restrict__ out, int n) {
  int wid = (blockIdx.x * blockDim.x + threadIdx.x) >> 6;
  int lane = threadIdx.x & 63;
  if (wid >= n) return;
  int base = lane * 8;
  uint laneB = (uint)lane * 16u;
  const char* xb8 = (const char*)xlr;
  float xrv[8], attv[8];
  {
    bf16x8 t = *(const bf16x8*)(xb8 + ((uint)wid * 2048u + 1024u + laneB));
    unpack8(t, xrv);
    const float* ap = &att[base];
    float4 u0 = *(const float4*)ap;
    float4 u1 = *(const float4*)(ap + 4);
    attv[0] = u0.x; attv[1] = u0.y; attv[2] = u0.z; attv[3] = u0.w;
    attv[4] = u1.x; attv[5] = u1.y; attv[6] = u1.z; attv[7] = u1.w;
  }
  float s = 0.f;
  float acc[8] = {};
  int e0 = rowptr[wid], e1 = rowptr[wid + 1];
  int last = e1 - 1;

#define LROW1(IDX) (*(const bf16x8*)(xb8 + (((uint)csr[IDX]) * 2048u + laneB)))
  bf16x8 r0 = LROW1(e0);
  bf16x8 r1 = LROW1(min(e0 + 1, last));
  bf16x8 r2 = LROW1(min(e0 + 2, last));
  bf16x8 r3 = LROW1(min(e0 + 3, last));

  for (int pp = e0; pp < e1; pp += 4) {
    bf16x8 c0 = r0, c1 = r1, c2 = r2, c3 = r3;
    if (pp + 4 < e1) {
      r0 = LROW1(pp + 4);
      r1 = LROW1(min(pp + 5, last));
      r2 = LROW1(min(pp + 6, last));
      r3 = LROW1(min(pp + 7, last));
    }
    float v0[8], v1[8], v2[8], v3[8];
    unpack8(c0, v0); unpack8(c1, v1); unpack8(c2, v2); unpack8(c3, v3);
    float p1a = 0.f, p2a = 0.f, p1b = 0.f, p2b = 0.f;
    float p1c = 0.f, p2c = 0.f, p1d = 0.f, p2d = 0.f;
#pragma unroll
    for (int j = 0; j < 8; ++j) {
      float a = attv[j];
      float t0 = v0[j] + xrv[j];
      float t1 = v1[j] + xrv[j];
      float t2 = v2[j] + xrv[j];
      float t3 = v3[j] + xrv[j];
      p1a = fmaf(a, t0, p1a); p2a = fmaf(a, fabsf(t0), p2a);
      p1b = fmaf(a, t1, p1b); p2b = fmaf(a, fabsf(t1), p2b);
      p1c = fmaf(a, t2, p1c); p2c = fmaf(a, fabsf(t2), p2c);
      p1d = fmaf(a, t3, p1d); p2d = fmaf(a, fabsf(t3), p2d);
    }
    float pe0 = 0.6f * p1a + 0.4f * p2a;
    float pe1 = 0.6f * p1b + 0.4f * p2b;
    float pe2 = 0.6f * p1c + 0.4f * p2c;
    float pe3 = 0.6f * p1d + 0.4f * p2d;
#pragma unroll
    for (int off = 1; off < 16; off <<= 1) {
      pe0 += __shfl_xor(pe0, off);
      pe1 += __shfl_xor(pe1, off);
      pe2 += __shfl_xor(pe2, off);
      pe3 += __shfl_xor(pe3, off);
    }
    float w0 = __expf(pe0 - 8.f);
    float w1 = (pp + 1 <= last) ? __expf(pe1 - 8.f) : 0.f;
    float w2 = (pp + 2 <= last) ? __expf(pe2 - 8.f) : 0.f;
    float w3 = (pp + 3 <= last) ? __expf(pe3 - 8.f) : 0.f;
    s += (w0 + w1) + (w2 + w3);
#pragma unroll
    for (int j = 0; j < 8; ++j) {
      float t = fmaf(w0, v0[j], acc[j]);
      t = fmaf(w1, v1[j], t);
      t = fmaf(w2, v2[j], t);
      acc[j] = fmaf(w3, v3[j], t);
    }
  }
#undef LROW1
  float inv = 1.f / s;
  float o[8];
#pragma unroll
  for (int j = 0; j < 8; ++j) o[j] = acc[j] * inv + bias[base + j];
  float sum = 0.f, sq = 0.f;
#pragma unroll
  for (int j = 0; j < 8; ++j) { sum += o[j]; sq += o[j] * o[j]; }
#pragma unroll
  for (int off = 1; off < 64; off <<= 1) {
    sum += __shfl_xor(sum, off);
    sq += __shfl_xor(sq, off);
  }
  float mean = sum * (1.f / 512.f);
  float var = fmaxf(sq * (1.f / 512.f) - mean * mean, 0.f);
  float rstd = rsqrtf(var + 1e-5f);
  bf16x8 ov;
#pragma unroll
  for (int j = 0; j < 8; ++j) {
    float y = (o[j] - mean) * rstd * lng[base + j] + lnb[base + j];
    y = y > 0.f ? y : __expf(y) - 1.f;   // ELU
    ov[j] = (short)f2b(y);
  }
  *(bf16x8*)&out[(size_t)wid * 512 + base] = ov;
}

// ---------------- GAT layer 2 aggregate (H=1, C=256) + bias + LN + ELU ----------------
// xlr: [N][512] bf16 (1024 B/row), cols 0..255 = xl, 256..511 = xr. out fp32 [N][256].
__global__ __launch_bounds__(256) void k_gat2(
    const ushort* __restrict__ xlr,
    const int* __restrict__ rowptr, const int* __restrict__ csr,
    const float* __restrict__ att, const float* __restrict__ bias,
    const float* __restrict__ lng, const float* __restrict__ lnb,
    float* __restrict__ out, int n) {
  int wid = (blockIdx.x * blockDim.x + threadIdx.x) >> 6;
  int lane = threadIdx.x & 63;
  if (wid >= n) return;
  int base = lane * 4;
  uint laneB = (uint)lane * 8u;
  const char* xb8 = (const char*)xlr;
  float xrv[4], attv[4];
  {
    bf16x4 t = *(const bf16x4*)(xb8 + ((uint)wid * 1024u + 512u + laneB));
    unpack4(t, xrv);
    float4 at4 = *(const float4*)&att[base];
    attv[0] = at4.x; attv[1] = at4.y; attv[2] = at4.z; attv[3] = at4.w;
  }
  float s = 0.f;
  float acc[4] = {};
  int e0 = rowptr[wid], e1 = rowptr[wid + 1];
  int last = e1 - 1;

#define LROW2(IDX) (*(const bf16x4*)(xb8 + (((uint)csr[IDX]) * 1024u + laneB)))
  bf16x4 r0 = LROW2(e0);
  bf16x4 r1 = LROW2(min(e0 + 1, last));
  bf16x4 r2 = LROW2(min(e0 + 2, last));
  bf16x4 r3 = LROW2(min(e0 + 3, last));

  for (int pp = e0; pp < e1; pp += 4) {
    bf16x4 c0 = r0, c1 = r1, c2 = r2, c3 = r3;
    if (pp + 4 < e1) {
      r0 = LROW2(pp + 4);
      r1 = LROW2(min(pp + 5, last));
      r2 = LROW2(min(pp + 6, last));
      r3 = LROW2(min(pp + 7, last));
    }
    float v0[4], v1[4], v2[4], v3[4];
    unpack4(c0, v0); unpack4(c1, v1); unpack4(c2, v2); unpack4(c3, v3);
    float p1a = 0.f, p2a = 0.f, p1b = 0.f, p2b = 0.f;
    float p1c = 0.f, p2c = 0.f, p1d = 0.f, p2d = 0.f;
#pragma unroll
    for (int j = 0; j < 4; ++j) {
      float a = attv[j];
      float t0 = v0[j] + xrv[j];
      float t1 = v1[j] + xrv[j];
      float t2 = v2[j] + xrv[j];
      float t3 = v3[j] + xrv[j];
      p1a = fmaf(a, t0, p1a); p2a = fmaf(a, fabsf(t0), p2a);
      p1b = fmaf(a, t1, p1b); p2b = fmaf(a, fabsf(t1), p2b);
      p1c = fmaf(a, t2, p1c); p2c = fmaf(a, fabsf(t2), p2c);
      p1d = fmaf(a, t3, p1d); p2d = fmaf(a, fabsf(t3), p2d);
    }
    float pe0 = 0.6f * p1a + 0.4f * p2a;
    float pe1 = 0.6f * p1b + 0.4f * p2b;
    float pe2 = 0.6f * p1c + 0.4f * p2c;
    float pe3 = 0.6f * p1d + 0.4f * p2d;
#pragma unroll
    for (int off = 1; off < 64; off <<= 1) {
      pe0 += __shfl_xor(pe0, off);
      pe1 += __shfl_xor(pe1, off);
      pe2 += __shfl_xor(pe2, off);
      pe3 += __shfl_xor(pe3, off);
    }
    float w0 = __expf(pe0 - 8.f);
    float w1 = (pp + 1 <= last) ? __expf(pe1 - 8.f) : 0.f;
    float w2 = (pp + 2 <= last) ? __expf(pe2 - 8.f) : 0.f;
    float w3 = (pp + 3 <= last) ? __expf(pe3 - 8.f) : 0.f;
    s += (w0 + w1) + (w2 + w3);
#pragma unroll
    for (int j = 0; j < 4; ++j) {
      float t = fmaf(w0, v0[j], acc[j]);
      t = fmaf(w1, v1[j], t);
      t = fmaf(w2, v2[j], t);
      acc[j] = fmaf(w3, v3[j], t);
    }
  }
#undef LROW2
  float inv = 1.f / s;
  float o[4];
#pragma unroll
  for (int j = 0; j < 4; ++j) o[j] = acc[j] * inv + bias[base + j];
  float sum = 0.f, sq = 0.f;
#pragma unroll
  for (int j = 0; j < 4; ++j) { sum += o[j]; sq += o[j] * o[j]; }
#pragma unroll
  for (int off = 1; off < 64; off <<= 1) {
    sum += __shfl_xor(sum, off);
    sq += __shfl_xor(sq, off);
  }
  float mean = sum * (1.f / 256.f);
  float var = fmaxf(sq * (1.f / 256.f) - mean * mean, 0.f);
  float rstd = rsqrtf(var + 1e-5f);
#pragma unroll
  for (int j = 0; j < 4; ++j) {
    float y = (o[j] - mean) * rstd * lng[base + j] + lnb[base + j];
    y = y > 0.f ? y : __expf(y) - 1.f;
    out[(size_t)wid * 256 + base + j] = y;
  }
}

// ---------------- pooling (batch is sorted), 64-row chunks ----------------
__global__ __launch_bounds__(256) void k_pool(
    const float* __restrict__ h2, const int* __restrict__ batch,
    float* __restrict__ pooled, int* __restrict__ cnt, int n) {
  int c = threadIdx.x;  // 256 channels
  int n0 = blockIdx.x * 64;
  int n1 = min(n0 + 64, n);
  if (n0 >= n) return;
  float acc = 0.f;
  int cur = batch[n0];
  int cl = 0;
  for (int i = n0; i < n1; ++i) {
    int bb = batch[i];
    if (bb != cur) {
      atomicAdd(&pooled[cur * 256 + c], acc);
      if (c == 0) atomicAdd(&cnt[cur], cl);
      acc = 0.f; cl = 0; cur = bb;
    }
    acc += h2[(size_t)i * 256 + c];
    cl++;
  }
  atomicAdd(&pooled[cur * 256 + c], acc);
  if (c == 0) atomicAdd(&cnt[cur], cl);
}

// ---------------- projection head ----------------
__global__ __launch_bounds__(512) void k_proj1(
    const float* __restrict__ pooled, const int* __restrict__ cnt,
    const float* __restrict__ W, const float* __restrict__ b,
    const float* __restrict__ lng, const float* __restrict__ lnb,
    float* __restrict__ hout) {
  __shared__ float row[256];
  __shared__ float red[16];
  int g = blockIdx.x, c = threadIdx.x;
  if (c < 256) {
    float cc = fmaxf((float)cnt[g], 1.f);
    row[c] = pooled[g * 256 + c] / cc;
  }
  __syncthreads();
  float acc = b[c];
#pragma unroll 4
  for (int k = 0; k < 256; ++k) acc += row[k] * W[k * 512 + c];
  float sum = acc, sq = acc * acc;
#pragma unroll
  for (int off = 1; off < 64; off <<= 1) {
    sum += __shfl_xor(sum, off);
    sq += __shfl_xor(sq, off);
  }
  int wv = threadIdx.x >> 6;
  if ((threadIdx.x & 63) == 0) { red[wv] = sum; red[8 + wv] = sq; }
  __syncthreads();
  float S = 0.f, Q = 0.f;
#pragma unroll
  for (int t = 0; t < 8; ++t) { S += red[t]; Q += red[8 + t]; }
  float mean = S * (1.f / 512.f);
  float var = fmaxf(Q * (1.f / 512.f) - mean * mean, 0.f);
  float rstd = rsqrtf(var + 1e-5f);
  float y = (acc - mean) * rstd * lng[c] + lnb[c];
  float ge = 0.5f * y * (1.f + erff(y * 0.70710678118654752f));  // exact gelu
  hout[g * 512 + c] = ge;
}

__global__ __launch_bounds__(512) void k_proj2(
    const float* __restrict__ h, const float* __restrict__ W,
    const float* __restrict__ b, float* __restrict__ out) {
  __shared__ float row[512];
  __shared__ float red[8];
  int g = blockIdx.x, c = threadIdx.x;
  row[c] = h[g * 512 + c];
  __syncthreads();
  float acc = b[c];
#pragma unroll 4
  for (int k = 0; k < 512; ++k) acc += row[k] * W[k * 512 + c];
  float sq = acc * acc;
#pragma unroll
  for (int off = 1; off < 64; off <<= 1) sq += __shfl_xor(sq, off);
  int wv = threadIdx.x >> 6;
  if ((threadIdx.x & 63) == 0) red[wv] = sq;
  __syncthreads();
  float S = 0.f;
#pragma unroll
  for (int t = 0; t < 8; ++t) S += red[t];
  float norm = fmaxf(sqrtf(S), 1e-12f);
  out[g * 512 + c] = acc / norm;
}

// ---------------- launch ----------------
extern "C" void kernel_launch(void* const* d_in, const int* in_sizes, int n_in,
                              void* d_out, int out_size, void* d_ws, size_t ws_size,
                              hipStream_t stream) {
  const float* x_cont = (const float*)d_in[0];
  const int* x_class  = (const int*)d_in[1];
  const int* x_pitch  = (const int*)d_in[2];
  const int* ei       = (const int*)d_in[3];
  const int* batch    = (const int*)d_in[4];
  const float* ctab = (const float*)d_in[5];
  const float* ptab = (const float*)d_in[6];
  const float* Wl1 = (const float*)d_in[7];
  const float* bl1 = (const float*)d_in[8];
  const float* Wr1 = (const float*)d_in[9];
  const float* br1 = (const float*)d_in[10];
  const float* att1 = (const float*)d_in[11];
  const float* bias1 = (const float*)d_in[12];
  const float* ln1g = (const float*)d_in[13];
  const float* ln1b = (const float*)d_in[14];
  const float* Wl2 = (const float*)d_in[15];
  const float* bl2 = (const float*)d_in[16];
  const float* Wr2 = (const float*)d_in[17];
  const float* br2 = (const float*)d_in[18];
  const float* att2 = (const float*)d_in[19];
  const float* bias2 = (const float*)d_in[20];
  const float* ln2g = (const float*)d_in[21];
  const float* ln2b = (const float*)d_in[22];
  const float* Wp1 = (const float*)d_in[23];
  const float* bp1 = (const float*)d_in[24];
  const float* lnpg = (const float*)d_in[25];
  const float* lnpb = (const float*)d_in[26];
  const float* Wp2 = (const float*)d_in[27];
  const float* bp2 = (const float*)d_in[28];
  float* out = (float*)d_out;
  (void)n_in; (void)out_size; (void)ws_size;

  int N = in_sizes[1];
  int E = in_sizes[3] / 2;
  int ET = E + N;
  int NB = cdiv(N, 256);  // scan blocks (<= 256)

  // ---- workspace layout (with aliasing) ----
  char* p = (char*)d_ws;
  ushort* xb   = (ushort*)p; p += (size_t)N * 160 * 2;
  ushort* W1t  = (ushort*)p; p += (size_t)1024 * 160 * 2;
  ushort* W2t  = (ushort*)p; p += (size_t)512 * 512 * 2;
  ushort* xlr1 = (ushort*)p; p += (size_t)N * 1024 * 2;  // also xlr2 (bf16 N*512)
  ushort* h1b  = (ushort*)p; p += (size_t)N * 512 * 2;   // also h2 (fp32 N*256, same bytes)
  float* pooled = (float*)p; p += (size_t)NG * 256 * 4;
  int* cnt     = (int*)p;    p += NG * 4;
  float* hproj = (float*)p;  p += (size_t)NG * 512 * 4;
  int* deg     = (int*)p;    p += (size_t)N * 4;
  int* fill    = (int*)p;    p += (size_t)N * 4;
  int* rowptr  = (int*)p;    p += (size_t)(N + 1) * 4;
  int* csr     = (int*)p;    p += (size_t)ET * 4;
  int* bsum    = (int*)p;    p += 256 * 4;
  int* boff    = (int*)p;    p += 256 * 4;
  ushort* xlr2 = xlr1;
  float* h2   = (float*)h1b;

  const int* esrc = ei;
  const int* edst = ei + E;

  hipMemsetAsync(deg, 0, (size_t)2 * N * sizeof(int), stream);
  hipMemsetAsync(pooled, 0, (size_t)NG * 256 * sizeof(float) + NG * sizeof(int), stream);

  int prep_total = N * 160 + 1024 * 160 + 512 * 512 + ET;
  k_prep<<<cdiv(prep_total, 256), 256, 0, stream>>>(
      x_cont, x_class, x_pitch, ctab, ptab, Wl1, Wr1, Wl2, Wr2, edst,
      xb, W1t, W2t, deg, N, E);
  k_bsum<<<NB, 256, 0, stream>>>(deg, bsum, N);
  k_scanb<<<1, 256, 0, stream>>>(bsum, boff, NB);
  k_scanc<<<NB, 256, 0, stream>>>(deg, boff, rowptr, N);
  k_scatter<<<cdiv(ET, 256), 256, 0, stream>>>(esrc, edst, rowptr, fill, csr, E, N);

  dim3 g1(cdiv(N, GBM), 1024 / GBN);
  k_gemm_mfma<<<g1, 256, 0, stream>>>(xb, W1t, bl1, br1, 512, xlr1, N, 160, 1024);
  k_gat1<<<cdiv(N * 64, 256), 256, 0, stream>>>(xlr1, rowptr, csr, att1, bias1, ln1g, ln1b, h1b, N);

  dim3 g2(cdiv(N, GBM), 512 / GBN);
  k_gemm_mfma<<<g2, 256, 0, stream>>>(h1b, W2t, bl2, br2, 256, xlr2, N, 512, 512);
  k_gat2<<<cdiv(N * 64, 256), 256, 0, stream>>>(xlr2, rowptr, csr, att2, bias2, ln2g, ln2b, h2, N);

  k_pool<<<cdiv(N, 64), 256, 0, stream>>>(h2, batch, pooled, cnt, N);
  k_proj1<<<NG, 512, 0, stream>>>(pooled, cnt, Wp1, bp1, lnpg, lnpb, hproj);
  k_proj2<<<NG, 512, 0, stream>>>(hproj, Wp2, bp2, out);
}

// Round 7
// 342.048 us; speedup vs baseline: 3.0163x; 1.0190x over previous
//
#include <hip/hip_runtime.h>
#include <math.h>

#define NG 64   // graphs

typedef short bf16x8 __attribute__((ext_vector_type(8)));
typedef short bf16x4 __attribute__((ext_vector_type(4)));
typedef float f32x4 __attribute__((ext_vector_type(4)));
typedef float f32x2 __attribute__((ext_vector_type(2)));

static inline int cdiv(int a, int b) { return (a + b - 1) / b; }

__device__ inline ushort f2b(float f) {
  union { float f; uint u; } v; v.f = f;
  uint u = v.u;
  return (ushort)((u + 0x7fffu + ((u >> 16) & 1u)) >> 16);
}
__device__ inline float b2f(ushort h) {
  union { uint u; float f; } v; v.u = ((uint)h) << 16;
  return v.f;
}

// unpack a packed pair of bf16 (in one u32) to f32x2 {lo, hi}
__device__ __forceinline__ f32x2 up2(uint u) {
  union { uint u; float f; } lo, hi;
  lo.u = u << 16;
  hi.u = u & 0xffff0000u;
  f32x2 r; r.x = lo.f; r.y = hi.f;
  return r;
}

// pure-VALU all-reduce (sum) within each 16-lane row via DPP row_ror
__device__ __forceinline__ float dppsum16(float x) {
  union { float f; int i; } a, b;
  a.f = x;
  b.i = __builtin_amdgcn_update_dpp(0, a.i, 0x121, 0xF, 0xF, true); a.f += b.f; // ror:1
  b.i = __builtin_amdgcn_update_dpp(0, a.i, 0x122, 0xF, 0xF, true); a.f += b.f; // ror:2
  b.i = __builtin_amdgcn_update_dpp(0, a.i, 0x124, 0xF, 0xF, true); a.f += b.f; // ror:4
  b.i = __builtin_amdgcn_update_dpp(0, a.i, 0x128, 0xF, 0xF, true); a.f += b.f; // ror:8
  return a.f;
}

// ---------------- fused prep: features + both weight transposes + degree hist ----------------
__global__ __launch_bounds__(256) void k_prep(
    const float* __restrict__ xc, const int* __restrict__ xcl,
    const int* __restrict__ xpi, const float* __restrict__ ctab,
    const float* __restrict__ ptab,
    const float* __restrict__ Wl1, const float* __restrict__ Wr1,
    const float* __restrict__ Wl2, const float* __restrict__ Wr2,
    const int* __restrict__ edst,
    ushort* __restrict__ xb, ushort* __restrict__ W1t, ushort* __restrict__ W2t,
    int* __restrict__ deg, int n, int E) {
  int t = blockIdx.x * blockDim.x + threadIdx.x;
  int T1 = n * 160;
  int T2 = T1 + 1024 * 160;
  int T3 = T2 + 512 * 512;
  int T4 = T3 + E + n;
  if (t < T1) {
    int node = t / 160, c = t % 160;
    float v;
    if (c < 6)        v = xc[node * 6 + c];
    else if (c < 70)  v = ctab[xcl[node] * 64 + (c - 6)];
    else if (c < 134) v = ptab[xpi[node] * 64 + (c - 70)];
    else              v = 0.f;
    xb[t] = f2b(v);
  } else if (t < T2) {
    int u = t - T1;
    int c = u / 160, k = u % 160;
    float v = 0.f;
    if (k < 134) v = (c < 512) ? Wl1[k * 512 + c] : Wr1[k * 512 + (c - 512)];
    W1t[u] = f2b(v);
  } else if (t < T3) {
    int u = t - T2;
    int c = u / 512, k = u % 512;
    float v = (c < 256) ? Wl2[k * 256 + c] : Wr2[k * 256 + (c - 256)];
    W2t[u] = f2b(v);
  } else if (t < T4) {
    int u = t - T3;
    if (u < E) atomicAdd(&deg[edst[u]], 1);
    else atomicAdd(&deg[u - E], 1);   // self loops
  }
}

// 3-phase scan: block sums -> scan sums -> per-block scan + offset
__global__ __launch_bounds__(256) void k_bsum(const int* __restrict__ deg,
                                              int* __restrict__ bsum, int n) {
  int i = blockIdx.x * 256 + threadIdx.x;
  int v = (i < n) ? deg[i] : 0;
#pragma unroll
  for (int off = 1; off < 64; off <<= 1) v += __shfl_xor(v, off);
  __shared__ int ws[4];
  if ((threadIdx.x & 63) == 0) ws[threadIdx.x >> 6] = v;
  __syncthreads();
  if (threadIdx.x == 0) bsum[blockIdx.x] = ws[0] + ws[1] + ws[2] + ws[3];
}

__global__ __launch_bounds__(256) void k_scanb(const int* __restrict__ bsum,
                                               int* __restrict__ boff, int nb) {
  int t = threadIdx.x, lane = t & 63;
  int v = (t < nb) ? bsum[t] : 0;
  int incl = v;
#pragma unroll
  for (int off = 1; off < 64; off <<= 1) {
    int u = __shfl_up(incl, off);
    if (lane >= off) incl += u;
  }
  __shared__ int wsum[4];
  if (lane == 63) wsum[t >> 6] = incl;
  __syncthreads();
  int add = 0;
  for (int w = 0; w < (t >> 6); ++w) add += wsum[w];
  if (t < nb) boff[t] = incl + add - v;  // exclusive
}

__global__ __launch_bounds__(256) void k_scanc(const int* __restrict__ deg,
                                               const int* __restrict__ boff,
                                               int* __restrict__ rowptr, int n) {
  int b = blockIdx.x, t = threadIdx.x, lane = t & 63;
  int i = b * 256 + t;
  int v = (i < n) ? deg[i] : 0;
  int incl = v;
#pragma unroll
  for (int off = 1; off < 64; off <<= 1) {
    int u = __shfl_up(incl, off);
    if (lane >= off) incl += u;
  }
  __shared__ int wsum[4];
  if (lane == 63) wsum[t >> 6] = incl;
  __syncthreads();
  int add = boff[b];
  for (int w = 0; w < (t >> 6); ++w) add += wsum[w];
  if (i < n) rowptr[i + 1] = incl + add;
  if (i == 0) rowptr[0] = 0;
}

__global__ __launch_bounds__(256) void k_scatter(
    const int* __restrict__ src, const int* __restrict__ dst,
    const int* __restrict__ rowptr, int* __restrict__ fill,
    int* __restrict__ csr, int E, int N) {
  int t = blockIdx.x * blockDim.x + threadIdx.x;
  int s, d;
  if (t < E) { s = src[t]; d = dst[t]; }
  else if (t < E + N) { s = t - E; d = t - E; }
  else return;
  int pos = rowptr[d] + atomicAdd(&fill[d], 1);
  csr[pos] = s;
}

// ---------------- bf16 MFMA GEMM: C[M,NC] = A[M,Kp] @ Bt[NC,Kp]^T + bias -> bf16 ----------------
#define GBM 128
#define GBN 128
#define GBK 32
#define ESTRIDE 136   // epilogue LDS row stride in u16 (272B, 16B-aligned)
__device__ __forceinline__ int swzf(int r, int s) {
  return r * 64 + ((s * 16) ^ (((r >> 1) & 3) << 4));
}
__global__ __launch_bounds__(256) void k_gemm_mfma(
    const ushort* __restrict__ A, const ushort* __restrict__ Bt,
    const float* __restrict__ blo, const float* __restrict__ bhi, int nhalf,
    ushort* __restrict__ C, int M, int Kp, int NC) {
  __shared__ ushort smem[GBM * ESTRIDE];  // 34816 B; aliases sA/sB in main loop
  ushort* sA = smem;
  ushort* sB = smem + GBM * GBK;
  int tid = threadIdx.x;
  int lane = tid & 63, w = tid >> 6;
  int wr = w >> 1, wc = w & 1;
  int row0 = blockIdx.x * GBM, col0 = blockIdx.y * GBN;
  int nK = Kp / GBK;

  int rs = tid >> 2, ss = tid & 3;
  int wO0 = swzf(rs, ss);
  int wO1 = swzf(rs + 64, ss);
  bool okA0 = (row0 + rs) < M;
  bool okA1 = (row0 + rs + 64) < M;
  size_t baseA0 = (size_t)(row0 + rs) * Kp + ss * 8;
  size_t baseA1 = (size_t)(row0 + rs + 64) * Kp + ss * 8;
  size_t baseB0 = (size_t)(col0 + rs) * Kp + ss * 8;
  size_t baseB1 = (size_t)(col0 + rs + 64) * Kp + ss * 8;

  int fr = lane & 15, kq = lane >> 4;
  int aoff[4], boff[4];
#pragma unroll
  for (int m = 0; m < 4; ++m) {
    int ra = wr * 64 + m * 16 + fr;
    aoff[m] = ra * 64 + ((kq * 16) ^ (((ra >> 1) & 3) << 4));
    int rb = wc * 64 + m * 16 + fr;
    boff[m] = rb * 64 + ((kq * 16) ^ (((rb >> 1) & 3) << 4));
  }

  f32x4 acc[4][4] = {};
  bf16x8 zz = {};
  bf16x8 pa0, pa1, pb0, pb1, qa0, qa1, qb0, qb1;

#define LOADG(KS, RA0, RA1, RB0, RB1)                                   \
  do {                                                                  \
    const ushort* ap = A + (size_t)(KS) * GBK;                          \
    const ushort* bp = Bt + (size_t)(KS) * GBK;                         \
    RA0 = okA0 ? *(const bf16x8*)(ap + baseA0) : zz;                    \
    RA1 = okA1 ? *(const bf16x8*)(ap + baseA1) : zz;                    \
    RB0 = *(const bf16x8*)(bp + baseB0);                                \
    RB1 = *(const bf16x8*)(bp + baseB1);                                \
  } while (0)

#define STAGE(RA0, RA1, RB0, RB1)                                       \
  do {                                                                  \
    *(bf16x8*)((char*)sA + wO0) = RA0;                                  \
    *(bf16x8*)((char*)sA + wO1) = RA1;                                  \
    *(bf16x8*)((char*)sB + wO0) = RB0;                                  \
    *(bf16x8*)((char*)sB + wO1) = RB1;                                  \
  } while (0)

#define COMPUTE()                                                       \
  do {                                                                  \
    bf16x8 av[4], bv[4];                                                \
    _Pragma("unroll") for (int m = 0; m < 4; ++m)                       \
        av[m] = *(const bf16x8*)((const char*)sA + aoff[m]);            \
    _Pragma("unroll") for (int n = 0; n < 4; ++n)                       \
        bv[n] = *(const bf16x8*)((const char*)sB + boff[n]);            \
    _Pragma("unroll") for (int m = 0; m < 4; ++m)                       \
        _Pragma("unroll") for (int n = 0; n < 4; ++n)                   \
            acc[m][n] = __builtin_amdgcn_mfma_f32_16x16x32_bf16(        \
                av[m], bv[n], acc[m][n], 0, 0, 0);                      \
  } while (0)

  LOADG(0, pa0, pa1, pb0, pb1);
  for (int ks = 0; ks < nK; ++ks) {
    __syncthreads();
    if (ks & 1) {
      STAGE(qa0, qa1, qb0, qb1);
      if (ks + 1 < nK) LOADG(ks + 1, pa0, pa1, pb0, pb1);
    } else {
      STAGE(pa0, pa1, pb0, pb1);
      if (ks + 1 < nK) LOADG(ks + 1, qa0, qa1, qb0, qb1);
    }
    __syncthreads();
    COMPUTE();
  }

  // ---- epilogue: stage tile in LDS, then coalesced bf16x8 stores ----
  __syncthreads();  // sA/sB dead; reuse smem as tile
#pragma unroll
  for (int m = 0; m < 4; ++m) {
#pragma unroll
    for (int n = 0; n < 4; ++n) {
      int tc = wc * 64 + n * 16 + fr;
      float bv = ((col0 + tc) < nhalf) ? blo[col0 + tc] : bhi[col0 + tc - nhalf];
#pragma unroll
      for (int j = 0; j < 4; ++j) {
        int tr = wr * 64 + m * 16 + kq * 4 + j;
        smem[tr * ESTRIDE + tc] = f2b(acc[m][n][j] + bv);
      }
    }
  }
  __syncthreads();
  int r0 = tid >> 4, cb = (tid & 15) * 8;
#pragma unroll
  for (int pass = 0; pass < 8; ++pass) {
    int r = pass * 16 + r0;
    int grow = row0 + r;
    if (grow < M) {
      bf16x8 vv = *(const bf16x8*)&smem[r * ESTRIDE + cb];
      *(bf16x8*)&C[(size_t)grow * NC + col0 + cb] = vv;
    }
  }
#undef LOADG
#undef STAGE
#undef COMPUTE
}

// ---------------- GAT layer 1 aggregate (H=4, C=128) + bias + LN + ELU -> bf16 ----------------
// xlr: [N][1024] bf16 (2048 B/row), cols 0..511 = xl, 512..1023 = xr. out: [N][512] bf16.
// att.lrelu(t) == att.max(t,0) + (0.2att).min(t,0) exactly; max-free softmax w = exp(pe-8).
// f32x2-packed math (v_pk_*_f32), DPP rotate-reduce (no LDS in loop), 4-deep ring.
__global__ __launch_bounds__(256, 4) void k_gat1(
    const ushort* __restrict__ xlr,
    const int* __restrict__ rowptr, const int* __restrict__ csr,
    const float* __restrict__ att, const float* __restrict__ bias,
    const float* __restrict__ lng, const float* __restrict__ lnb,
    ushort* __restrict__ out, int n) {
  int wid = (blockIdx.x * blockDim.x + threadIdx.x) >> 6;
  int lane = threadIdx.x & 63;
  if (wid >= n) return;
  int base = lane * 8;
  uint laneB = (uint)lane * 16u;
  const char* xb8 = (const char*)xlr;
  f32x2 xr2[4], atM[4], atm[4];
  {
    union { bf16x8 b; uint u[4]; } t;
    t.b = *(const bf16x8*)(xb8 + ((uint)wid * 2048u + 1024u + laneB));
#pragma unroll
    for (int q = 0; q < 4; ++q) xr2[q] = up2(t.u[q]);
    const float* ap = &att[base];
#pragma unroll
    for (int q = 0; q < 4; ++q) {
      atM[q].x = ap[2 * q]; atM[q].y = ap[2 * q + 1];
      atm[q] = atM[q] * 0.2f;
    }
  }
  f32x2 z2 = {0.f, 0.f};
  float s = 0.f;
  f32x2 acc2[4] = {z2, z2, z2, z2};
  int e0 = rowptr[wid], e1 = rowptr[wid + 1];
  int last = e1 - 1;

#define LROW1(IDX) (*(const bf16x8*)(xb8 + (((uint)csr[IDX]) * 2048u + laneB)))
  bf16x8 r0 = LROW1(e0);
  bf16x8 r1 = LROW1(min(e0 + 1, last));
  bf16x8 r2 = LROW1(min(e0 + 2, last));
  bf16x8 r3 = LROW1(min(e0 + 3, last));

  for (int pp = e0; pp < e1; pp += 4) {
    union { bf16x8 b; uint u[4]; } c0, c1, c2, c3;
    c0.b = r0; c1.b = r1; c2.b = r2; c3.b = r3;
    if (pp + 4 < e1) {
      r0 = LROW1(pp + 4);
      r1 = LROW1(min(pp + 5, last));
      r2 = LROW1(min(pp + 6, last));
      r3 = LROW1(min(pp + 7, last));
    }
    f32x2 v0[4], v1[4], v2[4], v3[4];
#pragma unroll
    for (int q = 0; q < 4; ++q) {
      v0[q] = up2(c0.u[q]); v1[q] = up2(c1.u[q]);
      v2[q] = up2(c2.u[q]); v3[q] = up2(c3.u[q]);
    }
    f32x2 pv0 = z2, pv1 = z2, pv2 = z2, pv3 = z2;
#pragma unroll
    for (int q = 0; q < 4; ++q) {
      f32x2 t0 = v0[q] + xr2[q];
      f32x2 t1 = v1[q] + xr2[q];
      f32x2 t2 = v2[q] + xr2[q];
      f32x2 t3 = v3[q] + xr2[q];
      pv0 = __builtin_elementwise_fma(atM[q], __builtin_elementwise_max(t0, z2),
            __builtin_elementwise_fma(atm[q], __builtin_elementwise_min(t0, z2), pv0));
      pv1 = __builtin_elementwise_fma(atM[q], __builtin_elementwise_max(t1, z2),
            __builtin_elementwise_fma(atm[q], __builtin_elementwise_min(t1, z2), pv1));
      pv2 = __builtin_elementwise_fma(atM[q], __builtin_elementwise_max(t2, z2),
            __builtin_elementwise_fma(atm[q], __builtin_elementwise_min(t2, z2), pv2));
      pv3 = __builtin_elementwise_fma(atM[q], __builtin_elementwise_max(t3, z2),
            __builtin_elementwise_fma(atm[q], __builtin_elementwise_min(t3, z2), pv3));
    }
    float pe0 = dppsum16(pv0.x + pv0.y);
    float pe1 = dppsum16(pv1.x + pv1.y);
    float pe2 = dppsum16(pv2.x + pv2.y);
    float pe3 = dppsum16(pv3.x + pv3.y);
    float w0 = __expf(pe0 - 8.f);
    float w1 = (pp + 1 <= last) ? __expf(pe1 - 8.f) : 0.f;
    float w2 = (pp + 2 <= last) ? __expf(pe2 - 8.f) : 0.f;
    float w3 = (pp + 3 <= last) ? __expf(pe3 - 8.f) : 0.f;
    s += (w0 + w1) + (w2 + w3);
    f32x2 w02 = {w0, w0}, w12 = {w1, w1}, w22 = {w2, w2}, w32 = {w3, w3};
#pragma unroll
    for (int q = 0; q < 4; ++q) {
      f32x2 a = __builtin_elementwise_fma(w02, v0[q], acc2[q]);
      a = __builtin_elementwise_fma(w12, v1[q], a);
      a = __builtin_elementwise_fma(w22, v2[q], a);
      acc2[q] = __builtin_elementwise_fma(w32, v3[q], a);
    }
  }
#undef LROW1
  float inv = 1.f / s;
  float o[8];
#pragma unroll
  for (int q = 0; q < 4; ++q) {
    o[2 * q]     = acc2[q].x * inv + bias[base + 2 * q];
    o[2 * q + 1] = acc2[q].y * inv + bias[base + 2 * q + 1];
  }
  float sum = 0.f, sq = 0.f;
#pragma unroll
  for (int j = 0; j < 8; ++j) { sum += o[j]; sq += o[j] * o[j]; }
  sum = dppsum16(sum); sq = dppsum16(sq);
  sum += __shfl_xor(sum, 16); sq += __shfl_xor(sq, 16);
  sum += __shfl_xor(sum, 32); sq += __shfl_xor(sq, 32);
  float mean = sum * (1.f / 512.f);
  float var = fmaxf(sq * (1.f / 512.f) - mean * mean, 0.f);
  float rstd = rsqrtf(var + 1e-5f);
  bf16x8 ov;
#pragma unroll
  for (int j = 0; j < 8; ++j) {
    float y = (o[j] - mean) * rstd * lng[base + j] + lnb[base + j];
    y = y > 0.f ? y : __expf(y) - 1.f;   // ELU
    ov[j] = (short)f2b(y);
  }
  *(bf16x8*)&out[(size_t)wid * 512 + base] = ov;
}

// ---------------- GAT layer 2 aggregate (H=1, C=256) + bias + LN + ELU ----------------
// xlr: [N][512] bf16 (1024 B/row), cols 0..255 = xl, 256..511 = xr. out fp32 [N][256].
__global__ __launch_bounds__(256, 4) void k_gat2(
    const ushort* __restrict__ xlr,
    const int* __restrict__ rowptr, const int* __restrict__ csr,
    const float* __restrict__ att, const float* __restrict__ bias,
    const float* __restrict__ lng, const float* __restrict__ lnb,
    float* __restrict__ out, int n) {
  int wid = (blockIdx.x * blockDim.x + threadIdx.x) >> 6;
  int lane = threadIdx.x & 63;
  if (wid >= n) return;
  int base = lane * 4;
  uint laneB = (uint)lane * 8u;
  const char* xb8 = (const char*)xlr;
  f32x2 xr2[2], atM[2], atm[2];
  {
    union { bf16x4 b; uint u[2]; } t;
    t.b = *(const bf16x4*)(xb8 + ((uint)wid * 1024u + 512u + laneB));
#pragma unroll
    for (int q = 0; q < 2; ++q) xr2[q] = up2(t.u[q]);
    const float* ap = &att[base];
#pragma unroll
    for (int q = 0; q < 2; ++q) {
      atM[q].x = ap[2 * q]; atM[q].y = ap[2 * q + 1];
      atm[q] = atM[q] * 0.2f;
    }
  }
  f32x2 z2 = {0.f, 0.f};
  float s = 0.f;
  f32x2 acc2[2] = {z2, z2};
  int e0 = rowptr[wid], e1 = rowptr[wid + 1];
  int last = e1 - 1;

#define LROW2(IDX) (*(const bf16x4*)(xb8 + (((uint)csr[IDX]) * 1024u + laneB)))
  bf16x4 r0 = LROW2(e0);
  bf16x4 r1 = LROW2(min(e0 + 1, last));
  bf16x4 r2 = LROW2(min(e0 + 2, last));
  bf16x4 r3 = LROW2(min(e0 + 3, last));

  for (int pp = e0; pp < e1; pp += 4) {
    union { bf16x4 b; uint u[2]; } c0, c1, c2, c3;
    c0.b = r0; c1.b = r1; c2.b = r2; c3.b = r3;
    if (pp + 4 < e1) {
      r0 = LROW2(pp + 4);
      r1 = LROW2(min(pp + 5, last));
      r2 = LROW2(min(pp + 6, last));
      r3 = LROW2(min(pp + 7, last));
    }
    f32x2 v0[2], v1[2], v2[2], v3[2];
#pragma unroll
    for (int q = 0; q < 2; ++q) {
      v0[q] = up2(c0.u[q]); v1[q] = up2(c1.u[q]);
      v2[q] = up2(c2.u[q]); v3[q] = up2(c3.u[q]);
    }
    f32x2 pv0 = z2, pv1 = z2, pv2 = z2, pv3 = z2;
#pragma unroll
    for (int q = 0; q < 2; ++q) {
      f32x2 t0 = v0[q] + xr2[q];
      f32x2 t1 = v1[q] + xr2[q];
      f32x2 t2 = v2[q] + xr2[q];
      f32x2 t3 = v3[q] + xr2[q];
      pv0 = __builtin_elementwise_fma(atM[q], __builtin_elementwise_max(t0, z2),
            __builtin_elementwise_fma(atm[q], __builtin_elementwise_min(t0, z2), pv0));
      pv1 = __builtin_elementwise_fma(atM[q], __builtin_elementwise_max(t1, z2),
            __builtin_elementwise_fma(atm[q], __builtin_elementwise_min(t1, z2), pv1));
      pv2 = __builtin_elementwise_fma(atM[q], __builtin_elementwise_max(t2, z2),
            __builtin_elementwise_fma(atm[q], __builtin_elementwise_min(t2, z2), pv2));
      pv3 = __builtin_elementwise_fma(atM[q], __builtin_elementwise_max(t3, z2),
            __builtin_elementwise_fma(atm[q], __builtin_elementwise_min(t3, z2), pv3));
    }
    float pe0 = dppsum16(pv0.x + pv0.y);
    float pe1 = dppsum16(pv1.x + pv1.y);
    float pe2 = dppsum16(pv2.x + pv2.y);
    float pe3 = dppsum16(pv3.x + pv3.y);
    pe0 += __shfl_xor(pe0, 16); pe1 += __shfl_xor(pe1, 16);
    pe2 += __shfl_xor(pe2, 16); pe3 += __shfl_xor(pe3, 16);
    pe0 += __shfl_xor(pe0, 32); pe1 += __shfl_xor(pe1, 32);
    pe2 += __shfl_xor(pe2, 32); pe3 += __shfl_xor(pe3, 32);
    float w0 = __expf(pe0 - 8.f);
    float w1 = (pp + 1 <= last) ? __expf(pe1 - 8.f) : 0.f;
    float w2 = (pp + 2 <= last) ? __expf(pe2 - 8.f) : 0.f;
    float w3 = (pp + 3 <= last) ? __expf(pe3 - 8.f) : 0.f;
    s += (w0 + w1) + (w2 + w3);
    f32x2 w02 = {w0, w0}, w12 = {w1, w1}, w22 = {w2, w2}, w32 = {w3, w3};
#pragma unroll
    for (int q = 0; q < 2; ++q) {
      f32x2 a = __builtin_elementwise_fma(w02, v0[q], acc2[q]);
      a = __builtin_elementwise_fma(w12, v1[q], a);
      a = __builtin_elementwise_fma(w22, v2[q], a);
      acc2[q] = __builtin_elementwise_fma(w32, v3[q], a);
    }
  }
#undef LROW2
  float inv = 1.f / s;
  float o[4];
#pragma unroll
  for (int q = 0; q < 2; ++q) {
    o[2 * q]     = acc2[q].x * inv + bias[base + 2 * q];
    o[2 * q + 1] = acc2[q].y * inv + bias[base + 2 * q + 1];
  }
  float sum = 0.f, sq = 0.f;
#pragma unroll
  for (int j = 0; j < 4; ++j) { sum += o[j]; sq += o[j] * o[j]; }
  sum = dppsum16(sum); sq = dppsum16(sq);
  sum += __shfl_xor(sum, 16); sq += __shfl_xor(sq, 16);
  sum += __shfl_xor(sum, 32); sq += __shfl_xor(sq, 32);
  float mean = sum * (1.f / 256.f);
  float var = fmaxf(sq * (1.f / 256.f) - mean * mean, 0.f);
  float rstd = rsqrtf(var + 1e-5f);
#pragma unroll
  for (int j = 0; j < 4; ++j) {
    float y = (o[j] - mean) * rstd * lng[base + j] + lnb[base + j];
    y = y > 0.f ? y : __expf(y) - 1.f;
    out[(size_t)wid * 256 + base + j] = y;
  }
}

// ---------------- pooling (batch is sorted), 64-row chunks ----------------
__global__ __launch_bounds__(256) void k_pool(
    const float* __restrict__ h2, const int* __restrict__ batch,
    float* __restrict__ pooled, int* __restrict__ cnt, int n) {
  int c = threadIdx.x;  // 256 channels
  int n0 = blockIdx.x * 64;
  int n1 = min(n0 + 64, n);
  if (n0 >= n) return;
  float acc = 0.f;
  int cur = batch[n0];
  int cl = 0;
  for (int i = n0; i < n1; ++i) {
    int bb = batch[i];
    if (bb != cur) {
      atomicAdd(&pooled[cur * 256 + c], acc);
      if (c == 0) atomicAdd(&cnt[cur], cl);
      acc = 0.f; cl = 0; cur = bb;
    }
    acc += h2[(size_t)i * 256 + c];
    cl++;
  }
  atomicAdd(&pooled[cur * 256 + c], acc);
  if (c == 0) atomicAdd(&cnt[cur], cl);
}

// ---------------- projection head ----------------
__global__ __launch_bounds__(512) void k_proj1(
    const float* __restrict__ pooled, const int* __restrict__ cnt,
    const float* __restrict__ W, const float* __restrict__ b,
    const float* __restrict__ lng, const float* __restrict__ lnb,
    float* __restrict__ hout) {
  __shared__ float row[256];
  __shared__ float red[16];
  int g = blockIdx.x, c = threadIdx.x;
  if (c < 256) {
    float cc = fmaxf((float)cnt[g], 1.f);
    row[c] = pooled[g * 256 + c] / cc;
  }
  __syncthreads();
  float acc = b[c];
#pragma unroll 4
  for (int k = 0; k < 256; ++k) acc += row[k] * W[k * 512 + c];
  float sum = acc, sq = acc * acc;
#pragma unroll
  for (int off = 1; off < 64; off <<= 1) {
    sum += __shfl_xor(sum, off);
    sq += __shfl_xor(sq, off);
  }
  int wv = threadIdx.x >> 6;
  if ((threadIdx.x & 63) == 0) { red[wv] = sum; red[8 + wv] = sq; }
  __syncthreads();
  float S = 0.f, Q = 0.f;
#pragma unroll
  for (int t = 0; t < 8; ++t) { S += red[t]; Q += red[8 + t]; }
  float mean = S * (1.f / 512.f);
  float var = fmaxf(Q * (1.f / 512.f) - mean * mean, 0.f);
  float rstd = rsqrtf(var + 1e-5f);
  float y = (acc - mean) * rstd * lng[c] + lnb[c];
  float ge = 0.5f * y * (1.f + erff(y * 0.70710678118654752f));  // exact gelu
  hout[g * 512 + c] = ge;
}

__global__ __launch_bounds__(512) void k_proj2(
    const float* __restrict__ h, const float* __restrict__ W,
    const float* __restrict__ b, float* __restrict__ out) {
  __shared__ float row[512];
  __shared__ float red[8];
  int g = blockIdx.x, c = threadIdx.x;
  row[c] = h[g * 512 + c];
  __syncthreads();
  float acc = b[c];
#pragma unroll 4
  for (int k = 0; k < 512; ++k) acc += row[k] * W[k * 512 + c];
  float sq = acc * acc;
#pragma unroll
  for (int off = 1; off < 64; off <<= 1) sq += __shfl_xor(sq, off);
  int wv = threadIdx.x >> 6;
  if ((threadIdx.x & 63) == 0) red[wv] = sq;
  __syncthreads();
  float S = 0.f;
#pragma unroll
  for (int t = 0; t < 8; ++t) S += red[t];
  float norm = fmaxf(sqrtf(S), 1e-12f);
  out[g * 512 + c] = acc / norm;
}

// ---------------- launch ----------------
extern "C" void kernel_launch(void* const* d_in, const int* in_sizes, int n_in,
                              void* d_out, int out_size, void* d_ws, size_t ws_size,
                              hipStream_t stream) {
  const float* x_cont = (const float*)d_in[0];
  const int* x_class  = (const int*)d_in[1];
  const int* x_pitch  = (const int*)d_in[2];
  const int* ei       = (const int*)d_in[3];
  const int* batch    = (const int*)d_in[4];
  const float* ctab = (const float*)d_in[5];
  const float* ptab = (const float*)d_in[6];
  const float* Wl1 = (const float*)d_in[7];
  const float* bl1 = (const float*)d_in[8];
  const float* Wr1 = (const float*)d_in[9];
  const float* br1 = (const float*)d_in[10];
  const float* att1 = (const float*)d_in[11];
  const float* bias1 = (const float*)d_in[12];
  const float* ln1g = (const float*)d_in[13];
  const float* ln1b = (const float*)d_in[14];
  const float* Wl2 = (const float*)d_in[15];
  const float* bl2 = (const float*)d_in[16];
  const float* Wr2 = (const float*)d_in[17];
  const float* br2 = (const float*)d_in[18];
  const float* att2 = (const float*)d_in[19];
  const float* bias2 = (const float*)d_in[20];
  const float* ln2g = (const float*)d_in[21];
  const float* ln2b = (const float*)d_in[22];
  const float* Wp1 = (const float*)d_in[23];
  const float* bp1 = (const float*)d_in[24];
  const float* lnpg = (const float*)d_in[25];
  const float* lnpb = (const float*)d_in[26];
  const float* Wp2 = (const float*)d_in[27];
  const float* bp2 = (const float*)d_in[28];
  float* out = (float*)d_out;
  (void)n_in; (void)out_size; (void)ws_size;

  int N = in_sizes[1];
  int E = in_sizes[3] / 2;
  int ET = E + N;
  int NB = cdiv(N, 256);  // scan blocks (<= 256)

  // ---- workspace layout (with aliasing) ----
  char* p = (char*)d_ws;
  ushort* xb   = (ushort*)p; p += (size_t)N * 160 * 2;
  ushort* W1t  = (ushort*)p; p += (size_t)1024 * 160 * 2;
  ushort* W2t  = (ushort*)p; p += (size_t)512 * 512 * 2;
  ushort* xlr1 = (ushort*)p; p += (size_t)N * 1024 * 2;  // also xlr2 (bf16 N*512)
  ushort* h1b  = (ushort*)p; p += (size_t)N * 512 * 2;   // also h2 (fp32 N*256, same bytes)
  float* pooled = (float*)p; p += (size_t)NG * 256 * 4;
  int* cnt     = (int*)p;    p += NG * 4;
  float* hproj = (float*)p;  p += (size_t)NG * 512 * 4;
  int* deg     = (int*)p;    p += (size_t)N * 4;
  int* fill    = (int*)p;    p += (size_t)N * 4;
  int* rowptr  = (int*)p;    p += (size_t)(N + 1) * 4;
  int* csr     = (int*)p;    p += (size_t)ET * 4;
  int* bsum    = (int*)p;    p += 256 * 4;
  int* boff    = (int*)p;    p += 256 * 4;
  ushort* xlr2 = xlr1;
  float* h2   = (float*)h1b;

  const int* esrc = ei;
  const int* edst = ei + E;

  hipMemsetAsync(deg, 0, (size_t)2 * N * sizeof(int), stream);
  hipMemsetAsync(pooled, 0, (size_t)NG * 256 * sizeof(float) + NG * sizeof(int), stream);

  int prep_total = N * 160 + 1024 * 160 + 512 * 512 + ET;
  k_prep<<<cdiv(prep_total, 256), 256, 0, stream>>>(
      x_cont, x_class, x_pitch, ctab, ptab, Wl1, Wr1, Wl2, Wr2, edst,
      xb, W1t, W2t, deg, N, E);
  k_bsum<<<NB, 256, 0, stream>>>(deg, bsum, N);
  k_scanb<<<1, 256, 0, stream>>>(bsum, boff, NB);
  k_scanc<<<NB, 256, 0, stream>>>(deg, boff, rowptr, N);
  k_scatter<<<cdiv(ET, 256), 256, 0, stream>>>(esrc, edst, rowptr, fill, csr, E, N);

  dim3 g1(cdiv(N, GBM), 1024 / GBN);
  k_gemm_mfma<<<g1, 256, 0, stream>>>(xb, W1t, bl1, br1, 512, xlr1, N, 160, 1024);
  k_gat1<<<cdiv(N * 64, 256), 256, 0, stream>>>(xlr1, rowptr, csr, att1, bias1, ln1g, ln1b, h1b, N);

  dim3 g2(cdiv(N, GBM), 512 / GBN);
  k_gemm_mfma<<<g2, 256, 0, stream>>>(h1b, W2t, bl2, br2, 256, xlr2, N, 512, 512);
  k_gat2<<<cdiv(N * 64, 256), 256, 0, stream>>>(xlr2, rowptr, csr, att2, bias2, ln2g, ln2b, h2, N);

  k_pool<<<cdiv(N, 64), 256, 0, stream>>>(h2, batch, pooled, cnt, N);
  k_proj1<<<NG, 512, 0, stream>>>(pooled, cnt, Wp1, bp1, lnpg, lnpb, hproj);
  k_proj2<<<NG, 512, 0, stream>>>(hproj, Wp2, bp2, out);
}

// Round 8
// 337.980 us; speedup vs baseline: 3.0526x; 1.0120x over previous
//
#include <hip/hip_runtime.h>
#include <math.h>

#define NG 64   // graphs

typedef short bf16x8 __attribute__((ext_vector_type(8)));
typedef short bf16x4 __attribute__((ext_vector_type(4)));
typedef float f32x4 __attribute__((ext_vector_type(4)));

#define LOG2E 1.4426950408889634f

static inline int cdiv(int a, int b) { return (a + b - 1) / b; }

__device__ inline ushort f2b(float f) {
  union { float f; uint u; } v; v.f = f;
  uint u = v.u;
  return (ushort)((u + 0x7fffu + ((u >> 16) & 1u)) >> 16);
}
__device__ inline float b2f(ushort h) {
  union { uint u; float f; } v; v.u = ((uint)h) << 16;
  return v.f;
}

__device__ __forceinline__ void unpack8(bf16x8 vb, float* v) {
  union { bf16x8 b; uint u[4]; } cv; cv.b = vb;
#pragma unroll
  for (int q = 0; q < 4; ++q) {
    union { uint u; float f; } lo, hi;
    lo.u = cv.u[q] << 16;
    hi.u = cv.u[q] & 0xffff0000u;
    v[2 * q] = lo.f; v[2 * q + 1] = hi.f;
  }
}
__device__ __forceinline__ void unpack4(bf16x4 vb, float* v) {
  union { bf16x4 b; uint u[2]; } cv; cv.b = vb;
#pragma unroll
  for (int q = 0; q < 2; ++q) {
    union { uint u; float f; } lo, hi;
    lo.u = cv.u[q] << 16;
    hi.u = cv.u[q] & 0xffff0000u;
    v[2 * q] = lo.f; v[2 * q + 1] = hi.f;
  }
}

// pure-VALU all-reduce (sum) within each 16-lane row via DPP row_ror
__device__ __forceinline__ float dppsum16(float x) {
  union { float f; int i; } a, b;
  a.f = x;
  b.i = __builtin_amdgcn_update_dpp(0, a.i, 0x121, 0xF, 0xF, true); a.f += b.f; // ror:1
  b.i = __builtin_amdgcn_update_dpp(0, a.i, 0x122, 0xF, 0xF, true); a.f += b.f; // ror:2
  b.i = __builtin_amdgcn_update_dpp(0, a.i, 0x124, 0xF, 0xF, true); a.f += b.f; // ror:4
  b.i = __builtin_amdgcn_update_dpp(0, a.i, 0x128, 0xF, 0xF, true); a.f += b.f; // ror:8
  return a.f;
}

// ---------------- fused prep: features + both weight transposes + degree hist ----------------
__global__ __launch_bounds__(256) void k_prep(
    const float* __restrict__ xc, const int* __restrict__ xcl,
    const int* __restrict__ xpi, const float* __restrict__ ctab,
    const float* __restrict__ ptab,
    const float* __restrict__ Wl1, const float* __restrict__ Wr1,
    const float* __restrict__ Wl2, const float* __restrict__ Wr2,
    const int* __restrict__ edst,
    ushort* __restrict__ xb, ushort* __restrict__ W1t, ushort* __restrict__ W2t,
    int* __restrict__ deg, int n, int E) {
  int t = blockIdx.x * blockDim.x + threadIdx.x;
  int T1 = n * 160;
  int T2 = T1 + 1024 * 160;
  int T3 = T2 + 512 * 512;
  int T4 = T3 + E + n;
  if (t < T1) {
    int node = t / 160, c = t % 160;
    float v;
    if (c < 6)        v = xc[node * 6 + c];
    else if (c < 70)  v = ctab[xcl[node] * 64 + (c - 6)];
    else if (c < 134) v = ptab[xpi[node] * 64 + (c - 70)];
    else              v = 0.f;
    xb[t] = f2b(v);
  } else if (t < T2) {
    int u = t - T1;
    int c = u / 160, k = u % 160;
    float v = 0.f;
    if (k < 134) v = (c < 512) ? Wl1[k * 512 + c] : Wr1[k * 512 + (c - 512)];
    W1t[u] = f2b(v);
  } else if (t < T3) {
    int u = t - T2;
    int c = u / 512, k = u % 512;
    float v = (c < 256) ? Wl2[k * 256 + c] : Wr2[k * 256 + (c - 256)];
    W2t[u] = f2b(v);
  } else if (t < T4) {
    int u = t - T3;
    if (u < E) atomicAdd(&deg[edst[u]], 1);
    else atomicAdd(&deg[u - E], 1);   // self loops
  }
}

// 3-phase scan: block sums -> scan sums -> per-block scan + offset
__global__ __launch_bounds__(256) void k_bsum(const int* __restrict__ deg,
                                              int* __restrict__ bsum, int n) {
  int i = blockIdx.x * 256 + threadIdx.x;
  int v = (i < n) ? deg[i] : 0;
#pragma unroll
  for (int off = 1; off < 64; off <<= 1) v += __shfl_xor(v, off);
  __shared__ int ws[4];
  if ((threadIdx.x & 63) == 0) ws[threadIdx.x >> 6] = v;
  __syncthreads();
  if (threadIdx.x == 0) bsum[blockIdx.x] = ws[0] + ws[1] + ws[2] + ws[3];
}

__global__ __launch_bounds__(256) void k_scanb(const int* __restrict__ bsum,
                                               int* __restrict__ boff, int nb) {
  int t = threadIdx.x, lane = t & 63;
  int v = (t < nb) ? bsum[t] : 0;
  int incl = v;
#pragma unroll
  for (int off = 1; off < 64; off <<= 1) {
    int u = __shfl_up(incl, off);
    if (lane >= off) incl += u;
  }
  __shared__ int wsum[4];
  if (lane == 63) wsum[t >> 6] = incl;
  __syncthreads();
  int add = 0;
  for (int w = 0; w < (t >> 6); ++w) add += wsum[w];
  if (t < nb) boff[t] = incl + add - v;  // exclusive
}

__global__ __launch_bounds__(256) void k_scanc(const int* __restrict__ deg,
                                               const int* __restrict__ boff,
                                               int* __restrict__ rowptr, int n) {
  int b = blockIdx.x, t = threadIdx.x, lane = t & 63;
  int i = b * 256 + t;
  int v = (i < n) ? deg[i] : 0;
  int incl = v;
#pragma unroll
  for (int off = 1; off < 64; off <<= 1) {
    int u = __shfl_up(incl, off);
    if (lane >= off) incl += u;
  }
  __shared__ int wsum[4];
  if (lane == 63) wsum[t >> 6] = incl;
  __syncthreads();
  int add = boff[b];
  for (int w = 0; w < (t >> 6); ++w) add += wsum[w];
  if (i < n) rowptr[i + 1] = incl + add;
  if (i == 0) rowptr[0] = 0;
}

// scatter + write 8 sentinel pads (row 0) past the end of csr
__global__ __launch_bounds__(256) void k_scatter(
    const int* __restrict__ src, const int* __restrict__ dst,
    const int* __restrict__ rowptr, int* __restrict__ fill,
    int* __restrict__ csr, int E, int N) {
  int t = blockIdx.x * blockDim.x + threadIdx.x;
  int s, d;
  if (t < E) { s = src[t]; d = dst[t]; }
  else if (t < E + N) { s = t - E; d = t - E; }
  else if (t < E + N + 8) { csr[t] = 0; return; }
  else return;
  int pos = rowptr[d] + atomicAdd(&fill[d], 1);
  csr[pos] = s;
}

// ---------------- bf16 MFMA GEMM: C[M,NC] = A[M,Kp] @ Bt[NC,Kp]^T + bias -> bf16 ----------------
#define GBM 128
#define GBN 128
#define GBK 32
#define ESTRIDE 136   // epilogue LDS row stride in u16 (272B, 16B-aligned)
__device__ __forceinline__ int swzf(int r, int s) {
  return r * 64 + ((s * 16) ^ (((r >> 1) & 3) << 4));
}
__global__ __launch_bounds__(256) void k_gemm_mfma(
    const ushort* __restrict__ A, const ushort* __restrict__ Bt,
    const float* __restrict__ blo, const float* __restrict__ bhi, int nhalf,
    ushort* __restrict__ C, int M, int Kp, int NC) {
  __shared__ ushort smem[GBM * ESTRIDE];  // 34816 B; aliases sA/sB in main loop
  ushort* sA = smem;
  ushort* sB = smem + GBM * GBK;
  int tid = threadIdx.x;
  int lane = tid & 63, w = tid >> 6;
  int wr = w >> 1, wc = w & 1;
  int row0 = blockIdx.x * GBM, col0 = blockIdx.y * GBN;
  int nK = Kp / GBK;

  int rs = tid >> 2, ss = tid & 3;
  int wO0 = swzf(rs, ss);
  int wO1 = swzf(rs + 64, ss);
  bool okA0 = (row0 + rs) < M;
  bool okA1 = (row0 + rs + 64) < M;
  size_t baseA0 = (size_t)(row0 + rs) * Kp + ss * 8;
  size_t baseA1 = (size_t)(row0 + rs + 64) * Kp + ss * 8;
  size_t baseB0 = (size_t)(col0 + rs) * Kp + ss * 8;
  size_t baseB1 = (size_t)(col0 + rs + 64) * Kp + ss * 8;

  int fr = lane & 15, kq = lane >> 4;
  int aoff[4], boff[4];
#pragma unroll
  for (int m = 0; m < 4; ++m) {
    int ra = wr * 64 + m * 16 + fr;
    aoff[m] = ra * 64 + ((kq * 16) ^ (((ra >> 1) & 3) << 4));
    int rb = wc * 64 + m * 16 + fr;
    boff[m] = rb * 64 + ((kq * 16) ^ (((rb >> 1) & 3) << 4));
  }

  f32x4 acc[4][4] = {};
  bf16x8 zz = {};
  bf16x8 pa0, pa1, pb0, pb1, qa0, qa1, qb0, qb1;

#define LOADG(KS, RA0, RA1, RB0, RB1)                                   \
  do {                                                                  \
    const ushort* ap = A + (size_t)(KS) * GBK;                          \
    const ushort* bp = Bt + (size_t)(KS) * GBK;                         \
    RA0 = okA0 ? *(const bf16x8*)(ap + baseA0) : zz;                    \
    RA1 = okA1 ? *(const bf16x8*)(ap + baseA1) : zz;                    \
    RB0 = *(const bf16x8*)(bp + baseB0);                                \
    RB1 = *(const bf16x8*)(bp + baseB1);                                \
  } while (0)

#define STAGE(RA0, RA1, RB0, RB1)                                       \
  do {                                                                  \
    *(bf16x8*)((char*)sA + wO0) = RA0;                                  \
    *(bf16x8*)((char*)sA + wO1) = RA1;                                  \
    *(bf16x8*)((char*)sB + wO0) = RB0;                                  \
    *(bf16x8*)((char*)sB + wO1) = RB1;                                  \
  } while (0)

#define COMPUTE()                                                       \
  do {                                                                  \
    bf16x8 av[4], bv[4];                                                \
    _Pragma("unroll") for (int m = 0; m < 4; ++m)                       \
        av[m] = *(const bf16x8*)((const char*)sA + aoff[m]);            \
    _Pragma("unroll") for (int n = 0; n < 4; ++n)                       \
        bv[n] = *(const bf16x8*)((const char*)sB + boff[n]);            \
    _Pragma("unroll") for (int m = 0; m < 4; ++m)                       \
        _Pragma("unroll") for (int n = 0; n < 4; ++n)                   \
            acc[m][n] = __builtin_amdgcn_mfma_f32_16x16x32_bf16(        \
                av[m], bv[n], acc[m][n], 0, 0, 0);                      \
  } while (0)

  LOADG(0, pa0, pa1, pb0, pb1);
  for (int ks = 0; ks < nK; ++ks) {
    __syncthreads();
    if (ks & 1) {
      STAGE(qa0, qa1, qb0, qb1);
      if (ks + 1 < nK) LOADG(ks + 1, pa0, pa1, pb0, pb1);
    } else {
      STAGE(pa0, pa1, pb0, pb1);
      if (ks + 1 < nK) LOADG(ks + 1, qa0, qa1, qb0, qb1);
    }
    __syncthreads();
    COMPUTE();
  }

  // ---- epilogue: stage tile in LDS, then coalesced bf16x8 stores ----
  __syncthreads();  // sA/sB dead; reuse smem as tile
#pragma unroll
  for (int m = 0; m < 4; ++m) {
#pragma unroll
    for (int n = 0; n < 4; ++n) {
      int tc = wc * 64 + n * 16 + fr;
      float bv = ((col0 + tc) < nhalf) ? blo[col0 + tc] : bhi[col0 + tc - nhalf];
#pragma unroll
      for (int j = 0; j < 4; ++j) {
        int tr = wr * 64 + m * 16 + kq * 4 + j;
        smem[tr * ESTRIDE + tc] = f2b(acc[m][n][j] + bv);
      }
    }
  }
  __syncthreads();
  int r0 = tid >> 4, cb = (tid & 15) * 8;
#pragma unroll
  for (int pass = 0; pass < 8; ++pass) {
    int r = pass * 16 + r0;
    int grow = row0 + r;
    if (grow < M) {
      bf16x8 vv = *(const bf16x8*)&smem[r * ESTRIDE + cb];
      *(bf16x8*)&C[(size_t)grow * NC + col0 + cb] = vv;
    }
  }
#undef LOADG
#undef STAGE
#undef COMPUTE
}

// ---------------- GAT layer 1 aggregate (H=4, C=128) + bias + LN + ELU -> bf16 ----------------
// xlr: [N][1024] bf16 (2048 B/row), cols 0..511 = xl, 512..1023 = xr. out: [N][512] bf16.
// Whole CSR walk is SCALARIZED (readfirstlane wid): rowptr/csr -> s_load, row bases -> SGPR,
// gathers -> saddr-form global_load with constant lane voffset. csr padded by 8 (row 0).
// pe(scaled) = sum a6.t + a4.|t| with a6=0.6*log2e*att, a4=0.4*log2e*att; w = exp2(pe-8*log2e).
__global__ __launch_bounds__(256, 4) void k_gat1(
    const ushort* __restrict__ xlr,
    const int* __restrict__ rowptr, const int* __restrict__ csr,
    const float* __restrict__ att, const float* __restrict__ bias,
    const float* __restrict__ lng, const float* __restrict__ lnb,
    ushort* __restrict__ out, int n) {
  int lane = threadIdx.x & 63;
  int wid = __builtin_amdgcn_readfirstlane((int)((blockIdx.x * blockDim.x + threadIdx.x) >> 6));
  if (wid >= n) return;
  int base = lane * 8;
  float xrv[8], a6[8], a4[8];
  {
    bf16x8 t = *(const bf16x8*)(xlr + (size_t)wid * 1024 + 512 + base);
    unpack8(t, xrv);
#pragma unroll
    for (int j = 0; j < 8; ++j) {
      float a = att[base + j] * LOG2E;
      a6[j] = 0.6f * a;
      a4[j] = 0.4f * a;
    }
  }
  float s = 0.f;
  float acc[8] = {};
  int e0 = rowptr[wid], e1 = rowptr[wid + 1];
  int last = e1 - 1;

#define LROW1(ROW) (*(const bf16x8*)(xlr + (size_t)(ROW) * 1024 + base))
  bf16x8 r0 = LROW1(csr[e0]);
  bf16x8 r1 = LROW1(csr[e0 + 1]);
  bf16x8 r2 = LROW1(csr[e0 + 2]);
  bf16x8 r3 = LROW1(csr[e0 + 3]);

  for (int pp = e0; pp < e1; pp += 4) {
    int i0 = csr[pp + 4], i1 = csr[pp + 5], i2 = csr[pp + 6], i3 = csr[pp + 7];
    bf16x8 c0 = r0, c1 = r1, c2 = r2, c3 = r3;
    r0 = LROW1(i0); r1 = LROW1(i1); r2 = LROW1(i2); r3 = LROW1(i3);
    float v0[8], v1[8], v2[8], v3[8];
    unpack8(c0, v0); unpack8(c1, v1); unpack8(c2, v2); unpack8(c3, v3);
    float p0 = 0.f, p1 = 0.f, p2 = 0.f, p3 = 0.f;
#pragma unroll
    for (int j = 0; j < 8; ++j) {
      float t0 = v0[j] + xrv[j];
      float t1 = v1[j] + xrv[j];
      float t2 = v2[j] + xrv[j];
      float t3 = v3[j] + xrv[j];
      p0 = fmaf(a6[j], t0, fmaf(a4[j], fabsf(t0), p0));
      p1 = fmaf(a6[j], t1, fmaf(a4[j], fabsf(t1), p1));
      p2 = fmaf(a6[j], t2, fmaf(a4[j], fabsf(t2), p2));
      p3 = fmaf(a6[j], t3, fmaf(a4[j], fabsf(t3), p3));
    }
    float pe0 = dppsum16(p0);
    float pe1 = dppsum16(p1);
    float pe2 = dppsum16(p2);
    float pe3 = dppsum16(p3);
    float w0 = exp2f(pe0 - 8.f * LOG2E);
    float w1 = (pp + 1 <= last) ? exp2f(pe1 - 8.f * LOG2E) : 0.f;
    float w2 = (pp + 2 <= last) ? exp2f(pe2 - 8.f * LOG2E) : 0.f;
    float w3 = (pp + 3 <= last) ? exp2f(pe3 - 8.f * LOG2E) : 0.f;
    s += (w0 + w1) + (w2 + w3);
#pragma unroll
    for (int j = 0; j < 8; ++j) {
      float t = fmaf(w0, v0[j], acc[j]);
      t = fmaf(w1, v1[j], t);
      t = fmaf(w2, v2[j], t);
      acc[j] = fmaf(w3, v3[j], t);
    }
  }
#undef LROW1
  float inv = 1.f / s;
  float o[8];
#pragma unroll
  for (int j = 0; j < 8; ++j) o[j] = acc[j] * inv + bias[base + j];
  float sum = 0.f, sq = 0.f;
#pragma unroll
  for (int j = 0; j < 8; ++j) { sum += o[j]; sq += o[j] * o[j]; }
  sum = dppsum16(sum); sq = dppsum16(sq);
  sum += __shfl_xor(sum, 16); sq += __shfl_xor(sq, 16);
  sum += __shfl_xor(sum, 32); sq += __shfl_xor(sq, 32);
  float mean = sum * (1.f / 512.f);
  float var = fmaxf(sq * (1.f / 512.f) - mean * mean, 0.f);
  float rstd = rsqrtf(var + 1e-5f);
  bf16x8 ov;
#pragma unroll
  for (int j = 0; j < 8; ++j) {
    float y = (o[j] - mean) * rstd * lng[base + j] + lnb[base + j];
    y = y > 0.f ? y : __expf(y) - 1.f;   // ELU
    ov[j] = (short)f2b(y);
  }
  *(bf16x8*)&out[(size_t)wid * 512 + base] = ov;
}

// ---------------- GAT layer 2 aggregate (H=1, C=256) + bias + LN + ELU ----------------
// xlr: [N][512] bf16 (1024 B/row), cols 0..255 = xl, 256..511 = xr. out fp32 [N][256].
__global__ __launch_bounds__(256, 4) void k_gat2(
    const ushort* __restrict__ xlr,
    const int* __restrict__ rowptr, const int* __restrict__ csr,
    const float* __restrict__ att, const float* __restrict__ bias,
    const float* __restrict__ lng, const float* __restrict__ lnb,
    float* __restrict__ out, int n) {
  int lane = threadIdx.x & 63;
  int wid = __builtin_amdgcn_readfirstlane((int)((blockIdx.x * blockDim.x + threadIdx.x) >> 6));
  if (wid >= n) return;
  int base = lane * 4;
  float xrv[4], a6[4], a4[4];
  {
    bf16x4 t = *(const bf16x4*)(xlr + (size_t)wid * 512 + 256 + base);
    unpack4(t, xrv);
#pragma unroll
    for (int j = 0; j < 4; ++j) {
      float a = att[base + j] * LOG2E;
      a6[j] = 0.6f * a;
      a4[j] = 0.4f * a;
    }
  }
  float s = 0.f;
  float acc[4] = {};
  int e0 = rowptr[wid], e1 = rowptr[wid + 1];
  int last = e1 - 1;

#define LROW2(ROW) (*(const bf16x4*)(xlr + (size_t)(ROW) * 512 + base))
  bf16x4 r0 = LROW2(csr[e0]);
  bf16x4 r1 = LROW2(csr[e0 + 1]);
  bf16x4 r2 = LROW2(csr[e0 + 2]);
  bf16x4 r3 = LROW2(csr[e0 + 3]);

  for (int pp = e0; pp < e1; pp += 4) {
    int i0 = csr[pp + 4], i1 = csr[pp + 5], i2 = csr[pp + 6], i3 = csr[pp + 7];
    bf16x4 c0 = r0, c1 = r1, c2 = r2, c3 = r3;
    r0 = LROW2(i0); r1 = LROW2(i1); r2 = LROW2(i2); r3 = LROW2(i3);
    float v0[4], v1[4], v2[4], v3[4];
    unpack4(c0, v0); unpack4(c1, v1); unpack4(c2, v2); unpack4(c3, v3);
    float p0 = 0.f, p1 = 0.f, p2 = 0.f, p3 = 0.f;
#pragma unroll
    for (int j = 0; j < 4; ++j) {
      float t0 = v0[j] + xrv[j];
      float t1 = v1[j] + xrv[j];
      float t2 = v2[j] + xrv[j];
      float t3 = v3[j] + xrv[j];
      p0 = fmaf(a6[j], t0, fmaf(a4[j], fabsf(t0), p0));
      p1 = fmaf(a6[j], t1, fmaf(a4[j], fabsf(t1), p1));
      p2 = fmaf(a6[j], t2, fmaf(a4[j], fabsf(t2), p2));
      p3 = fmaf(a6[j], t3, fmaf(a4[j], fabsf(t3), p3));
    }
    float pe0 = dppsum16(p0);
    float pe1 = dppsum16(p1);
    float pe2 = dppsum16(p2);
    float pe3 = dppsum16(p3);
    pe0 += __shfl_xor(pe0, 16); pe1 += __shfl_xor(pe1, 16);
    pe2 += __shfl_xor(pe2, 16); pe3 += __shfl_xor(pe3, 16);
    pe0 += __shfl_xor(pe0, 32); pe1 += __shfl_xor(pe1, 32);
    pe2 += __shfl_xor(pe2, 32); pe3 += __shfl_xor(pe3, 32);
    float w0 = exp2f(pe0 - 8.f * LOG2E);
    float w1 = (pp + 1 <= last) ? exp2f(pe1 - 8.f * LOG2E) : 0.f;
    float w2 = (pp + 2 <= last) ? exp2f(pe2 - 8.f * LOG2E) : 0.f;
    float w3 = (pp + 3 <= last) ? exp2f(pe3 - 8.f * LOG2E) : 0.f;
    s += (w0 + w1) + (w2 + w3);
#pragma unroll
    for (int j = 0; j < 4; ++j) {
      float t = fmaf(w0, v0[j], acc[j]);
      t = fmaf(w1, v1[j], t);
      t = fmaf(w2, v2[j], t);
      acc[j] = fmaf(w3, v3[j], t);
    }
  }
#undef LROW2
  float inv = 1.f / s;
  float o[4];
#pragma unroll
  for (int j = 0; j < 4; ++j) o[j] = acc[j] * inv + bias[base + j];
  float sum = 0.f, sq = 0.f;
#pragma unroll
  for (int j = 0; j < 4; ++j) { sum += o[j]; sq += o[j] * o[j]; }
  sum = dppsum16(sum); sq = dppsum16(sq);
  sum += __shfl_xor(sum, 16); sq += __shfl_xor(sq, 16);
  sum += __shfl_xor(sum, 32); sq += __shfl_xor(sq, 32);
  float mean = sum * (1.f / 256.f);
  float var = fmaxf(sq * (1.f / 256.f) - mean * mean, 0.f);
  float rstd = rsqrtf(var + 1e-5f);
#pragma unroll
  for (int j = 0; j < 4; ++j) {
    float y = (o[j] - mean) * rstd * lng[base + j] + lnb[base + j];
    y = y > 0.f ? y : __expf(y) - 1.f;
    out[(size_t)wid * 256 + base + j] = y;
  }
}

// ---------------- pooling (batch is sorted), 64-row chunks ----------------
__global__ __launch_bounds__(256) void k_pool(
    const float* __restrict__ h2, const int* __restrict__ batch,
    float* __restrict__ pooled, int* __restrict__ cnt, int n) {
  int c = threadIdx.x;  // 256 channels
  int n0 = blockIdx.x * 64;
  int n1 = min(n0 + 64, n);
  if (n0 >= n) return;
  float acc = 0.f;
  int cur = batch[n0];
  int cl = 0;
  for (int i = n0; i < n1; ++i) {
    int bb = batch[i];
    if (bb != cur) {
      atomicAdd(&pooled[cur * 256 + c], acc);
      if (c == 0) atomicAdd(&cnt[cur], cl);
      acc = 0.f; cl = 0; cur = bb;
    }
    acc += h2[(size_t)i * 256 + c];
    cl++;
  }
  atomicAdd(&pooled[cur * 256 + c], acc);
  if (c == 0) atomicAdd(&cnt[cur], cl);
}

// ---------------- projection head ----------------
__global__ __launch_bounds__(512) void k_proj1(
    const float* __restrict__ pooled, const int* __restrict__ cnt,
    const float* __restrict__ W, const float* __restrict__ b,
    const float* __restrict__ lng, const float* __restrict__ lnb,
    float* __restrict__ hout) {
  __shared__ float row[256];
  __shared__ float red[16];
  int g = blockIdx.x, c = threadIdx.x;
  if (c < 256) {
    float cc = fmaxf((float)cnt[g], 1.f);
    row[c] = pooled[g * 256 + c] / cc;
  }
  __syncthreads();
  float acc = b[c];
#pragma unroll 4
  for (int k = 0; k < 256; ++k) acc += row[k] * W[k * 512 + c];
  float sum = acc, sq = acc * acc;
#pragma unroll
  for (int off = 1; off < 64; off <<= 1) {
    sum += __shfl_xor(sum, off);
    sq += __shfl_xor(sq, off);
  }
  int wv = threadIdx.x >> 6;
  if ((threadIdx.x & 63) == 0) { red[wv] = sum; red[8 + wv] = sq; }
  __syncthreads();
  float S = 0.f, Q = 0.f;
#pragma unroll
  for (int t = 0; t < 8; ++t) { S += red[t]; Q += red[8 + t]; }
  float mean = S * (1.f / 512.f);
  float var = fmaxf(Q * (1.f / 512.f) - mean * mean, 0.f);
  float rstd = rsqrtf(var + 1e-5f);
  float y = (acc - mean) * rstd * lng[c] + lnb[c];
  float ge = 0.5f * y * (1.f + erff(y * 0.70710678118654752f));  // exact gelu
  hout[g * 512 + c] = ge;
}

__global__ __launch_bounds__(512) void k_proj2(
    const float* __restrict__ h, const float* __restrict__ W,
    const float* __restrict__ b, float* __restrict__ out) {
  __shared__ float row[512];
  __shared__ float red[8];
  int g = blockIdx.x, c = threadIdx.x;
  row[c] = h[g * 512 + c];
  __syncthreads();
  float acc = b[c];
#pragma unroll 4
  for (int k = 0; k < 512; ++k) acc += row[k] * W[k * 512 + c];
  float sq = acc * acc;
#pragma unroll
  for (int off = 1; off < 64; off <<= 1) sq += __shfl_xor(sq, off);
  int wv = threadIdx.x >> 6;
  if ((threadIdx.x & 63) == 0) red[wv] = sq;
  __syncthreads();
  float S = 0.f;
#pragma unroll
  for (int t = 0; t < 8; ++t) S += red[t];
  float norm = fmaxf(sqrtf(S), 1e-12f);
  out[g * 512 + c] = acc / norm;
}

// ---------------- launch ----------------
extern "C" void kernel_launch(void* const* d_in, const int* in_sizes, int n_in,
                              void* d_out, int out_size, void* d_ws, size_t ws_size,
                              hipStream_t stream) {
  const float* x_cont = (const float*)d_in[0];
  const int* x_class  = (const int*)d_in[1];
  const int* x_pitch  = (const int*)d_in[2];
  const int* ei       = (const int*)d_in[3];
  const int* batch    = (const int*)d_in[4];
  const float* ctab = (const float*)d_in[5];
  const float* ptab = (const float*)d_in[6];
  const float* Wl1 = (const float*)d_in[7];
  const float* bl1 = (const float*)d_in[8];
  const float* Wr1 = (const float*)d_in[9];
  const float* br1 = (const float*)d_in[10];
  const float* att1 = (const float*)d_in[11];
  const float* bias1 = (const float*)d_in[12];
  const float* ln1g = (const float*)d_in[13];
  const float* ln1b = (const float*)d_in[14];
  const float* Wl2 = (const float*)d_in[15];
  const float* bl2 = (const float*)d_in[16];
  const float* Wr2 = (const float*)d_in[17];
  const float* br2 = (const float*)d_in[18];
  const float* att2 = (const float*)d_in[19];
  const float* bias2 = (const float*)d_in[20];
  const float* ln2g = (const float*)d_in[21];
  const float* ln2b = (const float*)d_in[22];
  const float* Wp1 = (const float*)d_in[23];
  const float* bp1 = (const float*)d_in[24];
  const float* lnpg = (const float*)d_in[25];
  const float* lnpb = (const float*)d_in[26];
  const float* Wp2 = (const float*)d_in[27];
  const float* bp2 = (const float*)d_in[28];
  float* out = (float*)d_out;
  (void)n_in; (void)out_size; (void)ws_size;

  int N = in_sizes[1];
  int E = in_sizes[3] / 2;
  int ET = E + N;
  int NB = cdiv(N, 256);  // scan blocks (<= 256)

  // ---- workspace layout (with aliasing) ----
  char* p = (char*)d_ws;
  ushort* xb   = (ushort*)p; p += (size_t)N * 160 * 2;
  ushort* W1t  = (ushort*)p; p += (size_t)1024 * 160 * 2;
  ushort* W2t  = (ushort*)p; p += (size_t)512 * 512 * 2;
  ushort* xlr1 = (ushort*)p; p += (size_t)N * 1024 * 2;  // also xlr2 (bf16 N*512)
  ushort* h1b  = (ushort*)p; p += (size_t)N * 512 * 2;   // also h2 (fp32 N*256, same bytes)
  float* pooled = (float*)p; p += (size_t)NG * 256 * 4;
  int* cnt     = (int*)p;    p += NG * 4;
  float* hproj = (float*)p;  p += (size_t)NG * 512 * 4;
  int* deg     = (int*)p;    p += (size_t)N * 4;
  int* fill    = (int*)p;    p += (size_t)N * 4;
  int* rowptr  = (int*)p;    p += (size_t)(N + 1) * 4;
  int* csr     = (int*)p;    p += (size_t)(ET + 8) * 4;  // +8 sentinel pads
  int* bsum    = (int*)p;    p += 256 * 4;
  int* boff    = (int*)p;    p += 256 * 4;
  ushort* xlr2 = xlr1;
  float* h2   = (float*)h1b;

  const int* esrc = ei;
  const int* edst = ei + E;

  hipMemsetAsync(deg, 0, (size_t)2 * N * sizeof(int), stream);
  hipMemsetAsync(pooled, 0, (size_t)NG * 256 * sizeof(float) + NG * sizeof(int), stream);

  int prep_total = N * 160 + 1024 * 160 + 512 * 512 + ET;
  k_prep<<<cdiv(prep_total, 256), 256, 0, stream>>>(
      x_cont, x_class, x_pitch, ctab, ptab, Wl1, Wr1, Wl2, Wr2, edst,
      xb, W1t, W2t, deg, N, E);
  k_bsum<<<NB, 256, 0, stream>>>(deg, bsum, N);
  k_scanb<<<1, 256, 0, stream>>>(bsum, boff, NB);
  k_scanc<<<NB, 256, 0, stream>>>(deg, boff, rowptr, N);
  k_scatter<<<cdiv(ET + 8, 256), 256, 0, stream>>>(esrc, edst, rowptr, fill, csr, E, N);

  dim3 g1(cdiv(N, GBM), 1024 / GBN);
  k_gemm_mfma<<<g1, 256, 0, stream>>>(xb, W1t, bl1, br1, 512, xlr1, N, 160, 1024);
  k_gat1<<<cdiv(N * 64, 256), 256, 0, stream>>>(xlr1, rowptr, csr, att1, bias1, ln1g, ln1b, h1b, N);

  dim3 g2(cdiv(N, GBM), 512 / GBN);
  k_gemm_mfma<<<g2, 256, 0, stream>>>(h1b, W2t, bl2, br2, 256, xlr2, N, 512, 512);
  k_gat2<<<cdiv(N * 64, 256), 256, 0, stream>>>(xlr2, rowptr, csr, att2, bias2, ln2g, ln2b, h2, N);

  k_pool<<<cdiv(N, 64), 256, 0, stream>>>(h2, batch, pooled, cnt, N);
  k_proj1<<<NG, 512, 0, stream>>>(pooled, cnt, Wp1, bp1, lnpg, lnpb, hproj);
  k_proj2<<<NG, 512, 0, stream>>>(hproj, Wp2, bp2, out);
}

// Round 9
// 333.660 us; speedup vs baseline: 3.0921x; 1.0129x over previous
//
#include <hip/hip_runtime.h>
#include <math.h>

#define NG 64   // graphs

typedef short bf16x8 __attribute__((ext_vector_type(8)));
typedef short bf16x4 __attribute__((ext_vector_type(4)));
typedef float f32x4 __attribute__((ext_vector_type(4)));

#define LOG2E 1.4426950408889634f

static inline int cdiv(int a, int b) { return (a + b - 1) / b; }

__device__ inline ushort f2b(float f) {
  union { float f; uint u; } v; v.f = f;
  uint u = v.u;
  return (ushort)((u + 0x7fffu + ((u >> 16) & 1u)) >> 16);
}

__device__ __forceinline__ void unpack8(bf16x8 vb, float* v) {
  union { bf16x8 b; uint u[4]; } cv; cv.b = vb;
#pragma unroll
  for (int q = 0; q < 4; ++q) {
    union { uint u; float f; } lo, hi;
    lo.u = cv.u[q] << 16;
    hi.u = cv.u[q] & 0xffff0000u;
    v[2 * q] = lo.f; v[2 * q + 1] = hi.f;
  }
}
__device__ __forceinline__ void unpack4(bf16x4 vb, float* v) {
  union { bf16x4 b; uint u[2]; } cv; cv.b = vb;
#pragma unroll
  for (int q = 0; q < 2; ++q) {
    union { uint u; float f; } lo, hi;
    lo.u = cv.u[q] << 16;
    hi.u = cv.u[q] & 0xffff0000u;
    v[2 * q] = lo.f; v[2 * q + 1] = hi.f;
  }
}

// pure-VALU all-reduce (sum) within each 16-lane row via DPP row_ror
__device__ __forceinline__ float dppsum16(float x) {
  union { float f; int i; } a, b;
  a.f = x;
  b.i = __builtin_amdgcn_update_dpp(0, a.i, 0x121, 0xF, 0xF, true); a.f += b.f; // ror:1
  b.i = __builtin_amdgcn_update_dpp(0, a.i, 0x122, 0xF, 0xF, true); a.f += b.f; // ror:2
  b.i = __builtin_amdgcn_update_dpp(0, a.i, 0x124, 0xF, 0xF, true); a.f += b.f; // ror:4
  b.i = __builtin_amdgcn_update_dpp(0, a.i, 0x128, 0xF, 0xF, true); a.f += b.f; // ror:8
  return a.f;
}

// ---------------- fused prep: features + both weight transposes + degree hist ----------------
__global__ __launch_bounds__(256) void k_prep(
    const float* __restrict__ xc, const int* __restrict__ xcl,
    const int* __restrict__ xpi, const float* __restrict__ ctab,
    const float* __restrict__ ptab,
    const float* __restrict__ Wl1, const float* __restrict__ Wr1,
    const float* __restrict__ Wl2, const float* __restrict__ Wr2,
    const int* __restrict__ edst,
    ushort* __restrict__ xb, ushort* __restrict__ W1t, ushort* __restrict__ W2t,
    int* __restrict__ deg, int n, int E) {
  int t = blockIdx.x * blockDim.x + threadIdx.x;
  int T1 = n * 160;
  int T2 = T1 + 1024 * 160;
  int T3 = T2 + 512 * 512;
  int T4 = T3 + E + n;
  if (t < T1) {
    int node = t / 160, c = t % 160;
    float v;
    if (c < 6)        v = xc[node * 6 + c];
    else if (c < 70)  v = ctab[xcl[node] * 64 + (c - 6)];
    else if (c < 134) v = ptab[xpi[node] * 64 + (c - 70)];
    else              v = 0.f;
    xb[t] = f2b(v);
  } else if (t < T2) {
    int u = t - T1;
    int c = u / 160, k = u % 160;
    float v = 0.f;
    if (k < 134) v = (c < 512) ? Wl1[k * 512 + c] : Wr1[k * 512 + (c - 512)];
    W1t[u] = f2b(v);
  } else if (t < T3) {
    int u = t - T2;
    int c = u / 512, k = u % 512;
    float v = (c < 256) ? Wl2[k * 256 + c] : Wr2[k * 256 + (c - 256)];
    W2t[u] = f2b(v);
  } else if (t < T4) {
    int u = t - T3;
    if (u < E) atomicAdd(&deg[edst[u]], 1);
    else atomicAdd(&deg[u - E], 1);   // self loops
  }
}

// 3-phase scan
__global__ __launch_bounds__(256) void k_bsum(const int* __restrict__ deg,
                                              int* __restrict__ bsum, int n) {
  int i = blockIdx.x * 256 + threadIdx.x;
  int v = (i < n) ? deg[i] : 0;
#pragma unroll
  for (int off = 1; off < 64; off <<= 1) v += __shfl_xor(v, off);
  __shared__ int ws[4];
  if ((threadIdx.x & 63) == 0) ws[threadIdx.x >> 6] = v;
  __syncthreads();
  if (threadIdx.x == 0) bsum[blockIdx.x] = ws[0] + ws[1] + ws[2] + ws[3];
}

__global__ __launch_bounds__(256) void k_scanb(const int* __restrict__ bsum,
                                               int* __restrict__ boff, int nb) {
  int t = threadIdx.x, lane = t & 63;
  int v = (t < nb) ? bsum[t] : 0;
  int incl = v;
#pragma unroll
  for (int off = 1; off < 64; off <<= 1) {
    int u = __shfl_up(incl, off);
    if (lane >= off) incl += u;
  }
  __shared__ int wsum[4];
  if (lane == 63) wsum[t >> 6] = incl;
  __syncthreads();
  int add = 0;
  for (int w = 0; w < (t >> 6); ++w) add += wsum[w];
  if (t < nb) boff[t] = incl + add - v;  // exclusive
}

__global__ __launch_bounds__(256) void k_scanc(const int* __restrict__ deg,
                                               const int* __restrict__ boff,
                                               int* __restrict__ rowptr, int n) {
  int b = blockIdx.x, t = threadIdx.x, lane = t & 63;
  int i = b * 256 + t;
  int v = (i < n) ? deg[i] : 0;
  int incl = v;
#pragma unroll
  for (int off = 1; off < 64; off <<= 1) {
    int u = __shfl_up(incl, off);
    if (lane >= off) incl += u;
  }
  __shared__ int wsum[4];
  if (lane == 63) wsum[t >> 6] = incl;
  __syncthreads();
  int add = boff[b];
  for (int w = 0; w < (t >> 6); ++w) add += wsum[w];
  if (i < n) rowptr[i + 1] = incl + add;
  if (i == 0) rowptr[0] = 0;
}

__global__ __launch_bounds__(256) void k_scatter(
    const int* __restrict__ src, const int* __restrict__ dst,
    const int* __restrict__ rowptr, int* __restrict__ fill,
    int* __restrict__ csr, int E, int N) {
  int t = blockIdx.x * blockDim.x + threadIdx.x;
  int s, d;
  if (t < E) { s = src[t]; d = dst[t]; }
  else if (t < E + N) { s = t - E; d = t - E; }
  else if (t < E + N + 8) { csr[t] = 0; return; }
  else return;
  int pos = rowptr[d] + atomicAdd(&fill[d], 1);
  csr[pos] = s;
}

// ---------------- bf16 MFMA GEMM with SPLIT output: cols<nhalf -> Clo, else Chi ----------------
// A bf16 [M][Kp]; Bt bf16 [NC][Kp]. Clo/Chi bf16 [M][nhalf]. Tile cols (128) always in one half.
#define GBM 128
#define GBN 128
#define GBK 32
#define ESTRIDE 136
__device__ __forceinline__ int swzf(int r, int s) {
  return r * 64 + ((s * 16) ^ (((r >> 1) & 3) << 4));
}
__global__ __launch_bounds__(256) void k_gemm_mfma(
    const ushort* __restrict__ A, const ushort* __restrict__ Bt,
    const float* __restrict__ blo, const float* __restrict__ bhi, int nhalf,
    ushort* __restrict__ Clo, ushort* __restrict__ Chi, int M, int Kp) {
  __shared__ ushort smem[GBM * ESTRIDE];
  ushort* sA = smem;
  ushort* sB = smem + GBM * GBK;
  int tid = threadIdx.x;
  int lane = tid & 63, w = tid >> 6;
  int wr = w >> 1, wc = w & 1;
  int row0 = blockIdx.x * GBM, col0 = blockIdx.y * GBN;
  int nK = Kp / GBK;

  int rs = tid >> 2, ss = tid & 3;
  int wO0 = swzf(rs, ss);
  int wO1 = swzf(rs + 64, ss);
  bool okA0 = (row0 + rs) < M;
  bool okA1 = (row0 + rs + 64) < M;
  size_t baseA0 = (size_t)(row0 + rs) * Kp + ss * 8;
  size_t baseA1 = (size_t)(row0 + rs + 64) * Kp + ss * 8;
  size_t baseB0 = (size_t)(col0 + rs) * Kp + ss * 8;
  size_t baseB1 = (size_t)(col0 + rs + 64) * Kp + ss * 8;

  int fr = lane & 15, kq = lane >> 4;
  int aoff[4], boff[4];
#pragma unroll
  for (int m = 0; m < 4; ++m) {
    int ra = wr * 64 + m * 16 + fr;
    aoff[m] = ra * 64 + ((kq * 16) ^ (((ra >> 1) & 3) << 4));
    int rb = wc * 64 + m * 16 + fr;
    boff[m] = rb * 64 + ((kq * 16) ^ (((rb >> 1) & 3) << 4));
  }

  f32x4 acc[4][4] = {};
  bf16x8 zz = {};
  bf16x8 pa0, pa1, pb0, pb1, qa0, qa1, qb0, qb1;

#define LOADG(KS, RA0, RA1, RB0, RB1)                                   \
  do {                                                                  \
    const ushort* ap = A + (size_t)(KS) * GBK;                          \
    const ushort* bp = Bt + (size_t)(KS) * GBK;                         \
    RA0 = okA0 ? *(const bf16x8*)(ap + baseA0) : zz;                    \
    RA1 = okA1 ? *(const bf16x8*)(ap + baseA1) : zz;                    \
    RB0 = *(const bf16x8*)(bp + baseB0);                                \
    RB1 = *(const bf16x8*)(bp + baseB1);                                \
  } while (0)

#define STAGE(RA0, RA1, RB0, RB1)                                       \
  do {                                                                  \
    *(bf16x8*)((char*)sA + wO0) = RA0;                                  \
    *(bf16x8*)((char*)sA + wO1) = RA1;                                  \
    *(bf16x8*)((char*)sB + wO0) = RB0;                                  \
    *(bf16x8*)((char*)sB + wO1) = RB1;                                  \
  } while (0)

#define COMPUTE()                                                       \
  do {                                                                  \
    bf16x8 av[4], bv[4];                                                \
    _Pragma("unroll") for (int m = 0; m < 4; ++m)                       \
        av[m] = *(const bf16x8*)((const char*)sA + aoff[m]);            \
    _Pragma("unroll") for (int n = 0; n < 4; ++n)                       \
        bv[n] = *(const bf16x8*)((const char*)sB + boff[n]);            \
    _Pragma("unroll") for (int m = 0; m < 4; ++m)                       \
        _Pragma("unroll") for (int n = 0; n < 4; ++n)                   \
            acc[m][n] = __builtin_amdgcn_mfma_f32_16x16x32_bf16(        \
                av[m], bv[n], acc[m][n], 0, 0, 0);                      \
  } while (0)

  LOADG(0, pa0, pa1, pb0, pb1);
  for (int ks = 0; ks < nK; ++ks) {
    __syncthreads();
    if (ks & 1) {
      STAGE(qa0, qa1, qb0, qb1);
      if (ks + 1 < nK) LOADG(ks + 1, pa0, pa1, pb0, pb1);
    } else {
      STAGE(pa0, pa1, pb0, pb1);
      if (ks + 1 < nK) LOADG(ks + 1, qa0, qa1, qb0, qb1);
    }
    __syncthreads();
    COMPUTE();
  }

  // epilogue: stage tile in LDS, then coalesced bf16x8 stores into the split half
  __syncthreads();
#pragma unroll
  for (int m = 0; m < 4; ++m) {
#pragma unroll
    for (int n = 0; n < 4; ++n) {
      int tc = wc * 64 + n * 16 + fr;
      float bv = ((col0 + tc) < nhalf) ? blo[col0 + tc] : bhi[col0 + tc - nhalf];
#pragma unroll
      for (int j = 0; j < 4; ++j) {
        int tr = wr * 64 + m * 16 + kq * 4 + j;
        smem[tr * ESTRIDE + tc] = f2b(acc[m][n][j] + bv);
      }
    }
  }
  __syncthreads();
  ushort* Cd = (col0 < nhalf) ? Clo : Chi;
  int cb0 = (col0 < nhalf) ? col0 : col0 - nhalf;
  int r0 = tid >> 4, cb = (tid & 15) * 8;
#pragma unroll
  for (int pass = 0; pass < 8; ++pass) {
    int r = pass * 16 + r0;
    int grow = row0 + r;
    if (grow < M) {
      bf16x8 vv = *(const bf16x8*)&smem[r * ESTRIDE + cb];
      *(bf16x8*)&Cd[(size_t)grow * nhalf + cb0 + cb] = vv;
    }
  }
#undef LOADG
#undef STAGE
#undef COMPUTE
}

// ---------------- GAT layer 1: dense xl table [N][512] bf16 (1KB rows), xr [N][512] ----------------
// Scalarized CSR walk; SALU-clamped 4-deep ring; pe = sum a6.t + a4.|t| (log2-scaled);
// w = exp2(pe - 8*log2e). out: [N][512] bf16 (bias+LN+ELU fused).
__global__ __launch_bounds__(256, 4) void k_gat1(
    const ushort* __restrict__ xl, const ushort* __restrict__ xr,
    const int* __restrict__ rowptr, const int* __restrict__ csr,
    const float* __restrict__ att, const float* __restrict__ bias,
    const float* __restrict__ lng, const float* __restrict__ lnb,
    ushort* __restrict__ out, int n) {
  int lane = threadIdx.x & 63;
  int wid = __builtin_amdgcn_readfirstlane((int)((blockIdx.x * blockDim.x + threadIdx.x) >> 6));
  if (wid >= n) return;
  int base = lane * 8;
  float xrv[8], a6[8], a4[8];
  {
    bf16x8 t = *(const bf16x8*)(xr + (size_t)wid * 512 + base);
    unpack8(t, xrv);
#pragma unroll
    for (int j = 0; j < 8; ++j) {
      float a = att[base + j] * LOG2E;
      a6[j] = 0.6f * a;
      a4[j] = 0.4f * a;
    }
  }
  float s = 0.f;
  float acc[8] = {};
  int e0 = rowptr[wid], e1 = rowptr[wid + 1];
  int last = e1 - 1;

#define LROW1(ROW) (*(const bf16x8*)(xl + (size_t)(ROW) * 512 + base))
  bf16x8 r0 = LROW1(csr[e0]);
  bf16x8 r1 = LROW1(csr[min(e0 + 1, last)]);
  bf16x8 r2 = LROW1(csr[min(e0 + 2, last)]);
  bf16x8 r3 = LROW1(csr[min(e0 + 3, last)]);

  for (int pp = e0; pp < e1; pp += 4) {
    int i0 = csr[min(pp + 4, last)], i1 = csr[min(pp + 5, last)];
    int i2 = csr[min(pp + 6, last)], i3 = csr[min(pp + 7, last)];
    bf16x8 c0 = r0, c1 = r1, c2 = r2, c3 = r3;
    r0 = LROW1(i0); r1 = LROW1(i1); r2 = LROW1(i2); r3 = LROW1(i3);
    float v0[8], v1[8], v2[8], v3[8];
    unpack8(c0, v0); unpack8(c1, v1); unpack8(c2, v2); unpack8(c3, v3);
    float p0 = 0.f, p1 = 0.f, p2 = 0.f, p3 = 0.f;
#pragma unroll
    for (int j = 0; j < 8; ++j) {
      float t0 = v0[j] + xrv[j];
      float t1 = v1[j] + xrv[j];
      float t2 = v2[j] + xrv[j];
      float t3 = v3[j] + xrv[j];
      p0 = fmaf(a6[j], t0, fmaf(a4[j], fabsf(t0), p0));
      p1 = fmaf(a6[j], t1, fmaf(a4[j], fabsf(t1), p1));
      p2 = fmaf(a6[j], t2, fmaf(a4[j], fabsf(t2), p2));
      p3 = fmaf(a6[j], t3, fmaf(a4[j], fabsf(t3), p3));
    }
    float pe0 = dppsum16(p0);
    float pe1 = dppsum16(p1);
    float pe2 = dppsum16(p2);
    float pe3 = dppsum16(p3);
    float w0 = exp2f(pe0 - 8.f * LOG2E);
    float w1 = (pp + 1 <= last) ? exp2f(pe1 - 8.f * LOG2E) : 0.f;
    float w2 = (pp + 2 <= last) ? exp2f(pe2 - 8.f * LOG2E) : 0.f;
    float w3 = (pp + 3 <= last) ? exp2f(pe3 - 8.f * LOG2E) : 0.f;
    s += (w0 + w1) + (w2 + w3);
#pragma unroll
    for (int j = 0; j < 8; ++j) {
      float t = fmaf(w0, v0[j], acc[j]);
      t = fmaf(w1, v1[j], t);
      t = fmaf(w2, v2[j], t);
      acc[j] = fmaf(w3, v3[j], t);
    }
  }
#undef LROW1
  float inv = 1.f / s;
  float o[8];
#pragma unroll
  for (int j = 0; j < 8; ++j) o[j] = acc[j] * inv + bias[base + j];
  float sum = 0.f, sq = 0.f;
#pragma unroll
  for (int j = 0; j < 8; ++j) { sum += o[j]; sq += o[j] * o[j]; }
  sum = dppsum16(sum); sq = dppsum16(sq);
  sum += __shfl_xor(sum, 16); sq += __shfl_xor(sq, 16);
  sum += __shfl_xor(sum, 32); sq += __shfl_xor(sq, 32);
  float mean = sum * (1.f / 512.f);
  float var = fmaxf(sq * (1.f / 512.f) - mean * mean, 0.f);
  float rstd = rsqrtf(var + 1e-5f);
  bf16x8 ov;
#pragma unroll
  for (int j = 0; j < 8; ++j) {
    float y = (o[j] - mean) * rstd * lng[base + j] + lnb[base + j];
    y = y > 0.f ? y : __expf(y) - 1.f;   // ELU
    ov[j] = (short)f2b(y);
  }
  *(bf16x8*)&out[(size_t)wid * 512 + base] = ov;
}

// ---------------- GAT layer 2: dense xl2 [N][256] bf16 (512B rows), xr2 [N][256] ----------------
__global__ __launch_bounds__(256, 4) void k_gat2(
    const ushort* __restrict__ xl, const ushort* __restrict__ xr,
    const int* __restrict__ rowptr, const int* __restrict__ csr,
    const float* __restrict__ att, const float* __restrict__ bias,
    const float* __restrict__ lng, const float* __restrict__ lnb,
    float* __restrict__ out, int n) {
  int lane = threadIdx.x & 63;
  int wid = __builtin_amdgcn_readfirstlane((int)((blockIdx.x * blockDim.x + threadIdx.x) >> 6));
  if (wid >= n) return;
  int base = lane * 4;
  float xrv[4], a6[4], a4[4];
  {
    bf16x4 t = *(const bf16x4*)(xr + (size_t)wid * 256 + base);
    unpack4(t, xrv);
#pragma unroll
    for (int j = 0; j < 4; ++j) {
      float a = att[base + j] * LOG2E;
      a6[j] = 0.6f * a;
      a4[j] = 0.4f * a;
    }
  }
  float s = 0.f;
  float acc[4] = {};
  int e0 = rowptr[wid], e1 = rowptr[wid + 1];
  int last = e1 - 1;

#define LROW2(ROW) (*(const bf16x4*)(xl + (size_t)(ROW) * 256 + base))
  bf16x4 r0 = LROW2(csr[e0]);
  bf16x4 r1 = LROW2(csr[min(e0 + 1, last)]);
  bf16x4 r2 = LROW2(csr[min(e0 + 2, last)]);
  bf16x4 r3 = LROW2(csr[min(e0 + 3, last)]);

  for (int pp = e0; pp < e1; pp += 4) {
    int i0 = csr[min(pp + 4, last)], i1 = csr[min(pp + 5, last)];
    int i2 = csr[min(pp + 6, last)], i3 = csr[min(pp + 7, last)];
    bf16x4 c0 = r0, c1 = r1, c2 = r2, c3 = r3;
    r0 = LROW2(i0); r1 = LROW2(i1); r2 = LROW2(i2); r3 = LROW2(i3);
    float v0[4], v1[4], v2[4], v3[4];
    unpack4(c0, v0); unpack4(c1, v1); unpack4(c2, v2); unpack4(c3, v3);
    float p0 = 0.f, p1 = 0.f, p2 = 0.f, p3 = 0.f;
#pragma unroll
    for (int j = 0; j < 4; ++j) {
      float t0 = v0[j] + xrv[j];
      float t1 = v1[j] + xrv[j];
      float t2 = v2[j] + xrv[j];
      float t3 = v3[j] + xrv[j];
      p0 = fmaf(a6[j], t0, fmaf(a4[j], fabsf(t0), p0));
      p1 = fmaf(a6[j], t1, fmaf(a4[j], fabsf(t1), p1));
      p2 = fmaf(a6[j], t2, fmaf(a4[j], fabsf(t2), p2));
      p3 = fmaf(a6[j], t3, fmaf(a4[j], fabsf(t3), p3));
    }
    float pe0 = dppsum16(p0);
    float pe1 = dppsum16(p1);
    float pe2 = dppsum16(p2);
    float pe3 = dppsum16(p3);
    pe0 += __shfl_xor(pe0, 16); pe1 += __shfl_xor(pe1, 16);
    pe2 += __shfl_xor(pe2, 16); pe3 += __shfl_xor(pe3, 16);
    pe0 += __shfl_xor(pe0, 32); pe1 += __shfl_xor(pe1, 32);
    pe2 += __shfl_xor(pe2, 32); pe3 += __shfl_xor(pe3, 32);
    float w0 = exp2f(pe0 - 8.f * LOG2E);
    float w1 = (pp + 1 <= last) ? exp2f(pe1 - 8.f * LOG2E) : 0.f;
    float w2 = (pp + 2 <= last) ? exp2f(pe2 - 8.f * LOG2E) : 0.f;
    float w3 = (pp + 3 <= last) ? exp2f(pe3 - 8.f * LOG2E) : 0.f;
    s += (w0 + w1) + (w2 + w3);
#pragma unroll
    for (int j = 0; j < 4; ++j) {
      float t = fmaf(w0, v0[j], acc[j]);
      t = fmaf(w1, v1[j], t);
      t = fmaf(w2, v2[j], t);
      acc[j] = fmaf(w3, v3[j], t);
    }
  }
#undef LROW2
  float inv = 1.f / s;
  float o[4];
#pragma unroll
  for (int j = 0; j < 4; ++j) o[j] = acc[j] * inv + bias[base + j];
  float sum = 0.f, sq = 0.f;
#pragma unroll
  for (int j = 0; j < 4; ++j) { sum += o[j]; sq += o[j] * o[j]; }
  sum = dppsum16(sum); sq = dppsum16(sq);
  sum += __shfl_xor(sum, 16); sq += __shfl_xor(sq, 16);
  sum += __shfl_xor(sum, 32); sq += __shfl_xor(sq, 32);
  float mean = sum * (1.f / 256.f);
  float var = fmaxf(sq * (1.f / 256.f) - mean * mean, 0.f);
  float rstd = rsqrtf(var + 1e-5f);
#pragma unroll
  for (int j = 0; j < 4; ++j) {
    float y = (o[j] - mean) * rstd * lng[base + j] + lnb[base + j];
    y = y > 0.f ? y : __expf(y) - 1.f;
    out[(size_t)wid * 256 + base + j] = y;
  }
}

// ---------------- pooling (batch is sorted), 64-row chunks ----------------
__global__ __launch_bounds__(256) void k_pool(
    const float* __restrict__ h2, const int* __restrict__ batch,
    float* __restrict__ pooled, int* __restrict__ cnt, int n) {
  int c = threadIdx.x;  // 256 channels
  int n0 = blockIdx.x * 64;
  int n1 = min(n0 + 64, n);
  if (n0 >= n) return;
  float acc = 0.f;
  int cur = batch[n0];
  int cl = 0;
  for (int i = n0; i < n1; ++i) {
    int bb = batch[i];
    if (bb != cur) {
      atomicAdd(&pooled[cur * 256 + c], acc);
      if (c == 0) atomicAdd(&cnt[cur], cl);
      acc = 0.f; cl = 0; cur = bb;
    }
    acc += h2[(size_t)i * 256 + c];
    cl++;
  }
  atomicAdd(&pooled[cur * 256 + c], acc);
  if (c == 0) atomicAdd(&cnt[cur], cl);
}

// ---------------- projection head ----------------
__global__ __launch_bounds__(512) void k_proj1(
    const float* __restrict__ pooled, const int* __restrict__ cnt,
    const float* __restrict__ W, const float* __restrict__ b,
    const float* __restrict__ lng, const float* __restrict__ lnb,
    float* __restrict__ hout) {
  __shared__ float row[256];
  __shared__ float red[16];
  int g = blockIdx.x, c = threadIdx.x;
  if (c < 256) {
    float cc = fmaxf((float)cnt[g], 1.f);
    row[c] = pooled[g * 256 + c] / cc;
  }
  __syncthreads();
  float acc = b[c];
#pragma unroll 4
  for (int k = 0; k < 256; ++k) acc += row[k] * W[k * 512 + c];
  float sum = acc, sq = acc * acc;
#pragma unroll
  for (int off = 1; off < 64; off <<= 1) {
    sum += __shfl_xor(sum, off);
    sq += __shfl_xor(sq, off);
  }
  int wv = threadIdx.x >> 6;
  if ((threadIdx.x & 63) == 0) { red[wv] = sum; red[8 + wv] = sq; }
  __syncthreads();
  float S = 0.f, Q = 0.f;
#pragma unroll
  for (int t = 0; t < 8; ++t) { S += red[t]; Q += red[8 + t]; }
  float mean = S * (1.f / 512.f);
  float var = fmaxf(Q * (1.f / 512.f) - mean * mean, 0.f);
  float rstd = rsqrtf(var + 1e-5f);
  float y = (acc - mean) * rstd * lng[c] + lnb[c];
  float ge = 0.5f * y * (1.f + erff(y * 0.70710678118654752f));  // exact gelu
  hout[g * 512 + c] = ge;
}

__global__ __launch_bounds__(512) void k_proj2(
    const float* __restrict__ h, const float* __restrict__ W,
    const float* __restrict__ b, float* __restrict__ out) {
  __shared__ float row[512];
  __shared__ float red[8];
  int g = blockIdx.x, c = threadIdx.x;
  row[c] = h[g * 512 + c];
  __syncthreads();
  float acc = b[c];
#pragma unroll 4
  for (int k = 0; k < 512; ++k) acc += row[k] * W[k * 512 + c];
  float sq = acc * acc;
#pragma unroll
  for (int off = 1; off < 64; off <<= 1) sq += __shfl_xor(sq, off);
  int wv = threadIdx.x >> 6;
  if ((threadIdx.x & 63) == 0) red[wv] = sq;
  __syncthreads();
  float S = 0.f;
#pragma unroll
  for (int t = 0; t < 8; ++t) S += red[t];
  float norm = fmaxf(sqrtf(S), 1e-12f);
  out[g * 512 + c] = acc / norm;
}

// ---------------- launch ----------------
extern "C" void kernel_launch(void* const* d_in, const int* in_sizes, int n_in,
                              void* d_out, int out_size, void* d_ws, size_t ws_size,
                              hipStream_t stream) {
  const float* x_cont = (const float*)d_in[0];
  const int* x_class  = (const int*)d_in[1];
  const int* x_pitch  = (const int*)d_in[2];
  const int* ei       = (const int*)d_in[3];
  const int* batch    = (const int*)d_in[4];
  const float* ctab = (const float*)d_in[5];
  const float* ptab = (const float*)d_in[6];
  const float* Wl1 = (const float*)d_in[7];
  const float* bl1 = (const float*)d_in[8];
  const float* Wr1 = (const float*)d_in[9];
  const float* br1 = (const float*)d_in[10];
  const float* att1 = (const float*)d_in[11];
  const float* bias1 = (const float*)d_in[12];
  const float* ln1g = (const float*)d_in[13];
  const float* ln1b = (const float*)d_in[14];
  const float* Wl2 = (const float*)d_in[15];
  const float* bl2 = (const float*)d_in[16];
  const float* Wr2 = (const float*)d_in[17];
  const float* br2 = (const float*)d_in[18];
  const float* att2 = (const float*)d_in[19];
  const float* bias2 = (const float*)d_in[20];
  const float* ln2g = (const float*)d_in[21];
  const float* ln2b = (const float*)d_in[22];
  const float* Wp1 = (const float*)d_in[23];
  const float* bp1 = (const float*)d_in[24];
  const float* lnpg = (const float*)d_in[25];
  const float* lnpb = (const float*)d_in[26];
  const float* Wp2 = (const float*)d_in[27];
  const float* bp2 = (const float*)d_in[28];
  float* out = (float*)d_out;
  (void)n_in; (void)out_size; (void)ws_size;

  int N = in_sizes[1];
  int E = in_sizes[3] / 2;
  int ET = E + N;
  int NB = cdiv(N, 256);  // scan blocks (<= 256)

  // ---- workspace layout (with aliasing) ----
  char* p = (char*)d_ws;
  ushort* xb   = (ushort*)p; p += (size_t)N * 160 * 2;
  ushort* W1t  = (ushort*)p; p += (size_t)1024 * 160 * 2;
  ushort* W2t  = (ushort*)p; p += (size_t)512 * 512 * 2;
  ushort* xl1  = (ushort*)p; p += (size_t)N * 512 * 2;   // dense gather table L1
  ushort* xr1  = (ushort*)p; p += (size_t)N * 512 * 2;   // also h2 (fp32 N*256, same bytes)
  ushort* h1b  = (ushort*)p; p += (size_t)N * 512 * 2;   // gat1 out (bf16)
  float* pooled = (float*)p; p += (size_t)NG * 256 * 4;
  int* cnt     = (int*)p;    p += NG * 4;
  float* hproj = (float*)p;  p += (size_t)NG * 512 * 4;
  int* deg     = (int*)p;    p += (size_t)N * 4;
  int* fill    = (int*)p;    p += (size_t)N * 4;
  int* rowptr  = (int*)p;    p += (size_t)(N + 1) * 4;
  int* csr     = (int*)p;    p += (size_t)(ET + 8) * 4;  // +8 sentinel pads
  int* bsum    = (int*)p;    p += 256 * 4;
  int* boff    = (int*)p;    p += 256 * 4;
  ushort* xl2 = xl1;                         // dense [N][256] (xl1 dead after gat1)
  ushort* xr2 = xl1 + (size_t)N * 256;
  float* h2   = (float*)xr1;                 // fp32 [N][256] = N*1024 B

  const int* esrc = ei;
  const int* edst = ei + E;

  hipMemsetAsync(deg, 0, (size_t)2 * N * sizeof(int), stream);
  hipMemsetAsync(pooled, 0, (size_t)NG * 256 * sizeof(float) + NG * sizeof(int), stream);

  int prep_total = N * 160 + 1024 * 160 + 512 * 512 + ET;
  k_prep<<<cdiv(prep_total, 256), 256, 0, stream>>>(
      x_cont, x_class, x_pitch, ctab, ptab, Wl1, Wr1, Wl2, Wr2, edst,
      xb, W1t, W2t, deg, N, E);
  k_bsum<<<NB, 256, 0, stream>>>(deg, bsum, N);
  k_scanb<<<1, 256, 0, stream>>>(bsum, boff, NB);
  k_scanc<<<NB, 256, 0, stream>>>(deg, boff, rowptr, N);
  k_scatter<<<cdiv(ET + 8, 256), 256, 0, stream>>>(esrc, edst, rowptr, fill, csr, E, N);

  dim3 g1(cdiv(N, GBM), 1024 / GBN);
  k_gemm_mfma<<<g1, 256, 0, stream>>>(xb, W1t, bl1, br1, 512, xl1, xr1, N, 160);
  k_gat1<<<cdiv(N * 64, 256), 256, 0, stream>>>(xl1, xr1, rowptr, csr, att1, bias1, ln1g, ln1b, h1b, N);

  dim3 g2(cdiv(N, GBM), 512 / GBN);
  k_gemm_mfma<<<g2, 256, 0, stream>>>(h1b, W2t, bl2, br2, 256, xl2, xr2, N, 512);
  k_gat2<<<cdiv(N * 64, 256), 256, 0, stream>>>(xl2, xr2, rowptr, csr, att2, bias2, ln2g, ln2b, h2, N);

  k_pool<<<cdiv(N, 64), 256, 0, stream>>>(h2, batch, pooled, cnt, N);
  k_proj1<<<NG, 512, 0, stream>>>(pooled, cnt, Wp1, bp1, lnpg, lnpb, hproj);
  k_proj2<<<NG, 512, 0, stream>>>(hproj, Wp2, bp2, out);
}